// Round 2
// baseline (351.222 us; speedup 1.0000x reference)
//
#include <hip/hip_runtime.h>
#include <hip/hip_bf16.h>

#define B_   8
#define S_   2048
#define DM   1024
#define DH   128
#define BS_  16384
#define SCALE_  0.08838834764831845f
#define SCALE2_ 0.12751744f   // SCALE * log2(e)

typedef unsigned short u16;
typedef unsigned int   u32;
typedef _Float16 half8 __attribute__((ext_vector_type(8)));
typedef float    f32x4 __attribute__((ext_vector_type(4)));
typedef u32      u32x4 __attribute__((ext_vector_type(4)));

union H8 { u32x4 v; u32 u[4]; half8 h; };

__device__ __forceinline__ float bf2f(u16 u) {
    union { u32 i; float f; } w; w.i = ((u32)u) << 16; return w.f;
}
__device__ __forceinline__ void unpack8(uint4 v, float* f) {
    f[0] = bf2f(v.x & 0xffff); f[1] = bf2f(v.x >> 16);
    f[2] = bf2f(v.y & 0xffff); f[3] = bf2f(v.y >> 16);
    f[4] = bf2f(v.z & 0xffff); f[5] = bf2f(v.z >> 16);
    f[6] = bf2f(v.w & 0xffff); f[7] = bf2f(v.w >> 16);
}
__device__ __forceinline__ float ldE(const void* b, size_t i, int isbf16) {
    return isbf16 ? bf2f(((const u16*)b)[i]) : ((const float*)b)[i];
}
__device__ __forceinline__ void ld8(const void* b, size_t i, int isbf16, float* f) {
    if (isbf16) {
        unpack8(*(const uint4*)((const u16*)b + i), f);
    } else {
        float4 a = *(const float4*)((const float*)b + i);
        float4 c = *(const float4*)((const float*)b + i + 4);
        f[0] = a.x; f[1] = a.y; f[2] = a.z; f[3] = a.w;
        f[4] = c.x; f[5] = c.y; f[6] = c.z; f[7] = c.w;
    }
}
// fp32 -> packed (f16 hi << 16) | f16 lo  (2-term split, ~22 mantissa bits)
__device__ __forceinline__ u32 f2pk(float v) {
    _Float16 h = (_Float16)v;
    _Float16 l = (_Float16)(v - (float)h);
    union { _Float16 f; u16 u; } a, b; a.f = h; b.f = l;
    return ((u32)a.u << 16) | (u32)b.u;
}
// 8 floats -> pair-packed hi/lo frag u32x4
__device__ __forceinline__ void split8(const float* f, u32x4& hi, u32x4& lo) {
    u32 H[8], L[8];
#pragma unroll
    for (int j = 0; j < 8; ++j) {
        _Float16 h = (_Float16)f[j];
        _Float16 l = (_Float16)(f[j] - (float)h);
        union { _Float16 x; u16 u; } a, b; a.x = h; b.x = l;
        H[j] = a.u; L[j] = b.u;
    }
    hi = (u32x4){H[0] | (H[1] << 16), H[2] | (H[3] << 16), H[4] | (H[5] << 16), H[6] | (H[7] << 16)};
    lo = (u32x4){L[0] | (L[1] << 16), L[2] | (L[3] << 16), L[4] | (L[5] << 16), L[6] | (L[7] << 16)};
}
__device__ __forceinline__ u32 permHI(u32 eB, u32 eA) { return __builtin_amdgcn_perm(eB, eA, 0x07060302u); }
__device__ __forceinline__ u32 permLO(u32 eB, u32 eA) { return __builtin_amdgcn_perm(eB, eA, 0x05040100u); }

// ---------------- init: dtype detect + active mask + round counters ----------------
__global__ void init_kernel(const void* x, int* flag, int* active, int* counts) {
    int i = blockIdx.x * 256 + threadIdx.x;
    if (i < BS_) active[i] = 1;
    if (i < 4) counts[i] = (i == 0) ? BS_ : 0;
    if (i == 0) {
        const u16* w = (const u16*)x;
        int sane = 0;
        for (int t = 0; t < 256; ++t) {
            int e = (w[2 * t] >> 7) & 0xFF;
            if (e >= 100 && e <= 135) ++sane;
        }
        *flag = (sane >= 192) ? 1 : 0;   // 1 = bf16, 0 = fp32
    }
}

// ---------------- prepack W into MFMA fragment layout ----------------
// wpk[((z*32 + ks)*16 + 2*t + plane)*64 + lane] : u32x4
__global__ __launch_bounds__(256) void prepack_w_kernel(
    const void* __restrict__ wq, const void* __restrict__ wk, const void* __restrict__ wv,
    const int* __restrict__ flag, u32x4* __restrict__ wpk)
{
    const int isb = *flag;
    const int gid = blockIdx.x * 256 + threadIdx.x;
    const int l  = gid & 63;
    const int t  = (gid >> 6) & 7;
    const int ks = (gid >> 9) & 31;
    const int z  = gid >> 14;
    const void* W = (z == 0) ? wq : (z == 1) ? wk : wv;
    const int row = 16 * t + (l & 15);
    const int k0  = ks * 32 + 8 * (l >> 4);
    float f[8];
    ld8(W, (size_t)row * DM + k0, isb, f);
    u32x4 hi, lo;
    split8(f, hi, lo);
    const size_t base = ((((size_t)z * 32 + ks) * 16) + 2 * t) * 64 + l;
    wpk[base]      = hi;
    wpk[base + 64] = lo;
}

// ---------------- MFMA QKV v3: prepacked W + global_load_lds staging ----------------
__global__ __launch_bounds__(256) void qkv_kernel(
    const void* __restrict__ x, const u32x4* __restrict__ wpk,
    const int* __restrict__ flag, u32* __restrict__ qkv)
{
    const int isb = *flag;
    const int z = blockIdx.z;
    u32* out = qkv + (size_t)z * ((size_t)BS_ * DH);
    const int m0 = blockIdx.x * 64;
    const int tid = threadIdx.x;
    const int wave = tid >> 6, lane = tid & 63;
    const int qd = lane >> 4, c = lane & 15;

    __shared__ u32x4 WL[2][8][2][64];   // [buf][colTile][hi/lo][lane] 32 KB

    const u32x4* wz = wpk + (size_t)z * (32 * 16 * 64);
    const size_t arow = (size_t)(m0 + wave * 16 + c) * DM + 8 * qd;

#define STAGE_W(ks_, b_)                                                          \
    {                                                                             \
        const u32x4* _src = wz + ((size_t)(ks_) * 16 + 4 * wave) * 64 + lane;     \
        _Pragma("unroll")                                                         \
        for (int _j = 0; _j < 4; ++_j) {                                          \
            __builtin_amdgcn_global_load_lds(                                     \
                (const __attribute__((address_space(1))) u32*)(_src + _j * 64),   \
                (__attribute__((address_space(3))) u32*)&WL[b_][2 * wave + (_j >> 1)][_j & 1][0], \
                16, 0, 0);                                                        \
        }                                                                         \
    }

    float Ar[8], Arn[8];
    ld8(x, arow, isb, Ar);
    STAGE_W(0, 0);
    ld8(x, arow + 32, isb, Arn);
    __syncthreads();

    f32x4 acc[8] = {};

    for (int ks = 0; ks < 32; ++ks) {
        const int cb = ks & 1;
        if (ks + 1 < 32) STAGE_W(ks + 1, cb ^ 1);

        H8 Ah, Al;
        split8(Ar, Ah.v, Al.v);
#pragma unroll
        for (int t = 0; t < 8; ++t) {
            H8 bh, bl;
            bh.v = WL[cb][t][0][lane]; bl.v = WL[cb][t][1][lane];
            acc[t] = __builtin_amdgcn_mfma_f32_16x16x32_f16(Al.h, bh.h, acc[t], 0, 0, 0);
            acc[t] = __builtin_amdgcn_mfma_f32_16x16x32_f16(Ah.h, bl.h, acc[t], 0, 0, 0);
            acc[t] = __builtin_amdgcn_mfma_f32_16x16x32_f16(Ah.h, bh.h, acc[t], 0, 0, 0);
        }
#pragma unroll
        for (int j = 0; j < 8; ++j) Ar[j] = Arn[j];
        if (ks + 2 < 32) ld8(x, arow + (size_t)(ks + 2) * 32, isb, Arn);
        __syncthreads();
    }
#undef STAGE_W

#pragma unroll
    for (int r = 0; r < 4; ++r) {
        const int row = m0 + wave * 16 + qd * 4 + r;
        u32* op = out + (size_t)row * DH + c;
#pragma unroll
        for (int t = 0; t < 8; ++t) op[t * 16] = f2pk(acc[t][r]);
    }
}

// ---------------- attention core (shared by both variants) ----------------
template <bool WRITE_PARTIAL>
__device__ __forceinline__ void attn_body(
    const u32* qp, const u32* __restrict__ kp, const u32* __restrict__ vp,
    float* outO, float* outL, float* cur,
    int b, int q0, int kt0, int kt1, int part)
{
    const int tid = threadIdx.x;
    const int wave = tid >> 6, lane = tid & 63;
    const int qd = lane >> 4, c = lane & 15;

    __shared__ u32x4 KF[2][2][2][4][64];  // [buf][plane][tile][ks][lane] 32 KB
    __shared__ u32x4 VF[2][2][8][64];     // [buf][plane][t][lane]       32 KB
    __shared__ u32   PB[4][531];          // per-wave P, elem-packed, stride 33

    H8 Qh[4], Ql[4];
    {
        const u32* qr = qp + ((size_t)b * S_ + q0 + wave * 16 + c) * DH;
#pragma unroll
        for (int ks = 0; ks < 4; ++ks) {
            uint4 e0 = *(const uint4*)(qr + ks * 32 + qd * 8);
            uint4 e1 = *(const uint4*)(qr + ks * 32 + qd * 8 + 4);
            Qh[ks].u[0] = permHI(e0.y, e0.x); Qh[ks].u[1] = permHI(e0.w, e0.z);
            Qh[ks].u[2] = permHI(e1.y, e1.x); Qh[ks].u[3] = permHI(e1.w, e1.z);
            Ql[ks].u[0] = permLO(e0.y, e0.x); Ql[ks].u[1] = permLO(e0.w, e0.z);
            Ql[ks].u[2] = permLO(e1.y, e1.x); Ql[ks].u[3] = permLO(e1.w, e1.z);
        }
    }

    const int kKey = tid & 31, kD0 = (tid >> 5) * 16;
    const int vD = tid >> 1, vKg = (tid & 1) * 16;
    const int tK = (tid >> 4) & 1, cK = tid & 15;
    const int tV = tid >> 5,      cV = (tid >> 1) & 15;

    uint4 Kst[4]; u32 Vst[16];

    auto loadKV = [&](int kb) {
        const u32* kr = kp + ((size_t)b * S_ + kb * 32 + kKey) * DH + kD0;
#pragma unroll
        for (int j = 0; j < 4; ++j) Kst[j] = *(const uint4*)(kr + 4 * j);
        const u32* vc = vp + ((size_t)b * S_ + kb * 32 + vKg) * DH + vD;
#pragma unroll
        for (int j = 0; j < 16; ++j) Vst[j] = vc[(size_t)j * DH];
    };
    auto writeKV = [&](int wb) {
#pragma unroll
        for (int g = 0; g < 2; ++g) {
            const int dg = kD0 + 8 * g, ksK = dg >> 5, qK = (dg >> 3) & 3;
            KF[wb][0][tK][ksK][qK * 16 + cK] = (u32x4){
                permHI(Kst[2*g].y, Kst[2*g].x), permHI(Kst[2*g].w, Kst[2*g].z),
                permHI(Kst[2*g+1].y, Kst[2*g+1].x), permHI(Kst[2*g+1].w, Kst[2*g+1].z)};
            KF[wb][1][tK][ksK][qK * 16 + cK] = (u32x4){
                permLO(Kst[2*g].y, Kst[2*g].x), permLO(Kst[2*g].w, Kst[2*g].z),
                permLO(Kst[2*g+1].y, Kst[2*g+1].x), permLO(Kst[2*g+1].w, Kst[2*g+1].z)};
        }
#pragma unroll
        for (int g = 0; g < 2; ++g) {
            const int qV = 2 * (tid & 1) + g;
            VF[wb][0][tV][qV * 16 + cV] = (u32x4){
                permHI(Vst[8*g+1], Vst[8*g+0]), permHI(Vst[8*g+3], Vst[8*g+2]),
                permHI(Vst[8*g+5], Vst[8*g+4]), permHI(Vst[8*g+7], Vst[8*g+6])};
            VF[wb][1][tV][qV * 16 + cV] = (u32x4){
                permLO(Vst[8*g+1], Vst[8*g+0]), permLO(Vst[8*g+3], Vst[8*g+2]),
                permLO(Vst[8*g+5], Vst[8*g+4]), permLO(Vst[8*g+7], Vst[8*g+6])};
        }
    };

    loadKV(kt0);
    writeKV(0);
    if (kt0 + 1 < kt1) loadKV(kt0 + 1);
    __syncthreads();

    f32x4 O[8] = {};
    float lsum[4] = {};

    for (int kt = kt0; kt < kt1; ++kt) {
        const int cb = (kt - kt0) & 1;

        f32x4 S0 = {}, S1 = {};
#pragma unroll
        for (int ks = 0; ks < 4; ++ks) {
            H8 kh, kl;
            kh.v = KF[cb][0][0][ks][lane]; kl.v = KF[cb][1][0][ks][lane];
            S0 = __builtin_amdgcn_mfma_f32_16x16x32_f16(Ql[ks].h, kh.h, S0, 0, 0, 0);
            S0 = __builtin_amdgcn_mfma_f32_16x16x32_f16(Qh[ks].h, kl.h, S0, 0, 0, 0);
            S0 = __builtin_amdgcn_mfma_f32_16x16x32_f16(Qh[ks].h, kh.h, S0, 0, 0, 0);
            kh.v = KF[cb][0][1][ks][lane]; kl.v = KF[cb][1][1][ks][lane];
            S1 = __builtin_amdgcn_mfma_f32_16x16x32_f16(Ql[ks].h, kh.h, S1, 0, 0, 0);
            S1 = __builtin_amdgcn_mfma_f32_16x16x32_f16(Qh[ks].h, kl.h, S1, 0, 0, 0);
            S1 = __builtin_amdgcn_mfma_f32_16x16x32_f16(Qh[ks].h, kh.h, S1, 0, 0, 0);
        }

        u32* pw = PB[wave];
#pragma unroll
        for (int r = 0; r < 4; ++r) {
            float e0 = exp2f(fmaf(S0[r], SCALE2_, -4.0f));
            float e1 = exp2f(fmaf(S1[r], SCALE2_, -4.0f));
            lsum[r] += e0 + e1;
            pw[(4 * qd + r) * 33 + c]      = f2pk(e0);
            pw[(4 * qd + r) * 33 + 16 + c] = f2pk(e1);
        }

        u32 e[8];
#pragma unroll
        for (int j = 0; j < 8; ++j) e[j] = pw[c * 33 + 8 * qd + j];
        H8 Ph, Pl;
        Ph.u[0] = permHI(e[1], e[0]); Ph.u[1] = permHI(e[3], e[2]);
        Ph.u[2] = permHI(e[5], e[4]); Ph.u[3] = permHI(e[7], e[6]);
        Pl.u[0] = permLO(e[1], e[0]); Pl.u[1] = permLO(e[3], e[2]);
        Pl.u[2] = permLO(e[5], e[4]); Pl.u[3] = permLO(e[7], e[6]);

#pragma unroll
        for (int t = 0; t < 8; ++t) {
            H8 vh, vl;
            vh.v = VF[cb][0][t][lane]; vl.v = VF[cb][1][t][lane];
            O[t] = __builtin_amdgcn_mfma_f32_16x16x32_f16(Pl.h, vh.h, O[t], 0, 0, 0);
            O[t] = __builtin_amdgcn_mfma_f32_16x16x32_f16(Ph.h, vl.h, O[t], 0, 0, 0);
            O[t] = __builtin_amdgcn_mfma_f32_16x16x32_f16(Ph.h, vh.h, O[t], 0, 0, 0);
        }

        if (kt + 1 < kt1) {
            writeKV((kt + 1 - kt0) & 1);
            if (kt + 2 < kt1) loadKV(kt + 2);
        }
        __syncthreads();
    }

    if (WRITE_PARTIAL) {
        float lred[4];
#pragma unroll
        for (int r = 0; r < 4; ++r) {
            float l = lsum[r];
            l += __shfl_xor(l, 1); l += __shfl_xor(l, 2);
            l += __shfl_xor(l, 4); l += __shfl_xor(l, 8);
            lred[r] = l;
        }
        const size_t rb = (size_t)b * S_ + q0 + wave * 16 + 4 * qd;
        float* Op = outO + (size_t)part * ((size_t)BS_ * DH);
#pragma unroll
        for (int t = 0; t < 8; ++t)
#pragma unroll
            for (int r = 0; r < 4; ++r)
                Op[(rb + r) * DH + t * 16 + c] = O[t][r];
        if (c == 0) {
            float* lp = outL + (size_t)part * BS_;
#pragma unroll
            for (int r = 0; r < 4; ++r) lp[rb + r] = lred[r];
        }
    } else {
        float linv[4];
#pragma unroll
        for (int r = 0; r < 4; ++r) {
            float l = lsum[r];
            l += __shfl_xor(l, 1); l += __shfl_xor(l, 2);
            l += __shfl_xor(l, 4); l += __shfl_xor(l, 8);
            linv[r] = 1.0f / l;
        }
        const size_t rb = (size_t)b * S_ + q0 + wave * 16 + 4 * qd;
#pragma unroll
        for (int t = 0; t < 8; ++t)
#pragma unroll
            for (int r = 0; r < 4; ++r)
                cur[(rb + r) * DH + t * 16 + c] = O[t][r] * linv[r];
    }
}

__global__ __launch_bounds__(256) void attn_kernel(
    const u32* qp, const u32* __restrict__ kp, const u32* __restrict__ vp, float* cur)
{
    attn_body<false>(qp, kp, vp, nullptr, nullptr, cur,
                     blockIdx.y, blockIdx.x * 64, 0, S_ / 32, 0);
}

__global__ __launch_bounds__(256) void attn_split_kernel(
    const u32* qp, const u32* __restrict__ kp, const u32* __restrict__ vp,
    float* __restrict__ Opart, float* __restrict__ lpart)
{
    const int part = blockIdx.z;
    const int half = S_ / 64;   // 32 tiles per part
    attn_body<true>(qp, kp, vp, Opart, lpart, nullptr,
                    blockIdx.y, blockIdx.x * 64, part * half, (part + 1) * half, part);
}

// combine: cur0 = (Oa + Ob) / (la + lb). grid 512 x 256, 16 elems/thread.
__global__ __launch_bounds__(256) void combine_kernel(
    const float* __restrict__ Opart, const float* __restrict__ lpart,
    float* __restrict__ cur)
{
    const size_t N1 = (size_t)BS_ * DH;
    const size_t i0 = ((size_t)blockIdx.x * 256 + threadIdx.x) * 16;
    const int row = (int)(i0 >> 7);
    const float linv = 1.0f / (lpart[row] + lpart[BS_ + row]);
#pragma unroll
    for (int t = 0; t < 4; ++t) {
        float4 a = *(const float4*)(Opart + i0 + t * 4);
        float4 b = *(const float4*)(Opart + N1 + i0 + t * 4);
        *(float4*)(cur + i0 + t * 4) = make_float4(
            (a.x + b.x) * linv, (a.y + b.y) * linv,
            (a.z + b.z) * linv, (a.w + b.w) * linv);
    }
}

// ---------------- W2eff = (w1a - w1b) contracted with tw; beff = tb@w1a^T + ab@w1b^T ----
// W2eff[n,m] = sum_k (w1[n,k] - w1[n,128+k]) * tw[k,m].  grid 64 x 256.
__global__ __launch_bounds__(256) void weff_kernel(
    const void* __restrict__ tw, const void* __restrict__ w1,
    const void* __restrict__ tb, const void* __restrict__ ab,
    const int* __restrict__ flag, float* __restrict__ W2s, float* __restrict__ beff)
{
    const int isb = *flag;
    const int idx = blockIdx.x * 256 + threadIdx.x;
    const int n = idx >> 7, m = idx & 127;
    float s = 0.0f;
    for (int k = 0; k < 128; ++k) {
        float d = ldE(w1, (size_t)n * 384 + k, isb) - ldE(w1, (size_t)n * 384 + 128 + k, isb);
        s += d * ldE(tw, (size_t)k * 128 + m, isb);
    }
    W2s[n * 128 + m] = s;
    if (m == 0) {
        float bs = 0.0f;
        for (int k = 0; k < 128; ++k)
            bs += ldE(tb, k, isb) * ldE(w1, (size_t)n * 384 + k, isb)
                + ldE(ab, k, isb) * ldE(w1, (size_t)n * 384 + 128 + k, isb);
        beff[n] = bs;
    }
}

// ---------------- prepack round weights: mat 0=W2eff(f32 scratch), 1=w1c, 2=w2 ----------
// pk[((mat*4 + ks)*16 + 2*t + plane)*64 + lane].  grid 24 x 256.
__global__ __launch_bounds__(256) void prepack_rw_kernel(
    const void* __restrict__ w1, const void* __restrict__ w2,
    const float* __restrict__ W2s, const int* __restrict__ flag,
    u32x4* __restrict__ pk)
{
    const int isb = *flag;
    const int gid = blockIdx.x * 256 + threadIdx.x;   // 6144 total
    const int l = gid & 63, t = (gid >> 6) & 7, ks = (gid >> 9) & 3, mat = gid >> 11;
    const int row = 16 * t + (l & 15);
    const int k0  = ks * 32 + 8 * (l >> 4);
    float f[8];
    if (mat == 0) {
#pragma unroll
        for (int j = 0; j < 8; ++j) f[j] = W2s[row * 128 + k0 + j];
    } else if (mat == 1) {
        ld8(w1, (size_t)row * 384 + 256 + k0, isb, f);
    } else {
        ld8(w2, (size_t)row * 128 + k0, isb, f);
    }
    u32x4 hi, lo;
    split8(f, hi, lo);
    const size_t base = (((size_t)mat * 4 + ks) * 16 + 2 * t) * 64 + l;
    pk[base] = hi; pk[base + 64] = lo;
}

// stage one 128x128 packed mat into WS[4][16][64]: wave w handles ks=w
#define STAGE_MAT(pk_, mat_, WS_)                                                  \
    {                                                                              \
        _Pragma("unroll")                                                          \
        for (int _j = 0; _j < 16; ++_j) {                                          \
            __builtin_amdgcn_global_load_lds(                                      \
                (const __attribute__((address_space(1))) u32*)(                    \
                    (pk_) + (((size_t)(mat_) * 4 + wave) * 16 + _j) * 64 + lane),  \
                (__attribute__((address_space(3))) u32*)&WS_[wave][_j][0],         \
                16, 0, 0);                                                         \
        }                                                                          \
    }

// ---------------- T0eff = cur0 @ W2eff^T + beff (round-invariant), grid 256 ----------
__global__ __launch_bounds__(256) void t0eff_kernel(
    const float* __restrict__ cur0, const u32x4* __restrict__ pk,
    const float* __restrict__ beff, float* __restrict__ T0)
{
    const int tok0 = blockIdx.x * 64;
    const int tid = threadIdx.x;
    const int wave = tid >> 6, lane = tid & 63;
    const int qd = lane >> 4, c = lane & 15;
    __shared__ u32x4 WS[4][16][64];   // 64 KB
    __shared__ float beS[128];

    STAGE_MAT(pk, 0, WS);
    if (tid < 128) beS[tid] = beff[tid];

    float A1[4][8];
#pragma unroll
    for (int ks = 0; ks < 4; ++ks) {
        const float* ap = cur0 + (size_t)(tok0 + 16 * wave + c) * 128 + ks * 32 + 8 * qd;
        *(float4*)&A1[ks][0] = *(const float4*)ap;
        *(float4*)&A1[ks][4] = *(const float4*)(ap + 4);
    }
    __syncthreads();

    f32x4 acc[8] = {};
#pragma unroll
    for (int ks = 0; ks < 4; ++ks) {
        H8 Ah, Al;
        split8(A1[ks], Ah.v, Al.v);
#pragma unroll
        for (int t = 0; t < 8; ++t) {
            H8 bh, bl;
            bh.v = WS[ks][2 * t][lane]; bl.v = WS[ks][2 * t + 1][lane];
            acc[t] = __builtin_amdgcn_mfma_f32_16x16x32_f16(Al.h, bh.h, acc[t], 0, 0, 0);
            acc[t] = __builtin_amdgcn_mfma_f32_16x16x32_f16(Ah.h, bl.h, acc[t], 0, 0, 0);
            acc[t] = __builtin_amdgcn_mfma_f32_16x16x32_f16(Ah.h, bh.h, acc[t], 0, 0, 0);
        }
    }
#pragma unroll
    for (int t = 0; t < 8; ++t)
#pragma unroll
        for (int r = 0; r < 4; ++r)
            T0[(size_t)(tok0 + 16 * wave + 4 * qd + r) * 128 + 16 * t + c] = acc[t][r] + beS[16 * t + c];
}

// ---------------- one dialectic round, MFMA version ----------------
// h = relu( am*(T0eff + curr@w1c^T) + b1 ); synth = h@w2^T + b2; gate/update as before.
__global__ __launch_bounds__(256) void round2_kernel(
    const float* __restrict__ T0, const float* curr,
    const u32x4* __restrict__ pk,
    const void* __restrict__ b1, const void* __restrict__ b2,
    const void* __restrict__ gw, const void* __restrict__ gb,
    const int* __restrict__ flag, int* active, int* counts, int r,
    float* cur_out, void* dout)
{
    const int isb = *flag;
    const int tok0 = blockIdx.x * 64;
    const int tid = threadIdx.x;
    const bool last = (dout != nullptr);

    if (counts[r] <= 0) {
        if (last) {
            for (int e = tid; e < 64 * DH; e += 256) {
                size_t idx = (size_t)tok0 * DH + e;
                float v = curr[idx];
                if (isb) ((__hip_bfloat16*)dout)[idx] = __float2bfloat16(v);
                else     ((float*)dout)[idx] = v;
            }
        }
        return;
    }

    const int wave = tid >> 6, lane = tid & 63;
    const int qd = lane >> 4, c = lane & 15;

    __shared__ u32x4 WS[4][16][64];   // 64 KB (w1c, then w2)
    __shared__ float HS[64][132];     // h rows, then synth rows (33.8 KB)
    __shared__ float actS[64], b1S[128], b2S[128], gwS[256];
    __shared__ int blkcnt;

    // stage w1c (mat 1)
    STAGE_MAT(pk, 1, WS);

    if (tid < 64) actS[tid] = active[tok0 + tid] ? 1.0f : 0.0f;
    if (tid < 128) { b1S[tid] = ldE(b1, tid, isb); b2S[tid] = ldE(b2, tid, isb); }
    gwS[tid] = ldE(gw, tid, isb);
    if (tid == 0) blkcnt = 0;
    const float gbf = ldE(gb, 0, isb);

    // prefetch A rows (curr, fp32) and T0eff tile
    float A1[4][8];
#pragma unroll
    for (int ks = 0; ks < 4; ++ks) {
        const float* ap = curr + (size_t)(tok0 + 16 * wave + c) * 128 + ks * 32 + 8 * qd;
        *(float4*)&A1[ks][0] = *(const float4*)ap;
        *(float4*)&A1[ks][4] = *(const float4*)(ap + 4);
    }
    float T0r[8][4];
#pragma unroll
    for (int t = 0; t < 8; ++t)
#pragma unroll
        for (int rr = 0; rr < 4; ++rr)
            T0r[t][rr] = T0[(size_t)(tok0 + 16 * wave + 4 * qd + rr) * 128 + 16 * t + c];
    __syncthreads();

    // ---- GEMM1: S1 = curr @ w1c^T ----
    {
        f32x4 acc[8] = {};
#pragma unroll
        for (int ks = 0; ks < 4; ++ks) {
            H8 Ah, Al;
            split8(A1[ks], Ah.v, Al.v);
#pragma unroll
            for (int t = 0; t < 8; ++t) {
                H8 bh, bl;
                bh.v = WS[ks][2 * t][lane]; bl.v = WS[ks][2 * t + 1][lane];
                acc[t] = __builtin_amdgcn_mfma_f32_16x16x32_f16(Al.h, bh.h, acc[t], 0, 0, 0);
                acc[t] = __builtin_amdgcn_mfma_f32_16x16x32_f16(Ah.h, bl.h, acc[t], 0, 0, 0);
                acc[t] = __builtin_amdgcn_mfma_f32_16x16x32_f16(Ah.h, bh.h, acc[t], 0, 0, 0);
            }
        }
        const int grow = 16 * wave + 4 * qd;
#pragma unroll
        for (int t = 0; t < 8; ++t)
#pragma unroll
            for (int rr = 0; rr < 4; ++rr) {
                const float am = actS[grow + rr];
                HS[grow + rr][16 * t + c] =
                    fmaxf(am * (T0r[t][rr] + acc[t][rr]) + b1S[16 * t + c], 0.0f);
            }
    }
    __syncthreads();           // all waves done with WS (GEMM1)
    // restage WS with w2 (mat 2)
    STAGE_MAT(pk, 2, WS);
    __syncthreads();

    // ---- GEMM2: synth = h @ w2^T + b2 ----
    {
        f32x4 acc[8] = {};
#pragma unroll
        for (int ks = 0; ks < 4; ++ks) {
            float Ar[8];
            const float* hp = &HS[16 * wave + c][ks * 32 + 8 * qd];
            *(float4*)&Ar[0] = *(const float4*)hp;
            *(float4*)&Ar[4] = *(const float4*)(hp + 4);
            H8 Ah, Al;
            split8(Ar, Ah.v, Al.v);
#pragma unroll
            for (int t = 0; t < 8; ++t) {
                H8 bh, bl;
                bh.v = WS[ks][2 * t][lane]; bl.v = WS[ks][2 * t + 1][lane];
                acc[t] = __builtin_amdgcn_mfma_f32_16x16x32_f16(Al.h, bh.h, acc[t], 0, 0, 0);
                acc[t] = __builtin_amdgcn_mfma_f32_16x16x32_f16(Ah.h, bl.h, acc[t], 0, 0, 0);
                acc[t] = __builtin_amdgcn_mfma_f32_16x16x32_f16(Ah.h, bh.h, acc[t], 0, 0, 0);
            }
        }
        // synth -> HS (same-wave rows; all GEMM2 h-reads precede in program order)
        const int grow = 16 * wave + 4 * qd;
#pragma unroll
        for (int t = 0; t < 8; ++t)
#pragma unroll
            for (int rr = 0; rr < 4; ++rr)
                HS[grow + rr][16 * t + c] = acc[t][rr] + b2S[16 * t + c];
    }

    // ---- gate, update, norm, active (rows are wave-local in HS) ----
    const int tok = tid >> 2, d0 = (tid & 3) * 32;
    const float am = actS[tok];
    const float* cp = curr + (size_t)(tok0 + tok) * DH + d0;
    float cv[32];
#pragma unroll
    for (int t = 0; t < 8; ++t) {
        float4 vv = *(const float4*)(cp + t * 4);
        cv[t * 4] = vv.x; cv[t * 4 + 1] = vv.y; cv[t * 4 + 2] = vv.z; cv[t * 4 + 3] = vv.w;
    }
    const float* srow = &HS[tok][d0];
    float gp = 0.0f;
#pragma unroll
    for (int e = 0; e < 32; ++e)
        gp += cv[e] * am * gwS[d0 + e] + srow[e] * gwS[128 + d0 + e];
    gp += __shfl_xor(gp, 1, 4);
    gp += __shfl_xor(gp, 2, 4);
    const float gate = 1.0f / (1.0f + __expf(-(gp + gbf)));
    float ss = 0.0f; float up[32];
#pragma unroll
    for (int e = 0; e < 32; ++e) {
        float u = gate * (srow[e] - cv[e] * am) * 0.1f;
        up[e] = u; ss += u * u;
    }
    ss += __shfl_xor(ss, 1, 4);
    ss += __shfl_xor(ss, 2, 4);
    const bool stable = sqrtf(ss) < 0.1f;

    if (last) {
        size_t off = (size_t)(tok0 + tok) * DH + d0;
        if (isb) {
            __hip_bfloat16* op = (__hip_bfloat16*)dout + off;
#pragma unroll
            for (int e = 0; e < 32; ++e) op[e] = __float2bfloat16(cv[e] + up[e]);
        } else {
            float* op = (float*)dout + off;
#pragma unroll
            for (int t = 0; t < 8; ++t)
                *(float4*)(op + t * 4) = make_float4(cv[t * 4] + up[t * 4], cv[t * 4 + 1] + up[t * 4 + 1],
                                                     cv[t * 4 + 2] + up[t * 4 + 2], cv[t * 4 + 3] + up[t * 4 + 3]);
        }
    } else {
        float* op = cur_out + (size_t)(tok0 + tok) * DH + d0;
#pragma unroll
        for (int t = 0; t < 8; ++t)
            *(float4*)(op + t * 4) = make_float4(cv[t * 4] + up[t * 4], cv[t * 4 + 1] + up[t * 4 + 1],
                                                 cv[t * 4 + 2] + up[t * 4 + 2], cv[t * 4 + 3] + up[t * 4 + 3]);
    }
    const int newact = (am > 0.0f && !stable) ? 1 : 0;
    if ((tid & 3) == 0) {
        active[tok0 + tok] = newact;
        if (newact) atomicAdd(&blkcnt, 1);
    }
    __syncthreads();
    if (tid == 0 && blkcnt > 0) atomicAdd(&counts[r + 1], blkcnt);
}

#undef STAGE_MAT

extern "C" void kernel_launch(void* const* d_in, const int* in_sizes, int n_in,
                              void* d_out, int out_size, void* d_ws, size_t ws_size,
                              hipStream_t stream) {
    const void* x  = d_in[0];
    const void* wq = d_in[1];
    const void* wk = d_in[2];
    const void* wv = d_in[3];
    const void* tw = d_in[4];
    const void* tb = d_in[5];
    const void* ab = d_in[6];
    const void* w1 = d_in[7];
    const void* b1 = d_in[8];
    const void* w2 = d_in[9];
    const void* b2 = d_in[10];
    const void* gw = d_in[11];
    const void* gb = d_in[12];

    u32* ws = (u32*)d_ws;
    const size_t N1 = (size_t)BS_ * DH;
    // base layout (~24 MiB): qp | kp | vp | active | counts | flag | beff | pad
    u32* qp = ws;
    u32* kp = ws + N1;
    u32* vp = ws + 2 * N1;
    int* active = (int*)(ws + 3 * N1);
    int* counts = active + BS_;
    int* flag   = counts + 4;
    float* beff = (float*)(flag + 1);               // 128 f32, durable (in pad gap)
    float* cur0  = (float*)qp;
    float* cur_r = (float*)kp;
    float* T0    = (float*)vp;                       // vp is dead after attention
    // split-KV extension (needs ~42.3 MB total):
    float* Opart = (float*)(ws + 3 * N1 + 32768);    // 2 x N1 fp32
    float* lpart = (float*)(ws + 5 * N1 + 32768);    // 2 x BS_ fp32
    const bool big_ws = ws_size >= (size_t)42300000; // constant across calls
    // transient region at Opart base, used in two non-overlapping epochs:
    //  epoch 1 (pre-attn):  wpk = qkv weight packs (1.5 MB)
    //  epoch 2 (post-combine): pkRW (192 KB) + W2eff f32 scratch (64 KB)
    u32x4* wpk  = (u32x4*)(ws + 3 * N1 + 32768);
    u32x4* pkRW = (u32x4*)(ws + 3 * N1 + 32768);
    float* W2s  = (float*)(ws + 3 * N1 + 32768 + 49152);

    init_kernel<<<dim3(BS_ / 256), 256, 0, stream>>>(x, flag, active, counts);
    prepack_w_kernel<<<dim3(192), 256, 0, stream>>>(wq, wk, wv, flag, wpk);
    qkv_kernel<<<dim3(BS_ / 64, 1, 3), 256, 0, stream>>>(x, wpk, flag, qp);
    if (big_ws) {
        attn_split_kernel<<<dim3(S_ / 64, B_, 2), 256, 0, stream>>>(qp, kp, vp, Opart, lpart);
        combine_kernel<<<dim3(512), 256, 0, stream>>>(Opart, lpart, cur0);
    } else {
        attn_kernel<<<dim3(S_ / 64, B_), 256, 0, stream>>>(qp, kp, vp, cur0);
    }
    // round-invariant precomputation
    weff_kernel<<<dim3(64), 256, 0, stream>>>(tw, w1, tb, ab, flag, W2s, beff);
    prepack_rw_kernel<<<dim3(24), 256, 0, stream>>>(w1, w2, W2s, flag, pkRW);
    t0eff_kernel<<<dim3(BS_ / 64), 256, 0, stream>>>(cur0, pkRW, beff, T0);
    // rounds
    round2_kernel<<<dim3(BS_ / 64), 256, 0, stream>>>(
        T0, cur0, pkRW, b1, b2, gw, gb, flag, active, counts, 0, cur_r, nullptr);
    round2_kernel<<<dim3(BS_ / 64), 256, 0, stream>>>(
        T0, cur_r, pkRW, b1, b2, gw, gb, flag, active, counts, 1, cur_r, nullptr);
    round2_kernel<<<dim3(BS_ / 64), 256, 0, stream>>>(
        T0, cur_r, pkRW, b1, b2, gw, gb, flag, active, counts, 2, cur_r, d_out);
}

// Round 5
// 331.496 us; speedup vs baseline: 1.0595x; 1.0595x over previous
//
#include <hip/hip_runtime.h>
#include <hip/hip_bf16.h>

#define B_   8
#define S_   2048
#define DM   1024
#define DH   128
#define BS_  16384
#define SCALE_  0.08838834764831845f
#define SCALE2_ 0.12751744f   // SCALE * log2(e)

typedef unsigned short u16;
typedef unsigned int   u32;
typedef _Float16 half8 __attribute__((ext_vector_type(8)));
typedef float    f32x4 __attribute__((ext_vector_type(4)));
typedef u32      u32x4 __attribute__((ext_vector_type(4)));

union H8 { u32x4 v; u32 u[4]; half8 h; };

__device__ __forceinline__ float bf2f(u16 u) {
    union { u32 i; float f; } w; w.i = ((u32)u) << 16; return w.f;
}
__device__ __forceinline__ void unpack8(uint4 v, float* f) {
    f[0] = bf2f(v.x & 0xffff); f[1] = bf2f(v.x >> 16);
    f[2] = bf2f(v.y & 0xffff); f[3] = bf2f(v.y >> 16);
    f[4] = bf2f(v.z & 0xffff); f[5] = bf2f(v.z >> 16);
    f[6] = bf2f(v.w & 0xffff); f[7] = bf2f(v.w >> 16);
}
__device__ __forceinline__ float ldE(const void* b, size_t i, int isbf16) {
    return isbf16 ? bf2f(((const u16*)b)[i]) : ((const float*)b)[i];
}
__device__ __forceinline__ void ld8(const void* b, size_t i, int isbf16, float* f) {
    if (isbf16) {
        unpack8(*(const uint4*)((const u16*)b + i), f);
    } else {
        float4 a = *(const float4*)((const float*)b + i);
        float4 c = *(const float4*)((const float*)b + i + 4);
        f[0] = a.x; f[1] = a.y; f[2] = a.z; f[3] = a.w;
        f[4] = c.x; f[5] = c.y; f[6] = c.z; f[7] = c.w;
    }
}
// fp32 -> packed (f16 hi << 16) | f16 lo  (2-term split, ~22 mantissa bits)
__device__ __forceinline__ u32 f2pk(float v) {
    _Float16 h = (_Float16)v;
    _Float16 l = (_Float16)(v - (float)h);
    union { _Float16 f; u16 u; } a, b; a.f = h; b.f = l;
    return ((u32)a.u << 16) | (u32)b.u;
}
// 8 floats -> pair-packed hi/lo frag u32x4
__device__ __forceinline__ void split8(const float* f, u32x4& hi, u32x4& lo) {
    u32 H[8], L[8];
#pragma unroll
    for (int j = 0; j < 8; ++j) {
        _Float16 h = (_Float16)f[j];
        _Float16 l = (_Float16)(f[j] - (float)h);
        union { _Float16 x; u16 u; } a, b; a.x = h; b.x = l;
        H[j] = a.u; L[j] = b.u;
    }
    hi = (u32x4){H[0] | (H[1] << 16), H[2] | (H[3] << 16), H[4] | (H[5] << 16), H[6] | (H[7] << 16)};
    lo = (u32x4){L[0] | (L[1] << 16), L[2] | (L[3] << 16), L[4] | (L[5] << 16), L[6] | (L[7] << 16)};
}
__device__ __forceinline__ u32 permHI(u32 eB, u32 eA) { return __builtin_amdgcn_perm(eB, eA, 0x07060302u); }
__device__ __forceinline__ u32 permLO(u32 eB, u32 eA) { return __builtin_amdgcn_perm(eB, eA, 0x05040100u); }

// ---------------- init: dtype detect + active mask + round counters ----------------
__global__ void init_kernel(const void* x, int* flag, int* active, int* counts) {
    int i = blockIdx.x * 256 + threadIdx.x;
    if (i < BS_) active[i] = 1;
    if (i < 4) counts[i] = (i == 0) ? BS_ : 0;
    if (i == 0) {
        const u16* w = (const u16*)x;
        int sane = 0;
        for (int t = 0; t < 256; ++t) {
            int e = (w[2 * t] >> 7) & 0xFF;
            if (e >= 100 && e <= 135) ++sane;
        }
        *flag = (sane >= 192) ? 1 : 0;   // 1 = bf16, 0 = fp32
    }
}

// ---------------- prepack W into MFMA fragment layout ----------------
// wpk[((z*32 + ks)*16 + 2*t + plane)*64 + lane] : u32x4
__global__ __launch_bounds__(256) void prepack_w_kernel(
    const void* __restrict__ wq, const void* __restrict__ wk, const void* __restrict__ wv,
    const int* __restrict__ flag, u32x4* __restrict__ wpk)
{
    const int isb = *flag;
    const int gid = blockIdx.x * 256 + threadIdx.x;
    const int l  = gid & 63;
    const int t  = (gid >> 6) & 7;
    const int ks = (gid >> 9) & 31;
    const int z  = gid >> 14;
    const void* W = (z == 0) ? wq : (z == 1) ? wk : wv;
    const int row = 16 * t + (l & 15);
    const int k0  = ks * 32 + 8 * (l >> 4);
    float f[8];
    ld8(W, (size_t)row * DM + k0, isb, f);
    u32x4 hi, lo;
    split8(f, hi, lo);
    const size_t base = ((((size_t)z * 32 + ks) * 16) + 2 * t) * 64 + l;
    wpk[base]      = hi;
    wpk[base + 64] = lo;
}

// ---------------- MFMA QKV: prepacked W + global_load_lds + XCD swizzle ----------------
__global__ __launch_bounds__(256) void qkv_kernel(
    const void* __restrict__ x, const u32x4* __restrict__ wpk,
    const int* __restrict__ flag, u32* __restrict__ qkv)
{
    const int isb = *flag;
    const int z = blockIdx.z;
    u32* out = qkv + (size_t)z * ((size_t)BS_ * DH);
    // XCD swizzle (bijective on [0,256)): consecutive x-tiles stay on one XCD
    const int bx = blockIdx.x;
    const int m0 = ((bx & 7) * 32 + (bx >> 3)) * 64;
    const int tid = threadIdx.x;
    const int wave = tid >> 6, lane = tid & 63;
    const int qd = lane >> 4, c = lane & 15;

    __shared__ u32x4 WL[2][8][2][64];   // [buf][colTile][hi/lo][lane] 32 KB

    const u32x4* wz = wpk + (size_t)z * (32 * 16 * 64);
    const size_t arow = (size_t)(m0 + wave * 16 + c) * DM + 8 * qd;

#define STAGE_W(ks_, b_)                                                          \
    {                                                                             \
        const u32x4* _src = wz + ((size_t)(ks_) * 16 + 4 * wave) * 64 + lane;     \
        _Pragma("unroll")                                                         \
        for (int _j = 0; _j < 4; ++_j) {                                          \
            __builtin_amdgcn_global_load_lds(                                     \
                (const __attribute__((address_space(1))) u32*)(_src + _j * 64),   \
                (__attribute__((address_space(3))) u32*)&WL[b_][2 * wave + (_j >> 1)][_j & 1][0], \
                16, 0, 0);                                                        \
        }                                                                         \
    }

    float Ar[8], Arn[8];
    ld8(x, arow, isb, Ar);
    STAGE_W(0, 0);
    ld8(x, arow + 32, isb, Arn);
    __syncthreads();

    f32x4 acc[8] = {};

    for (int ks = 0; ks < 32; ++ks) {
        const int cb = ks & 1;
        if (ks + 1 < 32) STAGE_W(ks + 1, cb ^ 1);

        H8 Ah, Al;
        split8(Ar, Ah.v, Al.v);
#pragma unroll
        for (int t = 0; t < 8; ++t) {
            H8 bh, bl;
            bh.v = WL[cb][t][0][lane]; bl.v = WL[cb][t][1][lane];
            acc[t] = __builtin_amdgcn_mfma_f32_16x16x32_f16(Al.h, bh.h, acc[t], 0, 0, 0);
            acc[t] = __builtin_amdgcn_mfma_f32_16x16x32_f16(Ah.h, bl.h, acc[t], 0, 0, 0);
            acc[t] = __builtin_amdgcn_mfma_f32_16x16x32_f16(Ah.h, bh.h, acc[t], 0, 0, 0);
        }
#pragma unroll
        for (int j = 0; j < 8; ++j) Ar[j] = Arn[j];
        if (ks + 2 < 32) ld8(x, arow + (size_t)(ks + 2) * 32, isb, Arn);
        __syncthreads();
    }
#undef STAGE_W

#pragma unroll
    for (int r = 0; r < 4; ++r) {
        const int row = m0 + wave * 16 + qd * 4 + r;
        u32* op = out + (size_t)row * DH + c;
#pragma unroll
        for (int t = 0; t < 8; ++t) op[t * 16] = f2pk(acc[t][r]);
    }
}

// ---------------- attention core (shared by both variants) ----------------
template <bool WRITE_PARTIAL>
__device__ __forceinline__ void attn_body(
    const u32* qp, const u32* __restrict__ kp, const u32* __restrict__ vp,
    float* outO, float* outL, float* cur,
    int b, int q0, int kt0, int kt1, int part)
{
    const int tid = threadIdx.x;
    const int wave = tid >> 6, lane = tid & 63;
    const int qd = lane >> 4, c = lane & 15;

    __shared__ u32x4 KF[2][2][2][4][64];  // [buf][plane][tile][ks][lane] 32 KB
    __shared__ u32x4 VF[2][2][8][64];     // [buf][plane][t][lane]       32 KB
    __shared__ u32   PB[4][531];          // per-wave P, elem-packed, stride 33

    H8 Qh[4], Ql[4];
    {
        const u32* qr = qp + ((size_t)b * S_ + q0 + wave * 16 + c) * DH;
#pragma unroll
        for (int ks = 0; ks < 4; ++ks) {
            uint4 e0 = *(const uint4*)(qr + ks * 32 + qd * 8);
            uint4 e1 = *(const uint4*)(qr + ks * 32 + qd * 8 + 4);
            Qh[ks].u[0] = permHI(e0.y, e0.x); Qh[ks].u[1] = permHI(e0.w, e0.z);
            Qh[ks].u[2] = permHI(e1.y, e1.x); Qh[ks].u[3] = permHI(e1.w, e1.z);
            Ql[ks].u[0] = permLO(e0.y, e0.x); Ql[ks].u[1] = permLO(e0.w, e0.z);
            Ql[ks].u[2] = permLO(e1.y, e1.x); Ql[ks].u[3] = permLO(e1.w, e1.z);
        }
    }

    const int kKey = tid & 31, kD0 = (tid >> 5) * 16;
    const int vD = tid >> 1, vKg = (tid & 1) * 16;
    const int tK = (tid >> 4) & 1, cK = tid & 15;
    const int tV = tid >> 5,      cV = (tid >> 1) & 15;

    uint4 Kst[4]; u32 Vst[16];

    auto loadKV = [&](int kb) {
        const u32* kr = kp + ((size_t)b * S_ + kb * 32 + kKey) * DH + kD0;
#pragma unroll
        for (int j = 0; j < 4; ++j) Kst[j] = *(const uint4*)(kr + 4 * j);
        const u32* vc = vp + ((size_t)b * S_ + kb * 32 + vKg) * DH + vD;
#pragma unroll
        for (int j = 0; j < 16; ++j) Vst[j] = vc[(size_t)j * DH];
    };
    auto writeKV = [&](int wb) {
#pragma unroll
        for (int g = 0; g < 2; ++g) {
            const int dg = kD0 + 8 * g, ksK = dg >> 5, qK = (dg >> 3) & 3;
            KF[wb][0][tK][ksK][qK * 16 + cK] = (u32x4){
                permHI(Kst[2*g].y, Kst[2*g].x), permHI(Kst[2*g].w, Kst[2*g].z),
                permHI(Kst[2*g+1].y, Kst[2*g+1].x), permHI(Kst[2*g+1].w, Kst[2*g+1].z)};
            KF[wb][1][tK][ksK][qK * 16 + cK] = (u32x4){
                permLO(Kst[2*g].y, Kst[2*g].x), permLO(Kst[2*g].w, Kst[2*g].z),
                permLO(Kst[2*g+1].y, Kst[2*g+1].x), permLO(Kst[2*g+1].w, Kst[2*g+1].z)};
        }
#pragma unroll
        for (int g = 0; g < 2; ++g) {
            const int qV = 2 * (tid & 1) + g;
            VF[wb][0][tV][qV * 16 + cV] = (u32x4){
                permHI(Vst[8*g+1], Vst[8*g+0]), permHI(Vst[8*g+3], Vst[8*g+2]),
                permHI(Vst[8*g+5], Vst[8*g+4]), permHI(Vst[8*g+7], Vst[8*g+6])};
            VF[wb][1][tV][qV * 16 + cV] = (u32x4){
                permLO(Vst[8*g+1], Vst[8*g+0]), permLO(Vst[8*g+3], Vst[8*g+2]),
                permLO(Vst[8*g+5], Vst[8*g+4]), permLO(Vst[8*g+7], Vst[8*g+6])};
        }
    };

    loadKV(kt0);
    writeKV(0);
    if (kt0 + 1 < kt1) loadKV(kt0 + 1);
    __syncthreads();

    f32x4 O[8] = {};
    float lsum[4] = {};

    for (int kt = kt0; kt < kt1; ++kt) {
        const int cb = (kt - kt0) & 1;

        f32x4 S0 = {}, S1 = {};
#pragma unroll
        for (int ks = 0; ks < 4; ++ks) {
            H8 kh, kl;
            kh.v = KF[cb][0][0][ks][lane]; kl.v = KF[cb][1][0][ks][lane];
            S0 = __builtin_amdgcn_mfma_f32_16x16x32_f16(Ql[ks].h, kh.h, S0, 0, 0, 0);
            S0 = __builtin_amdgcn_mfma_f32_16x16x32_f16(Qh[ks].h, kl.h, S0, 0, 0, 0);
            S0 = __builtin_amdgcn_mfma_f32_16x16x32_f16(Qh[ks].h, kh.h, S0, 0, 0, 0);
            kh.v = KF[cb][0][1][ks][lane]; kl.v = KF[cb][1][1][ks][lane];
            S1 = __builtin_amdgcn_mfma_f32_16x16x32_f16(Ql[ks].h, kh.h, S1, 0, 0, 0);
            S1 = __builtin_amdgcn_mfma_f32_16x16x32_f16(Qh[ks].h, kl.h, S1, 0, 0, 0);
            S1 = __builtin_amdgcn_mfma_f32_16x16x32_f16(Qh[ks].h, kh.h, S1, 0, 0, 0);
        }

        u32* pw = PB[wave];
#pragma unroll
        for (int r = 0; r < 4; ++r) {
            float e0 = exp2f(fmaf(S0[r], SCALE2_, -4.0f));
            float e1 = exp2f(fmaf(S1[r], SCALE2_, -4.0f));
            lsum[r] += e0 + e1;
            pw[(4 * qd + r) * 33 + c]      = f2pk(e0);
            pw[(4 * qd + r) * 33 + 16 + c] = f2pk(e1);
        }

        u32 e[8];
#pragma unroll
        for (int j = 0; j < 8; ++j) e[j] = pw[c * 33 + 8 * qd + j];
        H8 Ph, Pl;
        Ph.u[0] = permHI(e[1], e[0]); Ph.u[1] = permHI(e[3], e[2]);
        Ph.u[2] = permHI(e[5], e[4]); Ph.u[3] = permHI(e[7], e[6]);
        Pl.u[0] = permLO(e[1], e[0]); Pl.u[1] = permLO(e[3], e[2]);
        Pl.u[2] = permLO(e[5], e[4]); Pl.u[3] = permLO(e[7], e[6]);

#pragma unroll
        for (int t = 0; t < 8; ++t) {
            H8 vh, vl;
            vh.v = VF[cb][0][t][lane]; vl.v = VF[cb][1][t][lane];
            O[t] = __builtin_amdgcn_mfma_f32_16x16x32_f16(Pl.h, vh.h, O[t], 0, 0, 0);
            O[t] = __builtin_amdgcn_mfma_f32_16x16x32_f16(Ph.h, vl.h, O[t], 0, 0, 0);
            O[t] = __builtin_amdgcn_mfma_f32_16x16x32_f16(Ph.h, vh.h, O[t], 0, 0, 0);
        }

        if (kt + 1 < kt1) {
            writeKV((kt + 1 - kt0) & 1);
            if (kt + 2 < kt1) loadKV(kt + 2);
        }
        __syncthreads();
    }

    if (WRITE_PARTIAL) {
        float lred[4];
#pragma unroll
        for (int r = 0; r < 4; ++r) {
            float l = lsum[r];
            l += __shfl_xor(l, 1); l += __shfl_xor(l, 2);
            l += __shfl_xor(l, 4); l += __shfl_xor(l, 8);
            lred[r] = l;
        }
        const size_t rb = (size_t)b * S_ + q0 + wave * 16 + 4 * qd;
        float* Op = outO + (size_t)part * ((size_t)BS_ * DH);
#pragma unroll
        for (int t = 0; t < 8; ++t)
#pragma unroll
            for (int r = 0; r < 4; ++r)
                Op[(rb + r) * DH + t * 16 + c] = O[t][r];
        if (c == 0) {
            float* lp = outL + (size_t)part * BS_;
#pragma unroll
            for (int r = 0; r < 4; ++r) lp[rb + r] = lred[r];
        }
    } else {
        float linv[4];
#pragma unroll
        for (int r = 0; r < 4; ++r) {
            float l = lsum[r];
            l += __shfl_xor(l, 1); l += __shfl_xor(l, 2);
            l += __shfl_xor(l, 4); l += __shfl_xor(l, 8);
            linv[r] = 1.0f / l;
        }
        const size_t rb = (size_t)b * S_ + q0 + wave * 16 + 4 * qd;
#pragma unroll
        for (int t = 0; t < 8; ++t)
#pragma unroll
            for (int r = 0; r < 4; ++r)
                cur[(rb + r) * DH + t * 16 + c] = O[t][r] * linv[r];
    }
}

// single-pass fallback: grid (32, 8). XCD swizzle: batch = rid&7 (bijective).
__global__ __launch_bounds__(256) void attn_kernel(
    const u32* qp, const u32* __restrict__ kp, const u32* __restrict__ vp, float* cur)
{
    const int rid = blockIdx.x + 32 * blockIdx.y;
    attn_body<false>(qp, kp, vp, nullptr, nullptr, cur,
                     rid & 7, ((rid >> 3) & 31) * 64, 0, S_ / 32, 0);
}

// split-KV x2: grid (32, 8, 2). XCD swizzle: batch = rid&7 -> Q/K/V of one batch per XCD L2.
__global__ __launch_bounds__(256) void attn_split_kernel(
    const u32* qp, const u32* __restrict__ kp, const u32* __restrict__ vp,
    float* __restrict__ Opart, float* __restrict__ lpart)
{
    const int rid = blockIdx.x + 32 * (blockIdx.y + 8 * blockIdx.z);
    const int b    = rid & 7;
    const int qx   = (rid >> 3) & 31;
    const int part = rid >> 8;
    const int half = S_ / 64;   // 32 tiles per part
    attn_body<true>(qp, kp, vp, Opart, lpart, nullptr,
                    b, qx * 64, part * half, (part + 1) * half, part);
}

// combine: cur0 = (Oa + Ob) / (la + lb). grid 512 x 256, 16 elems/thread.
__global__ __launch_bounds__(256) void combine_kernel(
    const float* __restrict__ Opart, const float* __restrict__ lpart,
    float* __restrict__ cur)
{
    const size_t N1 = (size_t)BS_ * DH;
    const size_t i0 = ((size_t)blockIdx.x * 256 + threadIdx.x) * 16;
    const int row = (int)(i0 >> 7);
    const float linv = 1.0f / (lpart[row] + lpart[BS_ + row]);
#pragma unroll
    for (int t = 0; t < 4; ++t) {
        float4 a = *(const float4*)(Opart + i0 + t * 4);
        float4 b = *(const float4*)(Opart + N1 + i0 + t * 4);
        *(float4*)(cur + i0 + t * 4) = make_float4(
            (a.x + b.x) * linv, (a.y + b.y) * linv,
            (a.z + b.z) * linv, (a.w + b.w) * linv);
    }
}

// ---------------- one dialectic round: 64 tokens/block ----------------
__global__ __launch_bounds__(256) void round_kernel(
    const float* cur0, const float* curr,
    const void* __restrict__ tw, const void* __restrict__ tb, const void* __restrict__ ab,
    const void* __restrict__ w1, const void* __restrict__ b1,
    const void* __restrict__ w2, const void* __restrict__ b2,
    const void* __restrict__ gw, const void* __restrict__ gb,
    const int* __restrict__ flag, int* active, int* counts, int r,
    float* cur_out, void* dout)
{
    const int isb = *flag;
    const int tok0 = blockIdx.x * 64;
    const int tid = threadIdx.x;
    const bool last = (dout != nullptr);

    if (counts[r] <= 0) {
        if (last) {
            for (int e = tid; e < 64 * DH; e += 256) {
                size_t idx = (size_t)tok0 * DH + e;
                float v = curr[idx];
                if (isb) ((__hip_bfloat16*)dout)[idx] = __float2bfloat16(v);
                else     ((float*)dout)[idx] = v;
            }
        }
        return;
    }

    __shared__ float As[32][65];
    __shared__ float Ws[32][129];
    __shared__ float HS[128 * 65];
    __shared__ float actS[64], tbS[128], abS[128], b1S[128], b2S[128], gwS[256];
    __shared__ int blkcnt;

    if (tid < 64) actS[tid] = active[tok0 + tid] ? 1.0f : 0.0f;
    if (tid < 128) {
        tbS[tid] = ldE(tb, tid, isb); abS[tid] = ldE(ab, tid, isb);
        b1S[tid] = ldE(b1, tid, isb); b2S[tid] = ldE(b2, tid, isb);
    }
    gwS[tid] = ldE(gw, tid, isb);
    if (tid == 0) blkcnt = 0;
    const float gbf = ldE(gb, 0, isb);
    __syncthreads();

    const int tm = (tid & 15) * 4, tn = (tid >> 4) * 8;
    const int ar = tid >> 2, ac4 = (tid & 3) * 8;
    const int bn = tid >> 1, bc = (tid & 1) * 16;

    // ---- t0 = cur0_tile @ tw^T ----
    {
        float acc[4][8] = {};
        for (int s = 0; s < 4; ++s) {
            const int k0 = s * 32;
            float4 a0 = *(const float4*)(cur0 + (size_t)(tok0 + ar) * DH + k0 + ac4);
            float4 a1 = *(const float4*)(cur0 + (size_t)(tok0 + ar) * DH + k0 + ac4 + 4);
            float bf0[8], bf1[8];
            ld8(tw, (size_t)bn * DH + k0 + bc, isb, bf0);
            ld8(tw, (size_t)bn * DH + k0 + bc + 8, isb, bf1);
            __syncthreads();
            As[ac4 + 0][ar] = a0.x; As[ac4 + 1][ar] = a0.y; As[ac4 + 2][ar] = a0.z; As[ac4 + 3][ar] = a0.w;
            As[ac4 + 4][ar] = a1.x; As[ac4 + 5][ar] = a1.y; As[ac4 + 6][ar] = a1.z; As[ac4 + 7][ar] = a1.w;
#pragma unroll
            for (int j = 0; j < 8; ++j) { Ws[bc + j][bn] = bf0[j]; Ws[bc + 8 + j][bn] = bf1[j]; }
            __syncthreads();
#pragma unroll 8
            for (int kk = 0; kk < 32; ++kk) {
                float a0v = As[kk][tm], a1v = As[kk][tm + 1], a2v = As[kk][tm + 2], a3v = As[kk][tm + 3];
#pragma unroll
                for (int j = 0; j < 8; ++j) {
                    float bb = Ws[kk][tn + j];
                    acc[0][j] += a0v * bb; acc[1][j] += a1v * bb;
                    acc[2][j] += a2v * bb; acc[3][j] += a3v * bb;
                }
            }
        }
#pragma unroll
        for (int i = 0; i < 4; ++i)
#pragma unroll
            for (int j = 0; j < 8; ++j)
                HS[(tm + i) * 129 + (tn + j)] = acc[i][j];
        __syncthreads();
    }

    // ---- layer 1: h = relu([at,aa,ac] @ w1^T + b1) ----
    float acc1[4][8] = {};
    for (int s = 0; s < 12; ++s) {
        const int k0 = s * 32;
        const int col0 = (s & 3) * 32;
        const float am = actS[ar];
        float av[8];
        if (s < 4) {
#pragma unroll
            for (int j = 0; j < 8; ++j) {
                int cc = col0 + ac4 + j;
                av[j] = (HS[ar * 129 + cc] + tbS[cc]) * am;
            }
        } else if (s < 8) {
#pragma unroll
            for (int j = 0; j < 8; ++j) {
                int cc = col0 + ac4 + j;
                av[j] = (abS[cc] - HS[ar * 129 + cc]) * am;
            }
        } else {
            float4 a0 = *(const float4*)(curr + (size_t)(tok0 + ar) * DH + col0 + ac4);
            float4 a1 = *(const float4*)(curr + (size_t)(tok0 + ar) * DH + col0 + ac4 + 4);
            av[0] = a0.x * am; av[1] = a0.y * am; av[2] = a0.z * am; av[3] = a0.w * am;
            av[4] = a1.x * am; av[5] = a1.y * am; av[6] = a1.z * am; av[7] = a1.w * am;
        }
        float bf0[8], bf1[8];
        ld8(w1, (size_t)bn * 384 + k0 + bc, isb, bf0);
        ld8(w1, (size_t)bn * 384 + k0 + bc + 8, isb, bf1);
        __syncthreads();
#pragma unroll
        for (int j = 0; j < 8; ++j) As[ac4 + j][ar] = av[j];
#pragma unroll
        for (int j = 0; j < 8; ++j) { Ws[bc + j][bn] = bf0[j]; Ws[bc + 8 + j][bn] = bf1[j]; }
        __syncthreads();
#pragma unroll 8
        for (int kk = 0; kk < 32; ++kk) {
            float a0v = As[kk][tm], a1v = As[kk][tm + 1], a2v = As[kk][tm + 2], a3v = As[kk][tm + 3];
#pragma unroll
            for (int j = 0; j < 8; ++j) {
                float bb = Ws[kk][tn + j];
                acc1[0][j] += a0v * bb; acc1[1][j] += a1v * bb;
                acc1[2][j] += a2v * bb; acc1[3][j] += a3v * bb;
            }
        }
    }
#pragma unroll
    for (int i = 0; i < 4; ++i)
#pragma unroll
        for (int j = 0; j < 8; ++j)
            HS[(tn + j) * 65 + (tm + i)] = fmaxf(acc1[i][j] + b1S[tn + j], 0.0f);

    // ---- layer 2 ----
    float acc2[4][8] = {};
    for (int s = 0; s < 4; ++s) {
        const int k0 = s * 32;
        float bf0[8], bf1[8];
        ld8(w2, (size_t)bn * DH + k0 + bc, isb, bf0);
        ld8(w2, (size_t)bn * DH + k0 + bc + 8, isb, bf1);
        __syncthreads();
#pragma unroll
        for (int j = 0; j < 8; ++j) { Ws[bc + j][bn] = bf0[j]; Ws[bc + 8 + j][bn] = bf1[j]; }
        __syncthreads();
#pragma unroll 8
        for (int kk = 0; kk < 32; ++kk) {
            float a0v = HS[(k0 + kk) * 65 + tm];
            float a1v = HS[(k0 + kk) * 65 + tm + 1];
            float a2v = HS[(k0 + kk) * 65 + tm + 2];
            float a3v = HS[(k0 + kk) * 65 + tm + 3];
#pragma unroll
            for (int j = 0; j < 8; ++j) {
                float bb = Ws[kk][tn + j];
                acc2[0][j] += a0v * bb; acc2[1][j] += a1v * bb;
                acc2[2][j] += a2v * bb; acc2[3][j] += a3v * bb;
            }
        }
    }
    __syncthreads();
#pragma unroll
    for (int i = 0; i < 4; ++i)
#pragma unroll
        for (int j = 0; j < 8; ++j)
            HS[(tm + i) * 129 + (tn + j)] = acc2[i][j] + b2S[tn + j];
    __syncthreads();

    // ---- gate, update, norm, active ----
    const int tok = tid >> 2, d0 = (tid & 3) * 32;
    const float am = actS[tok];
    const float* cp = curr + (size_t)(tok0 + tok) * DH + d0;
    float cv[32];
#pragma unroll
    for (int t = 0; t < 8; ++t) {
        float4 vv = *(const float4*)(cp + t * 4);
        cv[t * 4] = vv.x; cv[t * 4 + 1] = vv.y; cv[t * 4 + 2] = vv.z; cv[t * 4 + 3] = vv.w;
    }
    const float* srow = HS + tok * 129 + d0;
    float gp = 0.0f;
#pragma unroll
    for (int e = 0; e < 32; ++e)
        gp += cv[e] * am * gwS[d0 + e] + srow[e] * gwS[128 + d0 + e];
    gp += __shfl_xor(gp, 1, 4);
    gp += __shfl_xor(gp, 2, 4);
    const float gate = 1.0f / (1.0f + __expf(-(gp + gbf)));
    float ss = 0.0f; float up[32];
#pragma unroll
    for (int e = 0; e < 32; ++e) {
        float u = gate * (srow[e] - cv[e] * am) * 0.1f;
        up[e] = u; ss += u * u;
    }
    ss += __shfl_xor(ss, 1, 4);
    ss += __shfl_xor(ss, 2, 4);
    const bool stable = sqrtf(ss) < 0.1f;

    if (last) {
        size_t off = (size_t)(tok0 + tok) * DH + d0;
        if (isb) {
            __hip_bfloat16* op = (__hip_bfloat16*)dout + off;
#pragma unroll
            for (int e = 0; e < 32; ++e) op[e] = __float2bfloat16(cv[e] + up[e]);
        } else {
            float* op = (float*)dout + off;
#pragma unroll
            for (int t = 0; t < 8; ++t)
                *(float4*)(op + t * 4) = make_float4(cv[t * 4] + up[t * 4], cv[t * 4 + 1] + up[t * 4 + 1],
                                                     cv[t * 4 + 2] + up[t * 4 + 2], cv[t * 4 + 3] + up[t * 4 + 3]);
        }
    } else {
        float* op = cur_out + (size_t)(tok0 + tok) * DH + d0;
#pragma unroll
        for (int t = 0; t < 8; ++t)
            *(float4*)(op + t * 4) = make_float4(cv[t * 4] + up[t * 4], cv[t * 4 + 1] + up[t * 4 + 1],
                                                 cv[t * 4 + 2] + up[t * 4 + 2], cv[t * 4 + 3] + up[t * 4 + 3]);
    }
    const int newact = (am > 0.0f && !stable) ? 1 : 0;
    if ((tid & 3) == 0) {
        active[tok0 + tok] = newact;
        if (newact) atomicAdd(&blkcnt, 1);
    }
    __syncthreads();
    if (tid == 0 && blkcnt > 0) atomicAdd(&counts[r + 1], blkcnt);
}

extern "C" void kernel_launch(void* const* d_in, const int* in_sizes, int n_in,
                              void* d_out, int out_size, void* d_ws, size_t ws_size,
                              hipStream_t stream) {
    const void* x  = d_in[0];
    const void* wq = d_in[1];
    const void* wk = d_in[2];
    const void* wv = d_in[3];
    const void* tw = d_in[4];
    const void* tb = d_in[5];
    const void* ab = d_in[6];
    const void* w1 = d_in[7];
    const void* b1 = d_in[8];
    const void* w2 = d_in[9];
    const void* b2 = d_in[10];
    const void* gw = d_in[11];
    const void* gb = d_in[12];

    u32* ws = (u32*)d_ws;
    const size_t N1 = (size_t)BS_ * DH;
    // base layout (~24 MiB): qp | kp | vp | active | counts | flag
    u32* qp = ws;
    u32* kp = ws + N1;
    u32* vp = ws + 2 * N1;
    int* active = (int*)(ws + 3 * N1);
    int* counts = active + BS_;
    int* flag   = counts + 4;
    float* cur0  = (float*)qp;
    float* cur_r = (float*)kp;
    // split-KV extension (needs ~42.3 MB total):
    float* Opart = (float*)(ws + 3 * N1 + 32768);           // 2 x N1 fp32
    float* lpart = (float*)(ws + 5 * N1 + 32768);           // 2 x BS_ fp32
    const bool big_ws = ws_size >= (size_t)42300000;        // constant across calls
    // prepacked W lives in the Opart region (dead before attention writes it)
    u32x4* wpk = (u32x4*)(ws + 3 * N1 + 32768);

    init_kernel<<<dim3(BS_ / 256), 256, 0, stream>>>(x, flag, active, counts);
    prepack_w_kernel<<<dim3(192), 256, 0, stream>>>(wq, wk, wv, flag, wpk);
    qkv_kernel<<<dim3(BS_ / 64, 1, 3), 256, 0, stream>>>(x, wpk, flag, qp);
    if (big_ws) {
        attn_split_kernel<<<dim3(S_ / 64, B_, 2), 256, 0, stream>>>(qp, kp, vp, Opart, lpart);
        combine_kernel<<<dim3(512), 256, 0, stream>>>(Opart, lpart, cur0);
    } else {
        attn_kernel<<<dim3(S_ / 64, B_), 256, 0, stream>>>(qp, kp, vp, cur0);
    }
    round_kernel<<<dim3(BS_ / 64), 256, 0, stream>>>(
        cur0, cur0, tw, tb, ab, w1, b1, w2, b2, gw, gb, flag, active, counts, 0, cur_r, nullptr);
    round_kernel<<<dim3(BS_ / 64), 256, 0, stream>>>(
        cur0, cur_r, tw, tb, ab, w1, b1, w2, b2, gw, gb, flag, active, counts, 1, cur_r, nullptr);
    round_kernel<<<dim3(BS_ / 64), 256, 0, stream>>>(
        cur0, cur_r, tw, tb, ab, w1, b1, w2, b2, gw, gb, flag, active, counts, 2, cur_r, d_out);
}

// Round 6
// 331.194 us; speedup vs baseline: 1.0605x; 1.0009x over previous
//
#include <hip/hip_runtime.h>
#include <hip/hip_bf16.h>

#define B_   8
#define S_   2048
#define DM   1024
#define DH   128
#define BS_  16384
#define SCALE_  0.08838834764831845f
#define SCALE2_ 0.12751744f   // SCALE * log2(e)

typedef unsigned short u16;
typedef unsigned int   u32;
typedef _Float16 half8 __attribute__((ext_vector_type(8)));
typedef float    f32x4 __attribute__((ext_vector_type(4)));
typedef u32      u32x4 __attribute__((ext_vector_type(4)));

union H8 { u32x4 v; u32 u[4]; half8 h; };

__device__ __forceinline__ float bf2f(u16 u) {
    union { u32 i; float f; } w; w.i = ((u32)u) << 16; return w.f;
}
__device__ __forceinline__ void unpack8(uint4 v, float* f) {
    f[0] = bf2f(v.x & 0xffff); f[1] = bf2f(v.x >> 16);
    f[2] = bf2f(v.y & 0xffff); f[3] = bf2f(v.y >> 16);
    f[4] = bf2f(v.z & 0xffff); f[5] = bf2f(v.z >> 16);
    f[6] = bf2f(v.w & 0xffff); f[7] = bf2f(v.w >> 16);
}
__device__ __forceinline__ float ldE(const void* b, size_t i, int isbf16) {
    return isbf16 ? bf2f(((const u16*)b)[i]) : ((const float*)b)[i];
}
__device__ __forceinline__ void ld8(const void* b, size_t i, int isbf16, float* f) {
    if (isbf16) {
        unpack8(*(const uint4*)((const u16*)b + i), f);
    } else {
        float4 a = *(const float4*)((const float*)b + i);
        float4 c = *(const float4*)((const float*)b + i + 4);
        f[0] = a.x; f[1] = a.y; f[2] = a.z; f[3] = a.w;
        f[4] = c.x; f[5] = c.y; f[6] = c.z; f[7] = c.w;
    }
}
// fp32 -> packed (f16 hi << 16) | f16 lo  (2-term split, ~22 mantissa bits)
__device__ __forceinline__ u32 f2pk(float v) {
    _Float16 h = (_Float16)v;
    _Float16 l = (_Float16)(v - (float)h);
    union { _Float16 f; u16 u; } a, b; a.f = h; b.f = l;
    return ((u32)a.u << 16) | (u32)b.u;
}
// 8 floats -> pair-packed hi/lo frag u32x4
__device__ __forceinline__ void split8(const float* f, u32x4& hi, u32x4& lo) {
    u32 H[8], L[8];
#pragma unroll
    for (int j = 0; j < 8; ++j) {
        _Float16 h = (_Float16)f[j];
        _Float16 l = (_Float16)(f[j] - (float)h);
        union { _Float16 x; u16 u; } a, b; a.x = h; b.x = l;
        H[j] = a.u; L[j] = b.u;
    }
    hi = (u32x4){H[0] | (H[1] << 16), H[2] | (H[3] << 16), H[4] | (H[5] << 16), H[6] | (H[7] << 16)};
    lo = (u32x4){L[0] | (L[1] << 16), L[2] | (L[3] << 16), L[4] | (L[5] << 16), L[6] | (L[7] << 16)};
}
__device__ __forceinline__ u32 permHI(u32 eB, u32 eA) { return __builtin_amdgcn_perm(eB, eA, 0x07060302u); }
__device__ __forceinline__ u32 permLO(u32 eB, u32 eA) { return __builtin_amdgcn_perm(eB, eA, 0x05040100u); }
__device__ __forceinline__ u16 f2h(float v) { union { _Float16 f; u16 u; } a; a.f = (_Float16)v; return a.u; }
__device__ __forceinline__ float h2f(u16 u) { union { _Float16 f; u16 u; } a; a.u = u; return (float)a.f; }

// ---------------- init: dtype detect + active mask + round counters ----------------
__global__ void init_kernel(const void* x, int* flag, int* active, int* counts) {
    int i = blockIdx.x * 256 + threadIdx.x;
    if (i < BS_) active[i] = 1;
    if (i < 4) counts[i] = (i == 0) ? BS_ : 0;
    if (i == 0) {
        const u16* w = (const u16*)x;
        int sane = 0;
        for (int t = 0; t < 256; ++t) {
            int e = (w[2 * t] >> 7) & 0xFF;
            if (e >= 100 && e <= 135) ++sane;
        }
        *flag = (sane >= 192) ? 1 : 0;   // 1 = bf16, 0 = fp32
    }
}

// ---------------- prepack W into MFMA fragment layout ----------------
// wpk[((z*32 + ks)*16 + 2*t + plane)*64 + lane] : u32x4
__global__ __launch_bounds__(256) void prepack_w_kernel(
    const void* __restrict__ wq, const void* __restrict__ wk, const void* __restrict__ wv,
    const int* __restrict__ flag, u32x4* __restrict__ wpk)
{
    const int isb = *flag;
    const int gid = blockIdx.x * 256 + threadIdx.x;
    const int l  = gid & 63;
    const int t  = (gid >> 6) & 7;
    const int ks = (gid >> 9) & 31;
    const int z  = gid >> 14;
    const void* W = (z == 0) ? wq : (z == 1) ? wk : wv;
    const int row = 16 * t + (l & 15);
    const int k0  = ks * 32 + 8 * (l >> 4);
    float f[8];
    ld8(W, (size_t)row * DM + k0, isb, f);
    u32x4 hi, lo;
    split8(f, hi, lo);
    const size_t base = ((((size_t)z * 32 + ks) * 16) + 2 * t) * 64 + l;
    wpk[base]      = hi;
    wpk[base + 64] = lo;
}

// ---------------- MFMA QKV: prepacked W + global_load_lds + XCD swizzle ----------------
__global__ __launch_bounds__(256) void qkv_kernel(
    const void* __restrict__ x, const u32x4* __restrict__ wpk,
    const int* __restrict__ flag, u32* __restrict__ qkv)
{
    const int isb = *flag;
    const int z = blockIdx.z;
    u32* out = qkv + (size_t)z * ((size_t)BS_ * DH);
    // XCD swizzle (bijective on [0,256)): consecutive x-tiles stay on one XCD
    const int bx = blockIdx.x;
    const int m0 = ((bx & 7) * 32 + (bx >> 3)) * 64;
    const int tid = threadIdx.x;
    const int wave = tid >> 6, lane = tid & 63;
    const int qd = lane >> 4, c = lane & 15;

    __shared__ u32x4 WL[2][8][2][64];   // [buf][colTile][hi/lo][lane] 32 KB

    const u32x4* wz = wpk + (size_t)z * (32 * 16 * 64);
    const size_t arow = (size_t)(m0 + wave * 16 + c) * DM + 8 * qd;

#define STAGE_W(ks_, b_)                                                          \
    {                                                                             \
        const u32x4* _src = wz + ((size_t)(ks_) * 16 + 4 * wave) * 64 + lane;     \
        _Pragma("unroll")                                                         \
        for (int _j = 0; _j < 4; ++_j) {                                          \
            __builtin_amdgcn_global_load_lds(                                     \
                (const __attribute__((address_space(1))) u32*)(_src + _j * 64),   \
                (__attribute__((address_space(3))) u32*)&WL[b_][2 * wave + (_j >> 1)][_j & 1][0], \
                16, 0, 0);                                                        \
        }                                                                         \
    }

    float Ar[8], Arn[8];
    ld8(x, arow, isb, Ar);
    STAGE_W(0, 0);
    ld8(x, arow + 32, isb, Arn);
    __syncthreads();

    f32x4 acc[8] = {};

    for (int ks = 0; ks < 32; ++ks) {
        const int cb = ks & 1;
        if (ks + 1 < 32) STAGE_W(ks + 1, cb ^ 1);

        H8 Ah, Al;
        split8(Ar, Ah.v, Al.v);
#pragma unroll
        for (int t = 0; t < 8; ++t) {
            H8 bh, bl;
            bh.v = WL[cb][t][0][lane]; bl.v = WL[cb][t][1][lane];
            acc[t] = __builtin_amdgcn_mfma_f32_16x16x32_f16(Al.h, bh.h, acc[t], 0, 0, 0);
            acc[t] = __builtin_amdgcn_mfma_f32_16x16x32_f16(Ah.h, bl.h, acc[t], 0, 0, 0);
            acc[t] = __builtin_amdgcn_mfma_f32_16x16x32_f16(Ah.h, bh.h, acc[t], 0, 0, 0);
        }
#pragma unroll
        for (int j = 0; j < 8; ++j) Ar[j] = Arn[j];
        if (ks + 2 < 32) ld8(x, arow + (size_t)(ks + 2) * 32, isb, Arn);
        __syncthreads();
    }
#undef STAGE_W

#pragma unroll
    for (int r = 0; r < 4; ++r) {
        const int row = m0 + wave * 16 + qd * 4 + r;
        u32* op = out + (size_t)row * DH + c;
#pragma unroll
        for (int t = 0; t < 8; ++t) op[t * 16] = f2pk(acc[t][r]);
    }
}

// ---------------- attention core: hi-f16 single-plane frags ----------------
// Q/K/V stored as (hi<<16)|lo u32 pairs; attention uses hi plane only.
// LDS: KF 16KB + VF 16KB + PB 4.2KB = ~37KB -> 4 blocks/CU.
template <bool WRITE_PARTIAL>
__device__ __forceinline__ void attn_body(
    const u32* qp, const u32* __restrict__ kp, const u32* __restrict__ vp,
    u16* outO, u16* outL, float* cur,
    int b, int q0, int kt0, int kt1, int part)
{
    const int tid = threadIdx.x;
    const int wave = tid >> 6, lane = tid & 63;
    const int qd = lane >> 4, c = lane & 15;

    __shared__ u32x4 KF[2][2][4][64];  // [buf][tile][ks][lane] 16 KB
    __shared__ u32x4 VF[2][8][64];     // [buf][t][lane]        16 KB
    __shared__ u16   PB[4][531];       // per-wave P (f16), stride 33

    H8 Qh[4];
    {
        const u32* qr = qp + ((size_t)b * S_ + q0 + wave * 16 + c) * DH;
#pragma unroll
        for (int ks = 0; ks < 4; ++ks) {
            uint4 e0 = *(const uint4*)(qr + ks * 32 + qd * 8);
            uint4 e1 = *(const uint4*)(qr + ks * 32 + qd * 8 + 4);
            Qh[ks].u[0] = permHI(e0.y, e0.x); Qh[ks].u[1] = permHI(e0.w, e0.z);
            Qh[ks].u[2] = permHI(e1.y, e1.x); Qh[ks].u[3] = permHI(e1.w, e1.z);
        }
    }

    const int kKey = tid & 31, kD0 = (tid >> 5) * 16;
    const int vD = tid >> 1, vKg = (tid & 1) * 16;
    const int tK = (tid >> 4) & 1, cK = tid & 15;
    const int tV = tid >> 5,      cV = (tid >> 1) & 15;

    uint4 Kst[4]; u32 Vst[16];

    auto loadKV = [&](int kb) {
        const u32* kr = kp + ((size_t)b * S_ + kb * 32 + kKey) * DH + kD0;
#pragma unroll
        for (int j = 0; j < 4; ++j) Kst[j] = *(const uint4*)(kr + 4 * j);
        const u32* vc = vp + ((size_t)b * S_ + kb * 32 + vKg) * DH + vD;
#pragma unroll
        for (int j = 0; j < 16; ++j) Vst[j] = vc[(size_t)j * DH];
    };
    auto writeKV = [&](int wb) {
#pragma unroll
        for (int g = 0; g < 2; ++g) {
            const int dg = kD0 + 8 * g, ksK = dg >> 5, qK = (dg >> 3) & 3;
            KF[wb][tK][ksK][qK * 16 + cK] = (u32x4){
                permHI(Kst[2*g].y, Kst[2*g].x), permHI(Kst[2*g].w, Kst[2*g].z),
                permHI(Kst[2*g+1].y, Kst[2*g+1].x), permHI(Kst[2*g+1].w, Kst[2*g+1].z)};
        }
#pragma unroll
        for (int g = 0; g < 2; ++g) {
            const int qV = 2 * (tid & 1) + g;
            VF[wb][tV][qV * 16 + cV] = (u32x4){
                permHI(Vst[8*g+1], Vst[8*g+0]), permHI(Vst[8*g+3], Vst[8*g+2]),
                permHI(Vst[8*g+5], Vst[8*g+4]), permHI(Vst[8*g+7], Vst[8*g+6])};
        }
    };

    loadKV(kt0);
    writeKV(0);
    if (kt0 + 1 < kt1) loadKV(kt0 + 1);
    __syncthreads();

    f32x4 O[8] = {};
    float lsum[4] = {};

    for (int kt = kt0; kt < kt1; ++kt) {
        const int cb = (kt - kt0) & 1;

        f32x4 S0 = {}, S1 = {};
#pragma unroll
        for (int ks = 0; ks < 4; ++ks) {
            H8 kh;
            kh.v = KF[cb][0][ks][lane];
            S0 = __builtin_amdgcn_mfma_f32_16x16x32_f16(Qh[ks].h, kh.h, S0, 0, 0, 0);
            kh.v = KF[cb][1][ks][lane];
            S1 = __builtin_amdgcn_mfma_f32_16x16x32_f16(Qh[ks].h, kh.h, S1, 0, 0, 0);
        }

        u16* pw = PB[wave];
#pragma unroll
        for (int r = 0; r < 4; ++r) {
            float e0 = exp2f(fmaf(S0[r], SCALE2_, -4.0f));
            float e1 = exp2f(fmaf(S1[r], SCALE2_, -4.0f));
            lsum[r] += e0 + e1;
            pw[(4 * qd + r) * 33 + c]      = f2h(e0);
            pw[(4 * qd + r) * 33 + 16 + c] = f2h(e1);
        }

        u16 e[8];
#pragma unroll
        for (int j = 0; j < 8; ++j) e[j] = pw[c * 33 + 8 * qd + j];
        H8 Ph;
        Ph.u[0] = (u32)e[0] | ((u32)e[1] << 16);
        Ph.u[1] = (u32)e[2] | ((u32)e[3] << 16);
        Ph.u[2] = (u32)e[4] | ((u32)e[5] << 16);
        Ph.u[3] = (u32)e[6] | ((u32)e[7] << 16);

#pragma unroll
        for (int t = 0; t < 8; ++t) {
            H8 vh;
            vh.v = VF[cb][t][lane];
            O[t] = __builtin_amdgcn_mfma_f32_16x16x32_f16(Ph.h, vh.h, O[t], 0, 0, 0);
        }

        if (kt + 1 < kt1) {
            writeKV((kt + 1 - kt0) & 1);
            if (kt + 2 < kt1) loadKV(kt + 2);
        }
        __syncthreads();
    }

    if (WRITE_PARTIAL) {
        float lred[4];
#pragma unroll
        for (int r = 0; r < 4; ++r) {
            float l = lsum[r];
            l += __shfl_xor(l, 1); l += __shfl_xor(l, 2);
            l += __shfl_xor(l, 4); l += __shfl_xor(l, 8);
            lred[r] = l;
        }
        const size_t rb = (size_t)b * S_ + q0 + wave * 16 + 4 * qd;
        u16* Op = outO + (size_t)part * ((size_t)BS_ * DH);
#pragma unroll
        for (int t = 0; t < 8; ++t)
#pragma unroll
            for (int r = 0; r < 4; ++r)
                Op[(rb + r) * DH + t * 16 + c] = f2h(O[t][r]);
        if (c == 0) {
            u16* lp = outL + (size_t)part * BS_;
#pragma unroll
            for (int r = 0; r < 4; ++r) lp[rb + r] = f2h(lred[r]);
        }
    } else {
        float linv[4];
#pragma unroll
        for (int r = 0; r < 4; ++r) {
            float l = lsum[r];
            l += __shfl_xor(l, 1); l += __shfl_xor(l, 2);
            l += __shfl_xor(l, 4); l += __shfl_xor(l, 8);
            linv[r] = 1.0f / l;
        }
        const size_t rb = (size_t)b * S_ + q0 + wave * 16 + 4 * qd;
#pragma unroll
        for (int t = 0; t < 8; ++t)
#pragma unroll
            for (int r = 0; r < 4; ++r)
                cur[(rb + r) * DH + t * 16 + c] = O[t][r] * linv[r];
    }
}

// single-pass fallback: grid (32, 8). XCD swizzle: batch = rid&7 (bijective).
__global__ __launch_bounds__(256) void attn_kernel(
    const u32* qp, const u32* __restrict__ kp, const u32* __restrict__ vp, float* cur)
{
    const int rid = blockIdx.x + 32 * blockIdx.y;
    attn_body<false>(qp, kp, vp, nullptr, nullptr, cur,
                     rid & 7, ((rid >> 3) & 31) * 64, 0, S_ / 32, 0);
}

// split-KV x4: grid (32, 8, 4) = 1024 blocks (4 blocks/CU). batch = rid&7 per XCD.
__global__ __launch_bounds__(256) void attn_split_kernel(
    const u32* qp, const u32* __restrict__ kp, const u32* __restrict__ vp,
    u16* __restrict__ Opart, u16* __restrict__ lpart)
{
    const int rid = blockIdx.x + 32 * (blockIdx.y + 8 * blockIdx.z);
    const int b    = rid & 7;
    const int qx   = (rid >> 3) & 31;
    const int part = rid >> 8;
    const int quart = S_ / 128;   // 16 tiles per part
    attn_body<true>(qp, kp, vp, Opart, lpart, nullptr,
                    b, qx * 64, part * quart, (part + 1) * quart, part);
}

// combine: cur0 = sum_p O_p / sum_p l_p (f16 partials). grid 512 x 256, 16 elems/thread.
__global__ __launch_bounds__(256) void combine_kernel(
    const u16* __restrict__ Opart, const u16* __restrict__ lpart,
    float* __restrict__ cur)
{
    const size_t N1 = (size_t)BS_ * DH;
    const size_t i0 = ((size_t)blockIdx.x * 256 + threadIdx.x) * 16;
    const int row = (int)(i0 >> 7);
    const float lt = h2f(lpart[row]) + h2f(lpart[BS_ + row])
                   + h2f(lpart[2 * BS_ + row]) + h2f(lpart[3 * BS_ + row]);
    const float linv = 1.0f / lt;
    float acc[16] = {};
#pragma unroll
    for (int p = 0; p < 4; ++p) {
        const u16* op = Opart + (size_t)p * N1 + i0;
        uint4 v0 = *(const uint4*)op;
        uint4 v1 = *(const uint4*)(op + 8);
        const u32 w[8] = {v0.x, v0.y, v0.z, v0.w, v1.x, v1.y, v1.z, v1.w};
#pragma unroll
        for (int j = 0; j < 8; ++j) {
            acc[2 * j]     += h2f((u16)(w[j] & 0xffff));
            acc[2 * j + 1] += h2f((u16)(w[j] >> 16));
        }
    }
#pragma unroll
    for (int t = 0; t < 4; ++t)
        *(float4*)(cur + i0 + t * 4) = make_float4(
            acc[4*t] * linv, acc[4*t+1] * linv, acc[4*t+2] * linv, acc[4*t+3] * linv);
}

// ---------------- one dialectic round: 64 tokens/block ----------------
__global__ __launch_bounds__(256) void round_kernel(
    const float* cur0, const float* curr,
    const void* __restrict__ tw, const void* __restrict__ tb, const void* __restrict__ ab,
    const void* __restrict__ w1, const void* __restrict__ b1,
    const void* __restrict__ w2, const void* __restrict__ b2,
    const void* __restrict__ gw, const void* __restrict__ gb,
    const int* __restrict__ flag, int* active, int* counts, int r,
    float* cur_out, void* dout)
{
    const int isb = *flag;
    const int tok0 = blockIdx.x * 64;
    const int tid = threadIdx.x;
    const bool last = (dout != nullptr);

    if (counts[r] <= 0) {
        if (last) {
            for (int e = tid; e < 64 * DH; e += 256) {
                size_t idx = (size_t)tok0 * DH + e;
                float v = curr[idx];
                if (isb) ((__hip_bfloat16*)dout)[idx] = __float2bfloat16(v);
                else     ((float*)dout)[idx] = v;
            }
        }
        return;
    }

    __shared__ float As[32][65];
    __shared__ float Ws[32][129];
    __shared__ float HS[128 * 65];
    __shared__ float actS[64], tbS[128], abS[128], b1S[128], b2S[128], gwS[256];
    __shared__ int blkcnt;

    if (tid < 64) actS[tid] = active[tok0 + tid] ? 1.0f : 0.0f;
    if (tid < 128) {
        tbS[tid] = ldE(tb, tid, isb); abS[tid] = ldE(ab, tid, isb);
        b1S[tid] = ldE(b1, tid, isb); b2S[tid] = ldE(b2, tid, isb);
    }
    gwS[tid] = ldE(gw, tid, isb);
    if (tid == 0) blkcnt = 0;
    const float gbf = ldE(gb, 0, isb);
    __syncthreads();

    const int tm = (tid & 15) * 4, tn = (tid >> 4) * 8;
    const int ar = tid >> 2, ac4 = (tid & 3) * 8;
    const int bn = tid >> 1, bc = (tid & 1) * 16;

    // ---- t0 = cur0_tile @ tw^T ----
    {
        float acc[4][8] = {};
        for (int s = 0; s < 4; ++s) {
            const int k0 = s * 32;
            float4 a0 = *(const float4*)(cur0 + (size_t)(tok0 + ar) * DH + k0 + ac4);
            float4 a1 = *(const float4*)(cur0 + (size_t)(tok0 + ar) * DH + k0 + ac4 + 4);
            float bf0[8], bf1[8];
            ld8(tw, (size_t)bn * DH + k0 + bc, isb, bf0);
            ld8(tw, (size_t)bn * DH + k0 + bc + 8, isb, bf1);
            __syncthreads();
            As[ac4 + 0][ar] = a0.x; As[ac4 + 1][ar] = a0.y; As[ac4 + 2][ar] = a0.z; As[ac4 + 3][ar] = a0.w;
            As[ac4 + 4][ar] = a1.x; As[ac4 + 5][ar] = a1.y; As[ac4 + 6][ar] = a1.z; As[ac4 + 7][ar] = a1.w;
#pragma unroll
            for (int j = 0; j < 8; ++j) { Ws[bc + j][bn] = bf0[j]; Ws[bc + 8 + j][bn] = bf1[j]; }
            __syncthreads();
#pragma unroll 8
            for (int kk = 0; kk < 32; ++kk) {
                float a0v = As[kk][tm], a1v = As[kk][tm + 1], a2v = As[kk][tm + 2], a3v = As[kk][tm + 3];
#pragma unroll
                for (int j = 0; j < 8; ++j) {
                    float bb = Ws[kk][tn + j];
                    acc[0][j] += a0v * bb; acc[1][j] += a1v * bb;
                    acc[2][j] += a2v * bb; acc[3][j] += a3v * bb;
                }
            }
        }
#pragma unroll
        for (int i = 0; i < 4; ++i)
#pragma unroll
            for (int j = 0; j < 8; ++j)
                HS[(tm + i) * 129 + (tn + j)] = acc[i][j];
        __syncthreads();
    }

    // ---- layer 1: h = relu([at,aa,ac] @ w1^T + b1) ----
    float acc1[4][8] = {};
    for (int s = 0; s < 12; ++s) {
        const int k0 = s * 32;
        const int col0 = (s & 3) * 32;
        const float am = actS[ar];
        float av[8];
        if (s < 4) {
#pragma unroll
            for (int j = 0; j < 8; ++j) {
                int cc = col0 + ac4 + j;
                av[j] = (HS[ar * 129 + cc] + tbS[cc]) * am;
            }
        } else if (s < 8) {
#pragma unroll
            for (int j = 0; j < 8; ++j) {
                int cc = col0 + ac4 + j;
                av[j] = (abS[cc] - HS[ar * 129 + cc]) * am;
            }
        } else {
            float4 a0 = *(const float4*)(curr + (size_t)(tok0 + ar) * DH + col0 + ac4);
            float4 a1 = *(const float4*)(curr + (size_t)(tok0 + ar) * DH + col0 + ac4 + 4);
            av[0] = a0.x * am; av[1] = a0.y * am; av[2] = a0.z * am; av[3] = a0.w * am;
            av[4] = a1.x * am; av[5] = a1.y * am; av[6] = a1.z * am; av[7] = a1.w * am;
        }
        float bf0[8], bf1[8];
        ld8(w1, (size_t)bn * 384 + k0 + bc, isb, bf0);
        ld8(w1, (size_t)bn * 384 + k0 + bc + 8, isb, bf1);
        __syncthreads();
#pragma unroll
        for (int j = 0; j < 8; ++j) As[ac4 + j][ar] = av[j];
#pragma unroll
        for (int j = 0; j < 8; ++j) { Ws[bc + j][bn] = bf0[j]; Ws[bc + 8 + j][bn] = bf1[j]; }
        __syncthreads();
#pragma unroll 8
        for (int kk = 0; kk < 32; ++kk) {
            float a0v = As[kk][tm], a1v = As[kk][tm + 1], a2v = As[kk][tm + 2], a3v = As[kk][tm + 3];
#pragma unroll
            for (int j = 0; j < 8; ++j) {
                float bb = Ws[kk][tn + j];
                acc1[0][j] += a0v * bb; acc1[1][j] += a1v * bb;
                acc1[2][j] += a2v * bb; acc1[3][j] += a3v * bb;
            }
        }
    }
#pragma unroll
    for (int i = 0; i < 4; ++i)
#pragma unroll
        for (int j = 0; j < 8; ++j)
            HS[(tn + j) * 65 + (tm + i)] = fmaxf(acc1[i][j] + b1S[tn + j], 0.0f);

    // ---- layer 2 ----
    float acc2[4][8] = {};
    for (int s = 0; s < 4; ++s) {
        const int k0 = s * 32;
        float bf0[8], bf1[8];
        ld8(w2, (size_t)bn * DH + k0 + bc, isb, bf0);
        ld8(w2, (size_t)bn * DH + k0 + bc + 8, isb, bf1);
        __syncthreads();
#pragma unroll
        for (int j = 0; j < 8; ++j) { Ws[bc + j][bn] = bf0[j]; Ws[bc + 8 + j][bn] = bf1[j]; }
        __syncthreads();
#pragma unroll 8
        for (int kk = 0; kk < 32; ++kk) {
            float a0v = HS[(k0 + kk) * 65 + tm];
            float a1v = HS[(k0 + kk) * 65 + tm + 1];
            float a2v = HS[(k0 + kk) * 65 + tm + 2];
            float a3v = HS[(k0 + kk) * 65 + tm + 3];
#pragma unroll
            for (int j = 0; j < 8; ++j) {
                float bb = Ws[kk][tn + j];
                acc2[0][j] += a0v * bb; acc2[1][j] += a1v * bb;
                acc2[2][j] += a2v * bb; acc2[3][j] += a3v * bb;
            }
        }
    }
    __syncthreads();
#pragma unroll
    for (int i = 0; i < 4; ++i)
#pragma unroll
        for (int j = 0; j < 8; ++j)
            HS[(tm + i) * 129 + (tn + j)] = acc2[i][j] + b2S[tn + j];
    __syncthreads();

    // ---- gate, update, norm, active ----
    const int tok = tid >> 2, d0 = (tid & 3) * 32;
    const float am = actS[tok];
    const float* cp = curr + (size_t)(tok0 + tok) * DH + d0;
    float cv[32];
#pragma unroll
    for (int t = 0; t < 8; ++t) {
        float4 vv = *(const float4*)(cp + t * 4);
        cv[t * 4] = vv.x; cv[t * 4 + 1] = vv.y; cv[t * 4 + 2] = vv.z; cv[t * 4 + 3] = vv.w;
    }
    const float* srow = HS + tok * 129 + d0;
    float gp = 0.0f;
#pragma unroll
    for (int e = 0; e < 32; ++e)
        gp += cv[e] * am * gwS[d0 + e] + srow[e] * gwS[128 + d0 + e];
    gp += __shfl_xor(gp, 1, 4);
    gp += __shfl_xor(gp, 2, 4);
    const float gate = 1.0f / (1.0f + __expf(-(gp + gbf)));
    float ss = 0.0f; float up[32];
#pragma unroll
    for (int e = 0; e < 32; ++e) {
        float u = gate * (srow[e] - cv[e] * am) * 0.1f;
        up[e] = u; ss += u * u;
    }
    ss += __shfl_xor(ss, 1, 4);
    ss += __shfl_xor(ss, 2, 4);
    const bool stable = sqrtf(ss) < 0.1f;

    if (last) {
        size_t off = (size_t)(tok0 + tok) * DH + d0;
        if (isb) {
            __hip_bfloat16* op = (__hip_bfloat16*)dout + off;
#pragma unroll
            for (int e = 0; e < 32; ++e) op[e] = __float2bfloat16(cv[e] + up[e]);
        } else {
            float* op = (float*)dout + off;
#pragma unroll
            for (int t = 0; t < 8; ++t)
                *(float4*)(op + t * 4) = make_float4(cv[t * 4] + up[t * 4], cv[t * 4 + 1] + up[t * 4 + 1],
                                                     cv[t * 4 + 2] + up[t * 4 + 2], cv[t * 4 + 3] + up[t * 4 + 3]);
        }
    } else {
        float* op = cur_out + (size_t)(tok0 + tok) * DH + d0;
#pragma unroll
        for (int t = 0; t < 8; ++t)
            *(float4*)(op + t * 4) = make_float4(cv[t * 4] + up[t * 4], cv[t * 4 + 1] + up[t * 4 + 1],
                                                 cv[t * 4 + 2] + up[t * 4 + 2], cv[t * 4 + 3] + up[t * 4 + 3]);
    }
    const int newact = (am > 0.0f && !stable) ? 1 : 0;
    if ((tid & 3) == 0) {
        active[tok0 + tok] = newact;
        if (newact) atomicAdd(&blkcnt, 1);
    }
    __syncthreads();
    if (tid == 0 && blkcnt > 0) atomicAdd(&counts[r + 1], blkcnt);
}

extern "C" void kernel_launch(void* const* d_in, const int* in_sizes, int n_in,
                              void* d_out, int out_size, void* d_ws, size_t ws_size,
                              hipStream_t stream) {
    const void* x  = d_in[0];
    const void* wq = d_in[1];
    const void* wk = d_in[2];
    const void* wv = d_in[3];
    const void* tw = d_in[4];
    const void* tb = d_in[5];
    const void* ab = d_in[6];
    const void* w1 = d_in[7];
    const void* b1 = d_in[8];
    const void* w2 = d_in[9];
    const void* b2 = d_in[10];
    const void* gw = d_in[11];
    const void* gb = d_in[12];

    u32* ws = (u32*)d_ws;
    const size_t N1 = (size_t)BS_ * DH;
    // base layout (~24 MiB): qp | kp | vp | active | counts | flag
    u32* qp = ws;
    u32* kp = ws + N1;
    u32* vp = ws + 2 * N1;
    int* active = (int*)(ws + 3 * N1);
    int* counts = active + BS_;
    int* flag   = counts + 4;
    float* cur0  = (float*)qp;
    float* cur_r = (float*)kp;
    // split-KV x4 extension (f16 partials):
    //   Opart16: 4 x N1 u16 (16 MB) at ws+3N1+32768; lpart16: 4 x BS u16 after it.
    //   End = (5N1 + 32768)*4 + 131072 B = 42.2 MB <= 42.3 MB guarantee.
    u16* Opart16 = (u16*)(ws + 3 * N1 + 32768);
    u16* lpart16 = (u16*)(ws + 5 * N1 + 32768);
    const bool big_ws = ws_size >= (size_t)42300000;        // constant across calls
    // prepacked W lives in the Opart region (dead before attention writes it)
    u32x4* wpk = (u32x4*)(ws + 3 * N1 + 32768);

    init_kernel<<<dim3(BS_ / 256), 256, 0, stream>>>(x, flag, active, counts);
    prepack_w_kernel<<<dim3(192), 256, 0, stream>>>(wq, wk, wv, flag, wpk);
    qkv_kernel<<<dim3(BS_ / 64, 1, 3), 256, 0, stream>>>(x, wpk, flag, qp);
    if (big_ws) {
        attn_split_kernel<<<dim3(S_ / 64, B_, 4), 256, 0, stream>>>(qp, kp, vp, Opart16, lpart16);
        combine_kernel<<<dim3(512), 256, 0, stream>>>(Opart16, lpart16, cur0);
    } else {
        attn_kernel<<<dim3(S_ / 64, B_), 256, 0, stream>>>(qp, kp, vp, cur0);
    }
    round_kernel<<<dim3(BS_ / 64), 256, 0, stream>>>(
        cur0, cur0, tw, tb, ab, w1, b1, w2, b2, gw, gb, flag, active, counts, 0, cur_r, nullptr);
    round_kernel<<<dim3(BS_ / 64), 256, 0, stream>>>(
        cur0, cur_r, tw, tb, ab, w1, b1, w2, b2, gw, gb, flag, active, counts, 1, cur_r, nullptr);
    round_kernel<<<dim3(BS_ / 64), 256, 0, stream>>>(
        cur0, cur_r, tw, tb, ab, w1, b1, w2, b2, gw, gb, flag, active, counts, 2, cur_r, d_out);
}

// Round 7
// 283.595 us; speedup vs baseline: 1.2385x; 1.1678x over previous
//
#include <hip/hip_runtime.h>
#include <hip/hip_bf16.h>

#define B_   8
#define S_   2048
#define DM   1024
#define DH   128
#define BS_  16384
#define SCALE_  0.08838834764831845f
#define SCALE2_ 0.12751744f   // SCALE * log2(e)

typedef unsigned short u16;
typedef unsigned int   u32;
typedef _Float16 half8 __attribute__((ext_vector_type(8)));
typedef float    f32x4 __attribute__((ext_vector_type(4)));
typedef u32      u32x4 __attribute__((ext_vector_type(4)));

union H8 { u32x4 v; u32 u[4]; half8 h; };

__device__ __forceinline__ float bf2f(u16 u) {
    union { u32 i; float f; } w; w.i = ((u32)u) << 16; return w.f;
}
__device__ __forceinline__ void unpack8(uint4 v, float* f) {
    f[0] = bf2f(v.x & 0xffff); f[1] = bf2f(v.x >> 16);
    f[2] = bf2f(v.y & 0xffff); f[3] = bf2f(v.y >> 16);
    f[4] = bf2f(v.z & 0xffff); f[5] = bf2f(v.z >> 16);
    f[6] = bf2f(v.w & 0xffff); f[7] = bf2f(v.w >> 16);
}
__device__ __forceinline__ float ldE(const void* b, size_t i, int isbf16) {
    return isbf16 ? bf2f(((const u16*)b)[i]) : ((const float*)b)[i];
}
__device__ __forceinline__ void ld8(const void* b, size_t i, int isbf16, float* f) {
    if (isbf16) {
        unpack8(*(const uint4*)((const u16*)b + i), f);
    } else {
        float4 a = *(const float4*)((const float*)b + i);
        float4 c = *(const float4*)((const float*)b + i + 4);
        f[0] = a.x; f[1] = a.y; f[2] = a.z; f[3] = a.w;
        f[4] = c.x; f[5] = c.y; f[6] = c.z; f[7] = c.w;
    }
}
// fp32 -> packed (f16 hi << 16) | f16 lo  (2-term split, ~22 mantissa bits)
__device__ __forceinline__ u32 f2pk(float v) {
    _Float16 h = (_Float16)v;
    _Float16 l = (_Float16)(v - (float)h);
    union { _Float16 f; u16 u; } a, b; a.f = h; b.f = l;
    return ((u32)a.u << 16) | (u32)b.u;
}
// 8 floats -> pair-packed hi/lo frag u32x4
__device__ __forceinline__ void split8(const float* f, u32x4& hi, u32x4& lo) {
    u32 H[8], L[8];
#pragma unroll
    for (int j = 0; j < 8; ++j) {
        _Float16 h = (_Float16)f[j];
        _Float16 l = (_Float16)(f[j] - (float)h);
        union { _Float16 x; u16 u; } a, b; a.x = h; b.x = l;
        H[j] = a.u; L[j] = b.u;
    }
    hi = (u32x4){H[0] | (H[1] << 16), H[2] | (H[3] << 16), H[4] | (H[5] << 16), H[6] | (H[7] << 16)};
    lo = (u32x4){L[0] | (L[1] << 16), L[2] | (L[3] << 16), L[4] | (L[5] << 16), L[6] | (L[7] << 16)};
}
__device__ __forceinline__ u32 permHI(u32 eB, u32 eA) { return __builtin_amdgcn_perm(eB, eA, 0x07060302u); }
__device__ __forceinline__ u32 permLO(u32 eB, u32 eA) { return __builtin_amdgcn_perm(eB, eA, 0x05040100u); }
__device__ __forceinline__ u16 f2h(float v) { union { _Float16 f; u16 u; } a; a.f = (_Float16)v; return a.u; }
__device__ __forceinline__ float h2f(u16 u) { union { _Float16 f; u16 u; } a; a.u = u; return (float)a.f; }

// ---------------- init: dtype detect + active mask + round counters ----------------
__global__ void init_kernel(const void* x, int* flag, int* active, int* counts) {
    int i = blockIdx.x * 256 + threadIdx.x;
    if (i < BS_) active[i] = 1;
    if (i < 4) counts[i] = (i == 0) ? BS_ : 0;
    if (i == 0) {
        const u16* w = (const u16*)x;
        int sane = 0;
        for (int t = 0; t < 256; ++t) {
            int e = (w[2 * t] >> 7) & 0xFF;
            if (e >= 100 && e <= 135) ++sane;
        }
        *flag = (sane >= 192) ? 1 : 0;   // 1 = bf16, 0 = fp32
    }
}

// ---------------- prepack W into MFMA fragment layout ----------------
// wpk[((z*32 + ks)*16 + 2*t + plane)*64 + lane] : u32x4
__global__ __launch_bounds__(256) void prepack_w_kernel(
    const void* __restrict__ wq, const void* __restrict__ wk, const void* __restrict__ wv,
    const int* __restrict__ flag, u32x4* __restrict__ wpk)
{
    const int isb = *flag;
    const int gid = blockIdx.x * 256 + threadIdx.x;
    const int l  = gid & 63;
    const int t  = (gid >> 6) & 7;
    const int ks = (gid >> 9) & 31;
    const int z  = gid >> 14;
    const void* W = (z == 0) ? wq : (z == 1) ? wk : wv;
    const int row = 16 * t + (l & 15);
    const int k0  = ks * 32 + 8 * (l >> 4);
    float f[8];
    ld8(W, (size_t)row * DM + k0, isb, f);
    u32x4 hi, lo;
    split8(f, hi, lo);
    const size_t base = ((((size_t)z * 32 + ks) * 16) + 2 * t) * 64 + l;
    wpk[base]      = hi;
    wpk[base + 64] = lo;
}

// ---------------- MFMA QKV: prepacked W + global_load_lds + XCD swizzle ----------------
__global__ __launch_bounds__(256) void qkv_kernel(
    const void* __restrict__ x, const u32x4* __restrict__ wpk,
    const int* __restrict__ flag, u32* __restrict__ qkv)
{
    const int isb = *flag;
    const int z = blockIdx.z;
    u32* out = qkv + (size_t)z * ((size_t)BS_ * DH);
    // XCD swizzle (bijective on [0,256)): consecutive x-tiles stay on one XCD
    const int bx = blockIdx.x;
    const int m0 = ((bx & 7) * 32 + (bx >> 3)) * 64;
    const int tid = threadIdx.x;
    const int wave = tid >> 6, lane = tid & 63;
    const int qd = lane >> 4, c = lane & 15;

    __shared__ u32x4 WL[2][8][2][64];   // [buf][colTile][hi/lo][lane] 32 KB

    const u32x4* wz = wpk + (size_t)z * (32 * 16 * 64);
    const size_t arow = (size_t)(m0 + wave * 16 + c) * DM + 8 * qd;

#define STAGE_W(ks_, b_)                                                          \
    {                                                                             \
        const u32x4* _src = wz + ((size_t)(ks_) * 16 + 4 * wave) * 64 + lane;     \
        _Pragma("unroll")                                                         \
        for (int _j = 0; _j < 4; ++_j) {                                          \
            __builtin_amdgcn_global_load_lds(                                     \
                (const __attribute__((address_space(1))) u32*)(_src + _j * 64),   \
                (__attribute__((address_space(3))) u32*)&WL[b_][2 * wave + (_j >> 1)][_j & 1][0], \
                16, 0, 0);                                                        \
        }                                                                         \
    }

    float Ar[8], Arn[8];
    ld8(x, arow, isb, Ar);
    STAGE_W(0, 0);
    ld8(x, arow + 32, isb, Arn);
    __syncthreads();

    f32x4 acc[8] = {};

    for (int ks = 0; ks < 32; ++ks) {
        const int cb = ks & 1;
        if (ks + 1 < 32) STAGE_W(ks + 1, cb ^ 1);

        H8 Ah, Al;
        split8(Ar, Ah.v, Al.v);
#pragma unroll
        for (int t = 0; t < 8; ++t) {
            H8 bh, bl;
            bh.v = WL[cb][t][0][lane]; bl.v = WL[cb][t][1][lane];
            acc[t] = __builtin_amdgcn_mfma_f32_16x16x32_f16(Al.h, bh.h, acc[t], 0, 0, 0);
            acc[t] = __builtin_amdgcn_mfma_f32_16x16x32_f16(Ah.h, bl.h, acc[t], 0, 0, 0);
            acc[t] = __builtin_amdgcn_mfma_f32_16x16x32_f16(Ah.h, bh.h, acc[t], 0, 0, 0);
        }
#pragma unroll
        for (int j = 0; j < 8; ++j) Ar[j] = Arn[j];
        if (ks + 2 < 32) ld8(x, arow + (size_t)(ks + 2) * 32, isb, Arn);
        __syncthreads();
    }
#undef STAGE_W

#pragma unroll
    for (int r = 0; r < 4; ++r) {
        const int row = m0 + wave * 16 + qd * 4 + r;
        u32* op = out + (size_t)row * DH + c;
#pragma unroll
        for (int t = 0; t < 8; ++t) op[t * 16] = f2pk(acc[t][r]);
    }
}

// ---------------- attention core: hi-f16 single-plane frags ----------------
template <bool WRITE_PARTIAL>
__device__ __forceinline__ void attn_body(
    const u32* qp, const u32* __restrict__ kp, const u32* __restrict__ vp,
    u16* outO, u16* outL, float* cur,
    int b, int q0, int kt0, int kt1, int part)
{
    const int tid = threadIdx.x;
    const int wave = tid >> 6, lane = tid & 63;
    const int qd = lane >> 4, c = lane & 15;

    __shared__ u32x4 KF[2][2][4][64];  // [buf][tile][ks][lane] 16 KB
    __shared__ u32x4 VF[2][8][64];     // [buf][t][lane]        16 KB
    __shared__ u16   PB[4][531];       // per-wave P (f16), stride 33

    H8 Qh[4];
    {
        const u32* qr = qp + ((size_t)b * S_ + q0 + wave * 16 + c) * DH;
#pragma unroll
        for (int ks = 0; ks < 4; ++ks) {
            uint4 e0 = *(const uint4*)(qr + ks * 32 + qd * 8);
            uint4 e1 = *(const uint4*)(qr + ks * 32 + qd * 8 + 4);
            Qh[ks].u[0] = permHI(e0.y, e0.x); Qh[ks].u[1] = permHI(e0.w, e0.z);
            Qh[ks].u[2] = permHI(e1.y, e1.x); Qh[ks].u[3] = permHI(e1.w, e1.z);
        }
    }

    const int kKey = tid & 31, kD0 = (tid >> 5) * 16;
    const int vD = tid >> 1, vKg = (tid & 1) * 16;
    const int tK = (tid >> 4) & 1, cK = tid & 15;
    const int tV = tid >> 5,      cV = (tid >> 1) & 15;

    uint4 Kst[4]; u32 Vst[16];

    auto loadKV = [&](int kb) {
        const u32* kr = kp + ((size_t)b * S_ + kb * 32 + kKey) * DH + kD0;
#pragma unroll
        for (int j = 0; j < 4; ++j) Kst[j] = *(const uint4*)(kr + 4 * j);
        const u32* vc = vp + ((size_t)b * S_ + kb * 32 + vKg) * DH + vD;
#pragma unroll
        for (int j = 0; j < 16; ++j) Vst[j] = vc[(size_t)j * DH];
    };
    auto writeKV = [&](int wb) {
#pragma unroll
        for (int g = 0; g < 2; ++g) {
            const int dg = kD0 + 8 * g, ksK = dg >> 5, qK = (dg >> 3) & 3;
            KF[wb][tK][ksK][qK * 16 + cK] = (u32x4){
                permHI(Kst[2*g].y, Kst[2*g].x), permHI(Kst[2*g].w, Kst[2*g].z),
                permHI(Kst[2*g+1].y, Kst[2*g+1].x), permHI(Kst[2*g+1].w, Kst[2*g+1].z)};
        }
#pragma unroll
        for (int g = 0; g < 2; ++g) {
            const int qV = 2 * (tid & 1) + g;
            VF[wb][tV][qV * 16 + cV] = (u32x4){
                permHI(Vst[8*g+1], Vst[8*g+0]), permHI(Vst[8*g+3], Vst[8*g+2]),
                permHI(Vst[8*g+5], Vst[8*g+4]), permHI(Vst[8*g+7], Vst[8*g+6])};
        }
    };

    loadKV(kt0);
    writeKV(0);
    if (kt0 + 1 < kt1) loadKV(kt0 + 1);
    __syncthreads();

    f32x4 O[8] = {};
    float lsum[4] = {};

    for (int kt = kt0; kt < kt1; ++kt) {
        const int cb = (kt - kt0) & 1;

        f32x4 S0 = {}, S1 = {};
#pragma unroll
        for (int ks = 0; ks < 4; ++ks) {
            H8 kh;
            kh.v = KF[cb][0][ks][lane];
            S0 = __builtin_amdgcn_mfma_f32_16x16x32_f16(Qh[ks].h, kh.h, S0, 0, 0, 0);
            kh.v = KF[cb][1][ks][lane];
            S1 = __builtin_amdgcn_mfma_f32_16x16x32_f16(Qh[ks].h, kh.h, S1, 0, 0, 0);
        }

        u16* pw = PB[wave];
#pragma unroll
        for (int r = 0; r < 4; ++r) {
            float e0 = exp2f(fmaf(S0[r], SCALE2_, -4.0f));
            float e1 = exp2f(fmaf(S1[r], SCALE2_, -4.0f));
            lsum[r] += e0 + e1;
            pw[(4 * qd + r) * 33 + c]      = f2h(e0);
            pw[(4 * qd + r) * 33 + 16 + c] = f2h(e1);
        }

        u16 e[8];
#pragma unroll
        for (int j = 0; j < 8; ++j) e[j] = pw[c * 33 + 8 * qd + j];
        H8 Ph;
        Ph.u[0] = (u32)e[0] | ((u32)e[1] << 16);
        Ph.u[1] = (u32)e[2] | ((u32)e[3] << 16);
        Ph.u[2] = (u32)e[4] | ((u32)e[5] << 16);
        Ph.u[3] = (u32)e[6] | ((u32)e[7] << 16);

#pragma unroll
        for (int t = 0; t < 8; ++t) {
            H8 vh;
            vh.v = VF[cb][t][lane];
            O[t] = __builtin_amdgcn_mfma_f32_16x16x32_f16(Ph.h, vh.h, O[t], 0, 0, 0);
        }

        if (kt + 1 < kt1) {
            writeKV((kt + 1 - kt0) & 1);
            if (kt + 2 < kt1) loadKV(kt + 2);
        }
        __syncthreads();
    }

    if (WRITE_PARTIAL) {
        float lred[4];
#pragma unroll
        for (int r = 0; r < 4; ++r) {
            float l = lsum[r];
            l += __shfl_xor(l, 1); l += __shfl_xor(l, 2);
            l += __shfl_xor(l, 4); l += __shfl_xor(l, 8);
            lred[r] = l;
        }
        const size_t rb = (size_t)b * S_ + q0 + wave * 16 + 4 * qd;
        u16* Op = outO + (size_t)part * ((size_t)BS_ * DH);
#pragma unroll
        for (int t = 0; t < 8; ++t)
#pragma unroll
            for (int r = 0; r < 4; ++r)
                Op[(rb + r) * DH + t * 16 + c] = f2h(O[t][r]);
        if (c == 0) {
            u16* lp = outL + (size_t)part * BS_;
#pragma unroll
            for (int r = 0; r < 4; ++r) lp[rb + r] = f2h(lred[r]);
        }
    } else {
        float linv[4];
#pragma unroll
        for (int r = 0; r < 4; ++r) {
            float l = lsum[r];
            l += __shfl_xor(l, 1); l += __shfl_xor(l, 2);
            l += __shfl_xor(l, 4); l += __shfl_xor(l, 8);
            linv[r] = 1.0f / l;
        }
        const size_t rb = (size_t)b * S_ + q0 + wave * 16 + 4 * qd;
#pragma unroll
        for (int t = 0; t < 8; ++t)
#pragma unroll
            for (int r = 0; r < 4; ++r)
                cur[(rb + r) * DH + t * 16 + c] = O[t][r] * linv[r];
    }
}

// single-pass fallback: grid (32, 8). XCD swizzle: batch = rid&7 (bijective).
__global__ __launch_bounds__(256) void attn_kernel(
    const u32* qp, const u32* __restrict__ kp, const u32* __restrict__ vp, float* cur)
{
    const int rid = blockIdx.x + 32 * blockIdx.y;
    attn_body<false>(qp, kp, vp, nullptr, nullptr, cur,
                     rid & 7, ((rid >> 3) & 31) * 64, 0, S_ / 32, 0);
}

// split-KV x4: grid (32, 8, 4) = 1024 blocks (4 blocks/CU). batch = rid&7 per XCD.
__global__ __launch_bounds__(256) void attn_split_kernel(
    const u32* qp, const u32* __restrict__ kp, const u32* __restrict__ vp,
    u16* __restrict__ Opart, u16* __restrict__ lpart)
{
    const int rid = blockIdx.x + 32 * (blockIdx.y + 8 * blockIdx.z);
    const int b    = rid & 7;
    const int qx   = (rid >> 3) & 31;
    const int part = rid >> 8;
    const int quart = S_ / 128;   // 16 tiles per part
    attn_body<true>(qp, kp, vp, Opart, lpart, nullptr,
                    b, qx * 64, part * quart, (part + 1) * quart, part);
}

// combine: cur0 = sum_p O_p / sum_p l_p (f16 partials). grid 512 x 256, 16 elems/thread.
__global__ __launch_bounds__(256) void combine_kernel(
    const u16* __restrict__ Opart, const u16* __restrict__ lpart,
    float* __restrict__ cur)
{
    const size_t N1 = (size_t)BS_ * DH;
    const size_t i0 = ((size_t)blockIdx.x * 256 + threadIdx.x) * 16;
    const int row = (int)(i0 >> 7);
    const float lt = h2f(lpart[row]) + h2f(lpart[BS_ + row])
                   + h2f(lpart[2 * BS_ + row]) + h2f(lpart[3 * BS_ + row]);
    const float linv = 1.0f / lt;
    float acc[16] = {};
#pragma unroll
    for (int p = 0; p < 4; ++p) {
        const u16* op = Opart + (size_t)p * N1 + i0;
        uint4 v0 = *(const uint4*)op;
        uint4 v1 = *(const uint4*)(op + 8);
        const u32 w[8] = {v0.x, v0.y, v0.z, v0.w, v1.x, v1.y, v1.z, v1.w};
#pragma unroll
        for (int j = 0; j < 8; ++j) {
            acc[2 * j]     += h2f((u16)(w[j] & 0xffff));
            acc[2 * j + 1] += h2f((u16)(w[j] >> 16));
        }
    }
#pragma unroll
    for (int t = 0; t < 4; ++t)
        *(float4*)(cur + i0 + t * 4) = make_float4(
            acc[4*t] * linv, acc[4*t+1] * linv, acc[4*t+2] * linv, acc[4*t+3] * linv);
}

// ---------------- prepack round weights (straight repack, no algebra) ----------------
// mats: 0=tw, 1=w1[:,0:128], 2=w1[:,128:256], 3=w1[:,256:384], 4=w2
// pk[((mat*4 + ks)*16 + 2*t + plane)*64 + lane].  grid 40 x 256.
__global__ __launch_bounds__(256) void prepack_rw_kernel(
    const void* __restrict__ tw, const void* __restrict__ w1, const void* __restrict__ w2,
    const int* __restrict__ flag, u32x4* __restrict__ pk)
{
    const int isb = *flag;
    const int gid = blockIdx.x * 256 + threadIdx.x;   // 10240 total
    const int l = gid & 63, t = (gid >> 6) & 7, ks = (gid >> 9) & 3, mat = gid >> 11;
    const int row = 16 * t + (l & 15);
    const int k0  = ks * 32 + 8 * (l >> 4);
    float f[8];
    if (mat == 0)      ld8(tw, (size_t)row * DH + k0, isb, f);
    else if (mat <= 3) ld8(w1, (size_t)row * 384 + (mat - 1) * 128 + k0, isb, f);
    else               ld8(w2, (size_t)row * DH + k0, isb, f);
    u32x4 hi, lo;
    split8(f, hi, lo);
    const size_t base = (((size_t)mat * 4 + ks) * 16 + 2 * t) * 64 + l;
    pk[base] = hi; pk[base + 64] = lo;
}

// pre-split A fragments
struct Afrag { H8 h[4], l[4]; };
__device__ __forceinline__ void splitA(const float (&A)[4][8], Afrag& F) {
#pragma unroll
    for (int ks = 0; ks < 4; ++ks) split8(A[ks], F.h[ks].v, F.l[ks].v);
}
// 128x128 GEMM quarter over staged WB: acc[t] += A x WB, 3-term hi/lo
__device__ __forceinline__ void gemm_wb(const Afrag& F, const u32x4 (*WB)[16][64],
                                        const int lane, f32x4 (&acc)[8])
{
#pragma unroll
    for (int ks = 0; ks < 4; ++ks) {
#pragma unroll
        for (int t = 0; t < 8; ++t) {
            H8 bh, bl;
            bh.v = WB[ks][2 * t][lane];
            bl.v = WB[ks][2 * t + 1][lane];
            acc[t] = __builtin_amdgcn_mfma_f32_16x16x32_f16(F.l[ks].h, bh.h, acc[t], 0, 0, 0);
            acc[t] = __builtin_amdgcn_mfma_f32_16x16x32_f16(F.h[ks].h, bl.h, acc[t], 0, 0, 0);
            acc[t] = __builtin_amdgcn_mfma_f32_16x16x32_f16(F.h[ks].h, bh.h, acc[t], 0, 0, 0);
        }
    }
}

// ---------------- one dialectic round: 64 tokens/block, MFMA ----------------
// Exact reference algebra: t0 = cur0@tw^T; at=(t0+tb)am; aa=(ab-t0)am; ac=curr*am;
// h = relu(at@w1a^T + aa@w1b^T + ac@w1c^T + b1); synth = h@w2^T + b2; gate/update as before.
__global__ __launch_bounds__(256) void round_kernel(
    const float* cur0, const float* curr,
    const u32x4* __restrict__ pk,
    const void* __restrict__ tb, const void* __restrict__ ab,
    const void* __restrict__ b1, const void* __restrict__ b2,
    const void* __restrict__ gw, const void* __restrict__ gb,
    const int* __restrict__ flag, int* active, int* counts, int r,
    float* cur_out, void* dout)
{
    const int isb = *flag;
    const int tok0 = blockIdx.x * 64;
    const int tid = threadIdx.x;
    const bool last = (dout != nullptr);

    if (counts[r] <= 0) {
        if (last) {
            for (int e = tid; e < 64 * DH; e += 256) {
                size_t idx = (size_t)tok0 * DH + e;
                float v = curr[idx];
                if (isb) ((__hip_bfloat16*)dout)[idx] = __float2bfloat16(v);
                else     ((float*)dout)[idx] = v;
            }
        }
        return;
    }

    const int wave = tid >> 6, lane = tid & 63;
    const int qd = lane >> 4, c = lane & 15;

    __shared__ u32x4 WB[4][16][64];    // 64 KB weight stage buffer
    __shared__ float T0S[64][132];     // t0, later synth (33.8 KB)
    __shared__ float HSS[64][132];     // h (33.8 KB)
    __shared__ float actS[64], tbS[128], abS[128], b1S[128], b2S[128], gwS[256];
    __shared__ int blkcnt;

#define STAGE_RW(mat_)                                                             \
    {                                                                              \
        _Pragma("unroll")                                                          \
        for (int _j = 0; _j < 16; ++_j) {                                          \
            __builtin_amdgcn_global_load_lds(                                      \
                (const __attribute__((address_space(1))) u32*)(                    \
                    pk + (((size_t)(mat_) * 4 + wave) * 16 + _j) * 64 + lane),     \
                (__attribute__((address_space(3))) u32*)&WB[wave][_j][0],          \
                16, 0, 0);                                                         \
        }                                                                          \
    }

    STAGE_RW(0);   // tw
    if (tid < 64) actS[tid] = active[tok0 + tid] ? 1.0f : 0.0f;
    if (tid < 128) {
        tbS[tid] = ldE(tb, tid, isb); abS[tid] = ldE(ab, tid, isb);
        b1S[tid] = ldE(b1, tid, isb); b2S[tid] = ldE(b2, tid, isb);
    }
    gwS[tid] = ldE(gw, tid, isb);
    if (tid == 0) blkcnt = 0;
    const float gbf = ldE(gb, 0, isb);

    const int rowl = 16 * wave + c;      // this lane's A-row (local)
    const int hr   = 16 * wave + 4 * qd; // this lane's C-row base (local)

    // A-frags for cur0 rows
    float A1[4][8];
    {
        const float* cr = cur0 + (size_t)(tok0 + rowl) * DH;
#pragma unroll
        for (int ks = 0; ks < 4; ++ks) {
            *(float4*)&A1[ks][0] = *(const float4*)(cr + ks * 32 + 8 * qd);
            *(float4*)&A1[ks][4] = *(const float4*)(cr + ks * 32 + 8 * qd + 4);
        }
    }
    Afrag FA; splitA(A1, FA);
    __syncthreads();   // WB(tw) staged (syncthreads drains vmcnt), consts visible

    // ---- GEMM t0 = cur0 @ tw^T ----
    {
        f32x4 acc[8] = {};
        gemm_wb(FA, WB, lane, acc);
#pragma unroll
        for (int t = 0; t < 8; ++t)
#pragma unroll
            for (int rr = 0; rr < 4; ++rr)
                T0S[hr + rr][16 * t + c] = acc[t][rr];
    }
    __syncthreads();   // all waves done with WB(tw)
    STAGE_RW(1);       // w1a

    // ---- layer 1: 3 accumulated chunks ----
    f32x4 acc1[8] = {};
    const float am_r = actS[rowl];
    {
        float Ac[4][8];
#pragma unroll
        for (int ks = 0; ks < 4; ++ks)
#pragma unroll
            for (int j = 0; j < 8; ++j) {
                const int k = ks * 32 + 8 * qd + j;
                Ac[ks][j] = (T0S[rowl][k] + tbS[k]) * am_r;   // at
            }
        Afrag FC; splitA(Ac, FC);
        __syncthreads();   // WB(w1a) staged
        gemm_wb(FC, WB, lane, acc1);
    }
    __syncthreads();
    STAGE_RW(2);       // w1b
    {
        float Ac[4][8];
#pragma unroll
        for (int ks = 0; ks < 4; ++ks)
#pragma unroll
            for (int j = 0; j < 8; ++j) {
                const int k = ks * 32 + 8 * qd + j;
                Ac[ks][j] = (abS[k] - T0S[rowl][k]) * am_r;   // aa
            }
        Afrag FC; splitA(Ac, FC);
        __syncthreads();
        gemm_wb(FC, WB, lane, acc1);
    }
    __syncthreads();
    STAGE_RW(3);       // w1c
    {
        float Ac[4][8];
        const float* cr = curr + (size_t)(tok0 + rowl) * DH;
#pragma unroll
        for (int ks = 0; ks < 4; ++ks) {
            float4 a0 = *(const float4*)(cr + ks * 32 + 8 * qd);
            float4 a1 = *(const float4*)(cr + ks * 32 + 8 * qd + 4);
            Ac[ks][0] = a0.x * am_r; Ac[ks][1] = a0.y * am_r;
            Ac[ks][2] = a0.z * am_r; Ac[ks][3] = a0.w * am_r;
            Ac[ks][4] = a1.x * am_r; Ac[ks][5] = a1.y * am_r;
            Ac[ks][6] = a1.z * am_r; Ac[ks][7] = a1.w * am_r;
        }
        Afrag FC; splitA(Ac, FC);
        __syncthreads();
        gemm_wb(FC, WB, lane, acc1);
    }
    // h = relu(acc1 + b1) -> HSS (wave-local rows)
#pragma unroll
    for (int t = 0; t < 8; ++t)
#pragma unroll
        for (int rr = 0; rr < 4; ++rr)
            HSS[hr + rr][16 * t + c] = fmaxf(acc1[t][rr] + b1S[16 * t + c], 0.0f);
    __syncthreads();
    STAGE_RW(4);       // w2
    {
        float Ac[4][8];
#pragma unroll
        for (int ks = 0; ks < 4; ++ks) {
            const float* hp = &HSS[rowl][ks * 32 + 8 * qd];
            *(float4*)&Ac[ks][0] = *(const float4*)hp;
            *(float4*)&Ac[ks][4] = *(const float4*)(hp + 4);
        }
        Afrag FC; splitA(Ac, FC);
        __syncthreads();
        f32x4 acc2[8] = {};
        gemm_wb(FC, WB, lane, acc2);
        // synth -> T0S (reuse; t0 no longer needed)
#pragma unroll
        for (int t = 0; t < 8; ++t)
#pragma unroll
            for (int rr = 0; rr < 4; ++rr)
                T0S[hr + rr][16 * t + c] = acc2[t][rr] + b2S[16 * t + c];
    }
    __syncthreads();   // cross-wave: gate phase uses different row mapping

    // ---- gate, update, norm, active (verbatim from verified kernel) ----
    const int tok = tid >> 2, d0 = (tid & 3) * 32;
    const float am = actS[tok];
    const float* cp = curr + (size_t)(tok0 + tok) * DH + d0;
    float cv[32];
#pragma unroll
    for (int t = 0; t < 8; ++t) {
        float4 vv = *(const float4*)(cp + t * 4);
        cv[t * 4] = vv.x; cv[t * 4 + 1] = vv.y; cv[t * 4 + 2] = vv.z; cv[t * 4 + 3] = vv.w;
    }
    const float* srow = &T0S[tok][d0];
    float gp = 0.0f;
#pragma unroll
    for (int e = 0; e < 32; ++e)
        gp += cv[e] * am * gwS[d0 + e] + srow[e] * gwS[128 + d0 + e];
    gp += __shfl_xor(gp, 1, 4);
    gp += __shfl_xor(gp, 2, 4);
    const float gate = 1.0f / (1.0f + __expf(-(gp + gbf)));
    float ss = 0.0f; float up[32];
#pragma unroll
    for (int e = 0; e < 32; ++e) {
        float u = gate * (srow[e] - cv[e] * am) * 0.1f;
        up[e] = u; ss += u * u;
    }
    ss += __shfl_xor(ss, 1, 4);
    ss += __shfl_xor(ss, 2, 4);
    const bool stable = sqrtf(ss) < 0.1f;

    if (last) {
        size_t off = (size_t)(tok0 + tok) * DH + d0;
        if (isb) {
            __hip_bfloat16* op = (__hip_bfloat16*)dout + off;
#pragma unroll
            for (int e = 0; e < 32; ++e) op[e] = __float2bfloat16(cv[e] + up[e]);
        } else {
            float* op = (float*)dout + off;
#pragma unroll
            for (int t = 0; t < 8; ++t)
                *(float4*)(op + t * 4) = make_float4(cv[t * 4] + up[t * 4], cv[t * 4 + 1] + up[t * 4 + 1],
                                                     cv[t * 4 + 2] + up[t * 4 + 2], cv[t * 4 + 3] + up[t * 4 + 3]);
        }
    } else {
        float* op = cur_out + (size_t)(tok0 + tok) * DH + d0;
#pragma unroll
        for (int t = 0; t < 8; ++t)
            *(float4*)(op + t * 4) = make_float4(cv[t * 4] + up[t * 4], cv[t * 4 + 1] + up[t * 4 + 1],
                                                 cv[t * 4 + 2] + up[t * 4 + 2], cv[t * 4 + 3] + up[t * 4 + 3]);
    }
    const int newact = (am > 0.0f && !stable) ? 1 : 0;
    if ((tid & 3) == 0) {
        active[tok0 + tok] = newact;
        if (newact) atomicAdd(&blkcnt, 1);
    }
    __syncthreads();
    if (tid == 0 && blkcnt > 0) atomicAdd(&counts[r + 1], blkcnt);
#undef STAGE_RW
}

extern "C" void kernel_launch(void* const* d_in, const int* in_sizes, int n_in,
                              void* d_out, int out_size, void* d_ws, size_t ws_size,
                              hipStream_t stream) {
    const void* x  = d_in[0];
    const void* wq = d_in[1];
    const void* wk = d_in[2];
    const void* wv = d_in[3];
    const void* tw = d_in[4];
    const void* tb = d_in[5];
    const void* ab = d_in[6];
    const void* w1 = d_in[7];
    const void* b1 = d_in[8];
    const void* w2 = d_in[9];
    const void* b2 = d_in[10];
    const void* gw = d_in[11];
    const void* gb = d_in[12];

    u32* ws = (u32*)d_ws;
    const size_t N1 = (size_t)BS_ * DH;
    // base layout (~24 MiB): qp | kp | vp | active | counts | flag
    u32* qp = ws;
    u32* kp = ws + N1;
    u32* vp = ws + 2 * N1;
    int* active = (int*)(ws + 3 * N1);
    int* counts = active + BS_;
    int* flag   = counts + 4;
    float* cur0  = (float*)qp;
    float* cur_r = (float*)kp;
    // split-KV x4 extension (f16 partials), ends at 42.2 MB <= 42.3 MB guarantee
    u16* Opart16 = (u16*)(ws + 3 * N1 + 32768);
    u16* lpart16 = (u16*)(ws + 5 * N1 + 32768);
    const bool big_ws = ws_size >= (size_t)42300000;        // constant across calls
    // prepacked QKV W: transient in Opart region (dead before attention writes it)
    u32x4* wpk = (u32x4*)(ws + 3 * N1 + 32768);
    // prepacked round weights: in vp region (V packs dead after attention), 320 KB
    u32x4* pkRW = (u32x4*)vp;

    init_kernel<<<dim3(BS_ / 256), 256, 0, stream>>>(x, flag, active, counts);
    prepack_w_kernel<<<dim3(192), 256, 0, stream>>>(wq, wk, wv, flag, wpk);
    qkv_kernel<<<dim3(BS_ / 64, 1, 3), 256, 0, stream>>>(x, wpk, flag, qp);
    if (big_ws) {
        attn_split_kernel<<<dim3(S_ / 64, B_, 4), 256, 0, stream>>>(qp, kp, vp, Opart16, lpart16);
        combine_kernel<<<dim3(512), 256, 0, stream>>>(Opart16, lpart16, cur0);
    } else {
        attn_kernel<<<dim3(S_ / 64, B_), 256, 0, stream>>>(qp, kp, vp, cur0);
    }
    prepack_rw_kernel<<<dim3(40), 256, 0, stream>>>(tw, w1, w2, flag, pkRW);
    round_kernel<<<dim3(BS_ / 64), 256, 0, stream>>>(
        cur0, cur0, pkRW, tb, ab, b1, b2, gw, gb, flag, active, counts, 0, cur_r, nullptr);
    round_kernel<<<dim3(BS_ / 64), 256, 0, stream>>>(
        cur0, cur_r, pkRW, tb, ab, b1, b2, gw, gb, flag, active, counts, 1, cur_r, nullptr);
    round_kernel<<<dim3(BS_ / 64), 256, 0, stream>>>(
        cur0, cur_r, pkRW, tb, ab, b1, b2, gw, gb, flag, active, counts, 2, cur_r, d_out);
}

// Round 8
// 275.821 us; speedup vs baseline: 1.2734x; 1.0282x over previous
//
#include <hip/hip_runtime.h>
#include <hip/hip_bf16.h>

#define B_   8
#define S_   2048
#define DM   1024
#define DH   128
#define BS_  16384
#define SCALE_  0.08838834764831845f
#define SCALE2_ 0.12751744f   // SCALE * log2(e)

typedef unsigned short u16;
typedef unsigned int   u32;
typedef _Float16 half8 __attribute__((ext_vector_type(8)));
typedef float    f32x4 __attribute__((ext_vector_type(4)));
typedef u32      u32x4 __attribute__((ext_vector_type(4)));

union H8 { u32x4 v; u32 u[4]; half8 h; };

__device__ __forceinline__ float bf2f(u16 u) {
    union { u32 i; float f; } w; w.i = ((u32)u) << 16; return w.f;
}
__device__ __forceinline__ void unpack8(uint4 v, float* f) {
    f[0] = bf2f(v.x & 0xffff); f[1] = bf2f(v.x >> 16);
    f[2] = bf2f(v.y & 0xffff); f[3] = bf2f(v.y >> 16);
    f[4] = bf2f(v.z & 0xffff); f[5] = bf2f(v.z >> 16);
    f[6] = bf2f(v.w & 0xffff); f[7] = bf2f(v.w >> 16);
}
__device__ __forceinline__ float ldE(const void* b, size_t i, int isbf16) {
    return isbf16 ? bf2f(((const u16*)b)[i]) : ((const float*)b)[i];
}
__device__ __forceinline__ void ld8(const void* b, size_t i, int isbf16, float* f) {
    if (isbf16) {
        unpack8(*(const uint4*)((const u16*)b + i), f);
    } else {
        float4 a = *(const float4*)((const float*)b + i);
        float4 c = *(const float4*)((const float*)b + i + 4);
        f[0] = a.x; f[1] = a.y; f[2] = a.z; f[3] = a.w;
        f[4] = c.x; f[5] = c.y; f[6] = c.z; f[7] = c.w;
    }
}
// fp32 -> packed (f16 hi << 16) | f16 lo  (2-term split, ~22 mantissa bits)
__device__ __forceinline__ u32 f2pk(float v) {
    _Float16 h = (_Float16)v;
    _Float16 l = (_Float16)(v - (float)h);
    union { _Float16 f; u16 u; } a, b; a.f = h; b.f = l;
    return ((u32)a.u << 16) | (u32)b.u;
}
// 8 floats -> pair-packed hi/lo frag u32x4
__device__ __forceinline__ void split8(const float* f, u32x4& hi, u32x4& lo) {
    u32 H[8], L[8];
#pragma unroll
    for (int j = 0; j < 8; ++j) {
        _Float16 h = (_Float16)f[j];
        _Float16 l = (_Float16)(f[j] - (float)h);
        union { _Float16 x; u16 u; } a, b; a.x = h; b.x = l;
        H[j] = a.u; L[j] = b.u;
    }
    hi = (u32x4){H[0] | (H[1] << 16), H[2] | (H[3] << 16), H[4] | (H[5] << 16), H[6] | (H[7] << 16)};
    lo = (u32x4){L[0] | (L[1] << 16), L[2] | (L[3] << 16), L[4] | (L[5] << 16), L[6] | (L[7] << 16)};
}
// 8 floats -> hi-plane only (used when inputs are bf16: lo == 0 exactly)
__device__ __forceinline__ void cvt8hi(const float* f, u32x4& hi) {
    u32 H[8];
#pragma unroll
    for (int j = 0; j < 8; ++j) {
        union { _Float16 x; u16 u; } a; a.x = (_Float16)f[j];
        H[j] = a.u;
    }
    hi = (u32x4){H[0] | (H[1] << 16), H[2] | (H[3] << 16), H[4] | (H[5] << 16), H[6] | (H[7] << 16)};
}
__device__ __forceinline__ u32 permHI(u32 eB, u32 eA) { return __builtin_amdgcn_perm(eB, eA, 0x07060302u); }
__device__ __forceinline__ u16 f2h(float v) { union { _Float16 f; u16 u; } a; a.f = (_Float16)v; return a.u; }
__device__ __forceinline__ float h2f(u16 u) { union { _Float16 f; u16 u; } a; a.u = u; return (float)a.f; }

// ---------------- init: dtype detect + active mask + round counters ----------------
__global__ void init_kernel(const void* x, int* flag, int* active, int* counts) {
    int i = blockIdx.x * 256 + threadIdx.x;
    if (i < BS_) active[i] = 1;
    if (i < 4) counts[i] = (i == 0) ? BS_ : 0;
    if (i == 0) {
        const u16* w = (const u16*)x;
        int sane = 0;
        for (int t = 0; t < 256; ++t) {
            int e = (w[2 * t] >> 7) & 0xFF;
            if (e >= 100 && e <= 135) ++sane;
        }
        *flag = (sane >= 192) ? 1 : 0;   // 1 = bf16, 0 = fp32
    }
}

// ---------------- prepack W into MFMA fragment layout ----------------
__global__ __launch_bounds__(256) void prepack_w_kernel(
    const void* __restrict__ wq, const void* __restrict__ wk, const void* __restrict__ wv,
    const int* __restrict__ flag, u32x4* __restrict__ wpk)
{
    const int isb = *flag;
    const int gid = blockIdx.x * 256 + threadIdx.x;
    const int l  = gid & 63;
    const int t  = (gid >> 6) & 7;
    const int ks = (gid >> 9) & 31;
    const int z  = gid >> 14;
    const void* W = (z == 0) ? wq : (z == 1) ? wk : wv;
    const int row = 16 * t + (l & 15);
    const int k0  = ks * 32 + 8 * (l >> 4);
    float f[8];
    ld8(W, (size_t)row * DM + k0, isb, f);
    u32x4 hi, lo;
    split8(f, hi, lo);
    const size_t base = ((((size_t)z * 32 + ks) * 16) + 2 * t) * 64 + l;
    wpk[base]      = hi;
    wpk[base + 64] = lo;
}

// ---------------- MFMA QKV ----------------
// z=0: write Q packs (hi|lo u32). z=1: write K MFMA-frags. z=2: write V MFMA-frags.
// bf16 inputs (isb): lo planes are exactly 0 -> 1-term MFMA is bit-identical.
__global__ __launch_bounds__(256) void qkv_kernel(
    const void* __restrict__ x, const u32x4* __restrict__ wpk,
    const int* __restrict__ flag, u32* __restrict__ qout,
    u32x4* __restrict__ kfrag, u32x4* __restrict__ vfrag)
{
    const int isb = *flag;
    const int z = blockIdx.z;
    // XCD swizzle (bijective on [0,256)): consecutive x-tiles stay on one XCD
    const int bx = blockIdx.x;
    const int m0 = ((bx & 7) * 32 + (bx >> 3)) * 64;
    const int tid = threadIdx.x;
    const int wave = tid >> 6, lane = tid & 63;
    const int qd = lane >> 4, c = lane & 15;

    __shared__ u32x4 WL[2][8][2][64];   // [buf][colTile][hi/lo][lane] 32 KB
    __shared__ u16 TS[64][136];          // transpose tile for frag emission, 17 KB

    const u32x4* wz = wpk + (size_t)z * (32 * 16 * 64);
    const size_t arow = (size_t)(m0 + wave * 16 + c) * DM + 8 * qd;

#define STAGE_W(ks_, b_)                                                          \
    {                                                                             \
        const u32x4* _src = wz + ((size_t)(ks_) * 16 + 4 * wave) * 64 + lane;     \
        _Pragma("unroll")                                                         \
        for (int _j = 0; _j < 4; ++_j) {                                          \
            __builtin_amdgcn_global_load_lds(                                     \
                (const __attribute__((address_space(1))) u32*)(_src + _j * 64),   \
                (__attribute__((address_space(3))) u32*)&WL[b_][2 * wave + (_j >> 1)][_j & 1][0], \
                16, 0, 0);                                                        \
        }                                                                         \
    }

    float Ar[8], Arn[8];
    ld8(x, arow, isb, Ar);
    STAGE_W(0, 0);
    ld8(x, arow + 32, isb, Arn);
    __syncthreads();

    f32x4 acc[8] = {};

    for (int ks = 0; ks < 32; ++ks) {
        const int cb = ks & 1;
        if (ks + 1 < 32) STAGE_W(ks + 1, cb ^ 1);

        if (isb) {   // bf16: lo == 0 -> single-term, bit-identical
            H8 Ah;
            cvt8hi(Ar, Ah.v);
#pragma unroll
            for (int t = 0; t < 8; ++t) {
                H8 bh;
                bh.v = WL[cb][t][0][lane];
                acc[t] = __builtin_amdgcn_mfma_f32_16x16x32_f16(Ah.h, bh.h, acc[t], 0, 0, 0);
            }
        } else {
            H8 Ah, Al;
            split8(Ar, Ah.v, Al.v);
#pragma unroll
            for (int t = 0; t < 8; ++t) {
                H8 bh, bl;
                bh.v = WL[cb][t][0][lane]; bl.v = WL[cb][t][1][lane];
                acc[t] = __builtin_amdgcn_mfma_f32_16x16x32_f16(Al.h, bh.h, acc[t], 0, 0, 0);
                acc[t] = __builtin_amdgcn_mfma_f32_16x16x32_f16(Ah.h, bl.h, acc[t], 0, 0, 0);
                acc[t] = __builtin_amdgcn_mfma_f32_16x16x32_f16(Ah.h, bh.h, acc[t], 0, 0, 0);
            }
        }
#pragma unroll
        for (int j = 0; j < 8; ++j) Ar[j] = Arn[j];
        if (ks + 2 < 32) ld8(x, arow + (size_t)(ks + 2) * 32, isb, Arn);
        __syncthreads();
    }
#undef STAGE_W

    if (z == 0) {
#pragma unroll
        for (int r = 0; r < 4; ++r) {
            const int row = m0 + wave * 16 + qd * 4 + r;
            u32* op = qout + (size_t)row * DH + c;
#pragma unroll
            for (int t = 0; t < 8; ++t) op[t * 16] = f2pk(acc[t][r]);
        }
    } else {
        // stage [key(local)][dh] f16 tile, then emit MFMA B-fragments
#pragma unroll
        for (int t = 0; t < 8; ++t)
#pragma unroll
            for (int r = 0; r < 4; ++r)
                TS[wave * 16 + qd * 4 + r][16 * t + c] = f2h(acc[t][r]);
        __syncthreads();
        if (z == 1) {
            // kfrag[kt16][ks][lane] = K[kt16*16 + (lane&15)][ks*32 + 8*(lane>>4) + j]
#pragma unroll
            for (int i = 0; i < 4; ++i) {
                const int f = tid + 256 * i;          // 0..1023
                const int lf = f & 63, ks = (f >> 6) & 3, sub = f >> 8;
                const int key = sub * 16 + (lf & 15);
                const int d0  = ks * 32 + 8 * (lf >> 4);
                u32 w[4];
#pragma unroll
                for (int q = 0; q < 4; ++q)
                    w[q] = (u32)TS[key][d0 + 2 * q] | ((u32)TS[key][d0 + 2 * q + 1] << 16);
                kfrag[((size_t)(m0 / 16 + sub) * 4 + ks) * 64 + lf] = (u32x4){w[0], w[1], w[2], w[3]};
            }
        } else {
            // vfrag[kt32][t][lane] = V[kt32*32 + 8*(lane>>4) + j][16t + (lane&15)]
#pragma unroll
            for (int i = 0; i < 4; ++i) {
                const int f = tid + 256 * i;          // 0..1023
                const int lf = f & 63, t = (f >> 6) & 7, sub = f >> 9;
                const int kb2 = sub * 32 + 8 * (lf >> 4);
                const int dh  = 16 * t + (lf & 15);
                u32 w[4];
#pragma unroll
                for (int q = 0; q < 4; ++q)
                    w[q] = (u32)TS[kb2 + 2 * q][dh] | ((u32)TS[kb2 + 2 * q + 1][dh] << 16);
                vfrag[((size_t)(m0 / 32 + sub) * 8 + t) * 64 + lf] = (u32x4){w[0], w[1], w[2], w[3]};
            }
        }
    }
}

// ---------------- attention core: barrier-free, frags from global (L2-hot) ----------------
template <bool WRITE_PARTIAL>
__device__ __forceinline__ void attn_body(
    const u32* qp, const u32x4* __restrict__ kfrag, const u32x4* __restrict__ vfrag,
    u16* outO, u16* outL, float* cur,
    int b, int q0, int kt0, int kt1, int part)
{
    const int tid = threadIdx.x;
    const int wave = tid >> 6, lane = tid & 63;
    const int qd = lane >> 4, c = lane & 15;

    __shared__ u16 PB[4][531];   // per-wave P transpose (wave-private -> no barriers)

    H8 Qh[4];
    {
        const u32* qr = qp + ((size_t)b * S_ + q0 + wave * 16 + c) * DH;
#pragma unroll
        for (int ks = 0; ks < 4; ++ks) {
            uint4 e0 = *(const uint4*)(qr + ks * 32 + qd * 8);
            uint4 e1 = *(const uint4*)(qr + ks * 32 + qd * 8 + 4);
            Qh[ks].u[0] = permHI(e0.y, e0.x); Qh[ks].u[1] = permHI(e0.w, e0.z);
            Qh[ks].u[2] = permHI(e1.y, e1.x); Qh[ks].u[3] = permHI(e1.w, e1.z);
        }
    }

    f32x4 O[8] = {};
    float lsum[4] = {};

    const u32x4* kb0 = kfrag + (size_t)b * 128 * 256;   // kt16 stride = 4*64
    const u32x4* vb0 = vfrag + (size_t)b * 64 * 512;    // kt32 stride = 8*64

    for (int kt = kt0; kt < kt1; ++kt) {
        const u32x4* kf = kb0 + (size_t)kt * 512;       // two kt16 blocks
        const u32x4* vf = vb0 + (size_t)kt * 512;

        f32x4 S0 = {}, S1 = {};
#pragma unroll
        for (int ks = 0; ks < 4; ++ks) {
            H8 kh;
            kh.v = kf[ks * 64 + lane];
            S0 = __builtin_amdgcn_mfma_f32_16x16x32_f16(Qh[ks].h, kh.h, S0, 0, 0, 0);
            kh.v = kf[256 + ks * 64 + lane];
            S1 = __builtin_amdgcn_mfma_f32_16x16x32_f16(Qh[ks].h, kh.h, S1, 0, 0, 0);
        }

        u16* pw = PB[wave];
#pragma unroll
        for (int r = 0; r < 4; ++r) {
            float e0 = exp2f(fmaf(S0[r], SCALE2_, -4.0f));
            float e1 = exp2f(fmaf(S1[r], SCALE2_, -4.0f));
            lsum[r] += e0 + e1;
            pw[(4 * qd + r) * 33 + c]      = f2h(e0);
            pw[(4 * qd + r) * 33 + 16 + c] = f2h(e1);
        }

        u16 e[8];
#pragma unroll
        for (int j = 0; j < 8; ++j) e[j] = pw[c * 33 + 8 * qd + j];
        H8 Ph;
        Ph.u[0] = (u32)e[0] | ((u32)e[1] << 16);
        Ph.u[1] = (u32)e[2] | ((u32)e[3] << 16);
        Ph.u[2] = (u32)e[4] | ((u32)e[5] << 16);
        Ph.u[3] = (u32)e[6] | ((u32)e[7] << 16);

#pragma unroll
        for (int t = 0; t < 8; ++t) {
            H8 vh;
            vh.v = vf[t * 64 + lane];
            O[t] = __builtin_amdgcn_mfma_f32_16x16x32_f16(Ph.h, vh.h, O[t], 0, 0, 0);
        }
    }

    if (WRITE_PARTIAL) {
        float lred[4];
#pragma unroll
        for (int r = 0; r < 4; ++r) {
            float l = lsum[r];
            l += __shfl_xor(l, 1); l += __shfl_xor(l, 2);
            l += __shfl_xor(l, 4); l += __shfl_xor(l, 8);
            lred[r] = l;
        }
        const size_t rb = (size_t)b * S_ + q0 + wave * 16 + 4 * qd;
        u16* Op = outO + (size_t)part * ((size_t)BS_ * DH);
#pragma unroll
        for (int t = 0; t < 8; ++t)
#pragma unroll
            for (int r = 0; r < 4; ++r)
                Op[(rb + r) * DH + t * 16 + c] = f2h(O[t][r]);
        if (c == 0) {
            u16* lp = outL + (size_t)part * BS_;
#pragma unroll
            for (int r = 0; r < 4; ++r) lp[rb + r] = f2h(lred[r]);
        }
    } else {
        float linv[4];
#pragma unroll
        for (int r = 0; r < 4; ++r) {
            float l = lsum[r];
            l += __shfl_xor(l, 1); l += __shfl_xor(l, 2);
            l += __shfl_xor(l, 4); l += __shfl_xor(l, 8);
            linv[r] = 1.0f / l;
        }
        const size_t rb = (size_t)b * S_ + q0 + wave * 16 + 4 * qd;
#pragma unroll
        for (int t = 0; t < 8; ++t)
#pragma unroll
            for (int r = 0; r < 4; ++r)
                cur[(rb + r) * DH + t * 16 + c] = O[t][r] * linv[r];
    }
}

// single-pass fallback: grid (32, 8). XCD swizzle: batch = rid&7 (bijective).
__global__ __launch_bounds__(256) void attn_kernel(
    const u32* qp, const u32x4* __restrict__ kfrag, const u32x4* __restrict__ vfrag, float* cur)
{
    const int rid = blockIdx.x + 32 * blockIdx.y;
    attn_body<false>(qp, kfrag, vfrag, nullptr, nullptr, cur,
                     rid & 7, ((rid >> 3) & 31) * 64, 0, S_ / 32, 0);
}

// split-KV x4: grid (32, 8, 4) = 1024 blocks. batch = rid&7 per XCD.
__global__ __launch_bounds__(256) void attn_split_kernel(
    const u32* qp, const u32x4* __restrict__ kfrag, const u32x4* __restrict__ vfrag,
    u16* __restrict__ Opart, u16* __restrict__ lpart)
{
    const int rid = blockIdx.x + 32 * (blockIdx.y + 8 * blockIdx.z);
    const int b    = rid & 7;
    const int qx   = (rid >> 3) & 31;
    const int part = rid >> 8;
    const int quart = S_ / 128;   // 16 tiles per part
    attn_body<true>(qp, kfrag, vfrag, Opart, lpart, nullptr,
                    b, qx * 64, part * quart, (part + 1) * quart, part);
}

// combine: cur0 = sum_p O_p / sum_p l_p (f16 partials). grid 512 x 256, 16 elems/thread.
__global__ __launch_bounds__(256) void combine_kernel(
    const u16* __restrict__ Opart, const u16* __restrict__ lpart,
    float* __restrict__ cur)
{
    const size_t N1 = (size_t)BS_ * DH;
    const size_t i0 = ((size_t)blockIdx.x * 256 + threadIdx.x) * 16;
    const int row = (int)(i0 >> 7);
    const float lt = h2f(lpart[row]) + h2f(lpart[BS_ + row])
                   + h2f(lpart[2 * BS_ + row]) + h2f(lpart[3 * BS_ + row]);
    const float linv = 1.0f / lt;
    float acc[16] = {};
#pragma unroll
    for (int p = 0; p < 4; ++p) {
        const u16* op = Opart + (size_t)p * N1 + i0;
        uint4 v0 = *(const uint4*)op;
        uint4 v1 = *(const uint4*)(op + 8);
        const u32 w[8] = {v0.x, v0.y, v0.z, v0.w, v1.x, v1.y, v1.z, v1.w};
#pragma unroll
        for (int j = 0; j < 8; ++j) {
            acc[2 * j]     += h2f((u16)(w[j] & 0xffff));
            acc[2 * j + 1] += h2f((u16)(w[j] >> 16));
        }
    }
#pragma unroll
    for (int t = 0; t < 4; ++t)
        *(float4*)(cur + i0 + t * 4) = make_float4(
            acc[4*t] * linv, acc[4*t+1] * linv, acc[4*t+2] * linv, acc[4*t+3] * linv);
}

// ---------------- prepack round weights (straight repack, no algebra) ----------------
// mats: 0=tw, 1=w1[:,0:128], 2=w1[:,128:256], 3=w1[:,256:384], 4=w2
__global__ __launch_bounds__(256) void prepack_rw_kernel(
    const void* __restrict__ tw, const void* __restrict__ w1, const void* __restrict__ w2,
    const int* __restrict__ flag, u32x4* __restrict__ pk)
{
    const int isb = *flag;
    const int gid = blockIdx.x * 256 + threadIdx.x;   // 10240 total
    const int l = gid & 63, t = (gid >> 6) & 7, ks = (gid >> 9) & 3, mat = gid >> 11;
    const int row = 16 * t + (l & 15);
    const int k0  = ks * 32 + 8 * (l >> 4);
    float f[8];
    if (mat == 0)      ld8(tw, (size_t)row * DH + k0, isb, f);
    else if (mat <= 3) ld8(w1, (size_t)row * 384 + (mat - 1) * 128 + k0, isb, f);
    else               ld8(w2, (size_t)row * DH + k0, isb, f);
    u32x4 hi, lo;
    split8(f, hi, lo);
    const size_t base = (((size_t)mat * 4 + ks) * 16 + 2 * t) * 64 + l;
    pk[base] = hi; pk[base + 64] = lo;
}

// pre-split A fragments
struct Afrag { H8 h[4], l[4]; };
__device__ __forceinline__ void splitA(const float (&A)[4][8], Afrag& F) {
#pragma unroll
    for (int ks = 0; ks < 4; ++ks) split8(A[ks], F.h[ks].v, F.l[ks].v);
}
// 128x128 GEMM quarter over staged WB. When isb: weight lo-plane == 0 exactly ->
// skip the Ah x Bl term (bit-identical).
__device__ __forceinline__ void gemm_wb(const Afrag& F, const u32x4 (*WB)[16][64],
                                        const int lane, const int isb, f32x4 (&acc)[8])
{
#pragma unroll
    for (int ks = 0; ks < 4; ++ks) {
#pragma unroll
        for (int t = 0; t < 8; ++t) {
            H8 bh, bl;
            bh.v = WB[ks][2 * t][lane];
            bl.v = WB[ks][2 * t + 1][lane];
            acc[t] = __builtin_amdgcn_mfma_f32_16x16x32_f16(F.l[ks].h, bh.h, acc[t], 0, 0, 0);
            if (!isb)
                acc[t] = __builtin_amdgcn_mfma_f32_16x16x32_f16(F.h[ks].h, bl.h, acc[t], 0, 0, 0);
            acc[t] = __builtin_amdgcn_mfma_f32_16x16x32_f16(F.h[ks].h, bh.h, acc[t], 0, 0, 0);
        }
    }
}

// ---------------- one dialectic round: 64 tokens/block, MFMA ----------------
__global__ __launch_bounds__(256) void round_kernel(
    const float* cur0, const float* curr,
    const u32x4* __restrict__ pk,
    const void* __restrict__ tb, const void* __restrict__ ab,
    const void* __restrict__ b1, const void* __restrict__ b2,
    const void* __restrict__ gw, const void* __restrict__ gb,
    const int* __restrict__ flag, int* active, int* counts, int r,
    float* cur_out, void* dout)
{
    const int isb = *flag;
    const int tok0 = blockIdx.x * 64;
    const int tid = threadIdx.x;
    const bool last = (dout != nullptr);

    if (counts[r] <= 0) {
        if (last) {
            for (int e = tid; e < 64 * DH; e += 256) {
                size_t idx = (size_t)tok0 * DH + e;
                float v = curr[idx];
                if (isb) ((__hip_bfloat16*)dout)[idx] = __float2bfloat16(v);
                else     ((float*)dout)[idx] = v;
            }
        }
        return;
    }

    const int wave = tid >> 6, lane = tid & 63;
    const int qd = lane >> 4, c = lane & 15;

    __shared__ u32x4 WB[4][16][64];    // 64 KB weight stage buffer
    __shared__ float T0S[64][132];     // t0, later synth
    __shared__ float HSS[64][132];     // h
    __shared__ float actS[64], tbS[128], abS[128], b1S[128], b2S[128], gwS[256];
    __shared__ int blkcnt;

#define STAGE_RW(mat_)                                                             \
    {                                                                              \
        _Pragma("unroll")                                                          \
        for (int _j = 0; _j < 16; ++_j) {                                          \
            __builtin_amdgcn_global_load_lds(                                      \
                (const __attribute__((address_space(1))) u32*)(                    \
                    pk + (((size_t)(mat_) * 4 + wave) * 16 + _j) * 64 + lane),     \
                (__attribute__((address_space(3))) u32*)&WB[wave][_j][0],          \
                16, 0, 0);                                                         \
        }                                                                          \
    }

    STAGE_RW(0);   // tw
    if (tid < 64) actS[tid] = active[tok0 + tid] ? 1.0f : 0.0f;
    if (tid < 128) {
        tbS[tid] = ldE(tb, tid, isb); abS[tid] = ldE(ab, tid, isb);
        b1S[tid] = ldE(b1, tid, isb); b2S[tid] = ldE(b2, tid, isb);
    }
    gwS[tid] = ldE(gw, tid, isb);
    if (tid == 0) blkcnt = 0;
    const float gbf = ldE(gb, 0, isb);

    const int rowl = 16 * wave + c;      // this lane's A-row (local)
    const int hr   = 16 * wave + 4 * qd; // this lane's C-row base (local)

    float A1[4][8];
    {
        const float* cr = cur0 + (size_t)(tok0 + rowl) * DH;
#pragma unroll
        for (int ks = 0; ks < 4; ++ks) {
            *(float4*)&A1[ks][0] = *(const float4*)(cr + ks * 32 + 8 * qd);
            *(float4*)&A1[ks][4] = *(const float4*)(cr + ks * 32 + 8 * qd + 4);
        }
    }
    Afrag FA; splitA(A1, FA);
    __syncthreads();   // WB(tw) staged, consts visible

    // ---- GEMM t0 = cur0 @ tw^T ----
    {
        f32x4 acc[8] = {};
        gemm_wb(FA, WB, lane, isb, acc);
#pragma unroll
        for (int t = 0; t < 8; ++t)
#pragma unroll
            for (int rr = 0; rr < 4; ++rr)
                T0S[hr + rr][16 * t + c] = acc[t][rr];
    }
    __syncthreads();
    STAGE_RW(1);       // w1a

    f32x4 acc1[8] = {};
    const float am_r = actS[rowl];
    {
        float Ac[4][8];
#pragma unroll
        for (int ks = 0; ks < 4; ++ks)
#pragma unroll
            for (int j = 0; j < 8; ++j) {
                const int k = ks * 32 + 8 * qd + j;
                Ac[ks][j] = (T0S[rowl][k] + tbS[k]) * am_r;   // at
            }
        Afrag FC; splitA(Ac, FC);
        __syncthreads();
        gemm_wb(FC, WB, lane, isb, acc1);
    }
    __syncthreads();
    STAGE_RW(2);       // w1b
    {
        float Ac[4][8];
#pragma unroll
        for (int ks = 0; ks < 4; ++ks)
#pragma unroll
            for (int j = 0; j < 8; ++j) {
                const int k = ks * 32 + 8 * qd + j;
                Ac[ks][j] = (abS[k] - T0S[rowl][k]) * am_r;   // aa
            }
        Afrag FC; splitA(Ac, FC);
        __syncthreads();
        gemm_wb(FC, WB, lane, isb, acc1);
    }
    __syncthreads();
    STAGE_RW(3);       // w1c
    {
        float Ac[4][8];
        const float* cr = curr + (size_t)(tok0 + rowl) * DH;
#pragma unroll
        for (int ks = 0; ks < 4; ++ks) {
            float4 a0 = *(const float4*)(cr + ks * 32 + 8 * qd);
            float4 a1 = *(const float4*)(cr + ks * 32 + 8 * qd + 4);
            Ac[ks][0] = a0.x * am_r; Ac[ks][1] = a0.y * am_r;
            Ac[ks][2] = a0.z * am_r; Ac[ks][3] = a0.w * am_r;
            Ac[ks][4] = a1.x * am_r; Ac[ks][5] = a1.y * am_r;
            Ac[ks][6] = a1.z * am_r; Ac[ks][7] = a1.w * am_r;
        }
        Afrag FC; splitA(Ac, FC);
        __syncthreads();
        gemm_wb(FC, WB, lane, isb, acc1);
    }
#pragma unroll
    for (int t = 0; t < 8; ++t)
#pragma unroll
        for (int rr = 0; rr < 4; ++rr)
            HSS[hr + rr][16 * t + c] = fmaxf(acc1[t][rr] + b1S[16 * t + c], 0.0f);
    __syncthreads();
    STAGE_RW(4);       // w2
    {
        float Ac[4][8];
#pragma unroll
        for (int ks = 0; ks < 4; ++ks) {
            const float* hp = &HSS[rowl][ks * 32 + 8 * qd];
            *(float4*)&Ac[ks][0] = *(const float4*)hp;
            *(float4*)&Ac[ks][4] = *(const float4*)(hp + 4);
        }
        Afrag FC; splitA(Ac, FC);
        __syncthreads();
        f32x4 acc2[8] = {};
        gemm_wb(FC, WB, lane, isb, acc2);
#pragma unroll
        for (int t = 0; t < 8; ++t)
#pragma unroll
            for (int rr = 0; rr < 4; ++rr)
                T0S[hr + rr][16 * t + c] = acc2[t][rr] + b2S[16 * t + c];
    }
    __syncthreads();

    // ---- gate, update, norm, active ----
    const int tok = tid >> 2, d0 = (tid & 3) * 32;
    const float am = actS[tok];
    const float* cp = curr + (size_t)(tok0 + tok) * DH + d0;
    float cv[32];
#pragma unroll
    for (int t = 0; t < 8; ++t) {
        float4 vv = *(const float4*)(cp + t * 4);
        cv[t * 4] = vv.x; cv[t * 4 + 1] = vv.y; cv[t * 4 + 2] = vv.z; cv[t * 4 + 3] = vv.w;
    }
    const float* srow = &T0S[tok][d0];
    float gp = 0.0f;
#pragma unroll
    for (int e = 0; e < 32; ++e)
        gp += cv[e] * am * gwS[d0 + e] + srow[e] * gwS[128 + d0 + e];
    gp += __shfl_xor(gp, 1, 4);
    gp += __shfl_xor(gp, 2, 4);
    const float gate = 1.0f / (1.0f + __expf(-(gp + gbf)));
    float ss = 0.0f; float up[32];
#pragma unroll
    for (int e = 0; e < 32; ++e) {
        float u = gate * (srow[e] - cv[e] * am) * 0.1f;
        up[e] = u; ss += u * u;
    }
    ss += __shfl_xor(ss, 1, 4);
    ss += __shfl_xor(ss, 2, 4);
    const bool stable = sqrtf(ss) < 0.1f;

    if (last) {
        size_t off = (size_t)(tok0 + tok) * DH + d0;
        if (isb) {
            __hip_bfloat16* op = (__hip_bfloat16*)dout + off;
#pragma unroll
            for (int e = 0; e < 32; ++e) op[e] = __float2bfloat16(cv[e] + up[e]);
        } else {
            float* op = (float*)dout + off;
#pragma unroll
            for (int t = 0; t < 8; ++t)
                *(float4*)(op + t * 4) = make_float4(cv[t * 4] + up[t * 4], cv[t * 4 + 1] + up[t * 4 + 1],
                                                     cv[t * 4 + 2] + up[t * 4 + 2], cv[t * 4 + 3] + up[t * 4 + 3]);
        }
    } else {
        float* op = cur_out + (size_t)(tok0 + tok) * DH + d0;
#pragma unroll
        for (int t = 0; t < 8; ++t)
            *(float4*)(op + t * 4) = make_float4(cv[t * 4] + up[t * 4], cv[t * 4 + 1] + up[t * 4 + 1],
                                                 cv[t * 4 + 2] + up[t * 4 + 2], cv[t * 4 + 3] + up[t * 4 + 3]);
    }
    const int newact = (am > 0.0f && !stable) ? 1 : 0;
    if ((tid & 3) == 0) {
        active[tok0 + tok] = newact;
        if (newact) atomicAdd(&blkcnt, 1);
    }
    __syncthreads();
    if (tid == 0 && blkcnt > 0) atomicAdd(&counts[r + 1], blkcnt);
#undef STAGE_RW
}

extern "C" void kernel_launch(void* const* d_in, const int* in_sizes, int n_in,
                              void* d_out, int out_size, void* d_ws, size_t ws_size,
                              hipStream_t stream) {
    const void* x  = d_in[0];
    const void* wq = d_in[1];
    const void* wk = d_in[2];
    const void* wv = d_in[3];
    const void* tw = d_in[4];
    const void* tb = d_in[5];
    const void* ab = d_in[6];
    const void* w1 = d_in[7];
    const void* b1 = d_in[8];
    const void* w2 = d_in[9];
    const void* b2 = d_in[10];
    const void* gw = d_in[11];
    const void* gb = d_in[12];

    u32* ws = (u32*)d_ws;
    const size_t N1 = (size_t)BS_ * DH;
    // base layout (~24 MiB): qp | kp | vp | active | counts | flag
    u32* qp = ws;
    u32* kp = ws + N1;        // K MFMA-frags (4 MB used of 8 MB region)
    u32* vp = ws + 2 * N1;    // V MFMA-frags (4 MB used of 8 MB region)
    int* active = (int*)(ws + 3 * N1);
    int* counts = active + BS_;
    int* flag   = counts + 4;
    float* cur0  = (float*)qp;
    float* cur_r = (float*)kp;    // overwrites dead K-frags after attn
    // split-KV x4 extension (f16 partials), ends at 42.2 MB <= 42.3 MB guarantee
    u16* Opart16 = (u16*)(ws + 3 * N1 + 32768);
    u16* lpart16 = (u16*)(ws + 5 * N1 + 32768);
    const bool big_ws = ws_size >= (size_t)42300000;        // constant across calls
    // prepacked QKV W: transient in Opart region (dead before attention writes it)
    u32x4* wpk = (u32x4*)(ws + 3 * N1 + 32768);
    // prepacked round weights: in vp region (V-frags dead after attn), 320 KB
    u32x4* pkRW = (u32x4*)vp;
    u32x4* kfragP = (u32x4*)kp;
    u32x4* vfragP = (u32x4*)vp;

    init_kernel<<<dim3(BS_ / 256), 256, 0, stream>>>(x, flag, active, counts);
    prepack_w_kernel<<<dim3(192), 256, 0, stream>>>(wq, wk, wv, flag, wpk);
    qkv_kernel<<<dim3(BS_ / 64, 1, 3), 256, 0, stream>>>(x, wpk, flag, qp, kfragP, vfragP);
    if (big_ws) {
        attn_split_kernel<<<dim3(S_ / 64, B_, 4), 256, 0, stream>>>(qp, kfragP, vfragP, Opart16, lpart16);
        combine_kernel<<<dim3(512), 256, 0, stream>>>(Opart16, lpart16, cur0);
    } else {
        attn_kernel<<<dim3(S_ / 64, B_), 256, 0, stream>>>(qp, kfragP, vfragP, cur0);
    }
    prepack_rw_kernel<<<dim3(40), 256, 0, stream>>>(tw, w1, w2, flag, pkRW);
    round_kernel<<<dim3(BS_ / 64), 256, 0, stream>>>(
        cur0, cur0, pkRW, tb, ab, b1, b2, gw, gb, flag, active, counts, 0, cur_r, nullptr);
    round_kernel<<<dim3(BS_ / 64), 256, 0, stream>>>(
        cur0, cur_r, pkRW, tb, ab, b1, b2, gw, gb, flag, active, counts, 1, cur_r, nullptr);
    round_kernel<<<dim3(BS_ / 64), 256, 0, stream>>>(
        cur0, cur_r, pkRW, tb, ab, b1, b2, gw, gb, flag, active, counts, 2, cur_r, d_out);
}

// Round 9
// 266.525 us; speedup vs baseline: 1.3178x; 1.0349x over previous
//
#include <hip/hip_runtime.h>
#include <hip/hip_bf16.h>

#define B_   8
#define S_   2048
#define DM   1024
#define DH   128
#define BS_  16384
#define SCALE_  0.08838834764831845f
#define SCALE2_ 0.12751744f   // SCALE * log2(e)

typedef unsigned short u16;
typedef unsigned int   u32;
typedef _Float16 half8 __attribute__((ext_vector_type(8)));
typedef __bf16   bf16x8 __attribute__((ext_vector_type(8)));
typedef float    f32x4 __attribute__((ext_vector_type(4)));
typedef u32      u32x4 __attribute__((ext_vector_type(4)));

union H8 { u32x4 v; u32 u[4]; half8 h; bf16x8 b; };

__device__ __forceinline__ float bf2f(u16 u) {
    union { u32 i; float f; } w; w.i = ((u32)u) << 16; return w.f;
}
__device__ __forceinline__ void unpack8(uint4 v, float* f) {
    f[0] = bf2f(v.x & 0xffff); f[1] = bf2f(v.x >> 16);
    f[2] = bf2f(v.y & 0xffff); f[3] = bf2f(v.y >> 16);
    f[4] = bf2f(v.z & 0xffff); f[5] = bf2f(v.z >> 16);
    f[6] = bf2f(v.w & 0xffff); f[7] = bf2f(v.w >> 16);
}
__device__ __forceinline__ float ldE(const void* b, size_t i, int isbf16) {
    return isbf16 ? bf2f(((const u16*)b)[i]) : ((const float*)b)[i];
}
__device__ __forceinline__ void ld8(const void* b, size_t i, int isbf16, float* f) {
    if (isbf16) {
        unpack8(*(const uint4*)((const u16*)b + i), f);
    } else {
        float4 a = *(const float4*)((const float*)b + i);
        float4 c = *(const float4*)((const float*)b + i + 4);
        f[0] = a.x; f[1] = a.y; f[2] = a.z; f[3] = a.w;
        f[4] = c.x; f[5] = c.y; f[6] = c.z; f[7] = c.w;
    }
}
// fp32 -> packed (f16 hi << 16) | f16 lo  (2-term split, ~22 mantissa bits)
__device__ __forceinline__ u32 f2pk(float v) {
    _Float16 h = (_Float16)v;
    _Float16 l = (_Float16)(v - (float)h);
    union { _Float16 f; u16 u; } a, b; a.f = h; b.f = l;
    return ((u32)a.u << 16) | (u32)b.u;
}
// 8 floats -> pair-packed hi/lo frag u32x4
__device__ __forceinline__ void split8(const float* f, u32x4& hi, u32x4& lo) {
    u32 H[8], L[8];
#pragma unroll
    for (int j = 0; j < 8; ++j) {
        _Float16 h = (_Float16)f[j];
        _Float16 l = (_Float16)(f[j] - (float)h);
        union { _Float16 x; u16 u; } a, b; a.x = h; b.x = l;
        H[j] = a.u; L[j] = b.u;
    }
    hi = (u32x4){H[0] | (H[1] << 16), H[2] | (H[3] << 16), H[4] | (H[5] << 16), H[6] | (H[7] << 16)};
    lo = (u32x4){L[0] | (L[1] << 16), L[2] | (L[3] << 16), L[4] | (L[5] << 16), L[6] | (L[7] << 16)};
}
__device__ __forceinline__ u32 permHI(u32 eB, u32 eA) { return __builtin_amdgcn_perm(eB, eA, 0x07060302u); }
__device__ __forceinline__ u16 f2h(float v) { union { _Float16 f; u16 u; } a; a.f = (_Float16)v; return a.u; }
__device__ __forceinline__ float h2f(u16 u) { union { _Float16 f; u16 u; } a; a.u = u; return (float)a.f; }

// ---------------- init: dtype detect + active mask + round counters ----------------
__global__ void init_kernel(const void* x, int* flag, int* active, int* counts) {
    int i = blockIdx.x * 256 + threadIdx.x;
    if (i < BS_) active[i] = 1;
    if (i < 4) counts[i] = (i == 0) ? BS_ : 0;
    if (i == 0) {
        const u16* w = (const u16*)x;
        int sane = 0;
        for (int t = 0; t < 256; ++t) {
            int e = (w[2 * t] >> 7) & 0xFF;
            if (e >= 100 && e <= 135) ++sane;
        }
        *flag = (sane >= 192) ? 1 : 0;   // 1 = bf16, 0 = fp32
    }
}

// ---------------- prepack W into MFMA fragment layout ----------------
// bf16 path: hi slot = raw bf16 pairs (lo unused). fp32 path: f16 hi/lo split.
__global__ __launch_bounds__(256) void prepack_w_kernel(
    const void* __restrict__ wq, const void* __restrict__ wk, const void* __restrict__ wv,
    const int* __restrict__ flag, u32x4* __restrict__ wpk)
{
    const int isb = *flag;
    const int gid = blockIdx.x * 256 + threadIdx.x;
    const int l  = gid & 63;
    const int t  = (gid >> 6) & 7;
    const int ks = (gid >> 9) & 31;
    const int z  = gid >> 14;
    const void* W = (z == 0) ? wq : (z == 1) ? wk : wv;
    const int row = 16 * t + (l & 15);
    const int k0  = ks * 32 + 8 * (l >> 4);
    const size_t base = ((((size_t)z * 32 + ks) * 16) + 2 * t) * 64 + l;
    if (isb) {
        uint4 v = *(const uint4*)((const u16*)W + (size_t)row * DM + k0);
        wpk[base] = (u32x4){v.x, v.y, v.z, v.w};
    } else {
        float f[8];
        ld8(W, (size_t)row * DM + k0, 0, f);
        u32x4 hi, lo;
        split8(f, hi, lo);
        wpk[base]      = hi;
        wpk[base + 64] = lo;
    }
}

// ---------------- MFMA QKV ----------------
// z=0: write Q packs (hi|lo u32). z=1: write K MFMA-frags. z=2: write V MFMA-frags.
// bf16 inputs: native bf16 MFMA, raw-bit A/B frags, zero conversion VALU.
__global__ __launch_bounds__(256) void qkv_kernel(
    const void* __restrict__ x, const u32x4* __restrict__ wpk,
    const int* __restrict__ flag, u32* __restrict__ qout,
    u32x4* __restrict__ kfrag, u32x4* __restrict__ vfrag)
{
    const int isb = *flag;
    const int z = blockIdx.z;
    // XCD swizzle (bijective on [0,256)): consecutive x-tiles stay on one XCD
    const int bx = blockIdx.x;
    const int m0 = ((bx & 7) * 32 + (bx >> 3)) * 64;
    const int tid = threadIdx.x;
    const int wave = tid >> 6, lane = tid & 63;
    const int qd = lane >> 4, c = lane & 15;

    __shared__ u32x4 WL[2][8][2][64];   // [buf][colTile][hi/lo][lane] 32 KB
    __shared__ u16 TS[64][136];          // transpose tile for frag emission, 17 KB

    const u32x4* wz = wpk + (size_t)z * (32 * 16 * 64);
    const size_t arow = (size_t)(m0 + wave * 16 + c) * DM + 8 * qd;

// full stage: 16 slabs (8 tiles x hi/lo), 4 per wave
#define STAGE_W(ks_, b_)                                                          \
    {                                                                             \
        const u32x4* _src = wz + ((size_t)(ks_) * 16 + 4 * wave) * 64 + lane;     \
        _Pragma("unroll")                                                         \
        for (int _j = 0; _j < 4; ++_j) {                                          \
            __builtin_amdgcn_global_load_lds(                                     \
                (const __attribute__((address_space(1))) u32*)(_src + _j * 64),   \
                (__attribute__((address_space(3))) u32*)&WL[b_][2 * wave + (_j >> 1)][_j & 1][0], \
                16, 0, 0);                                                        \
        }                                                                         \
    }
// hi-only stage: 8 slabs (bf16 path), 2 per wave
#define STAGE_WH(ks_, b_)                                                         \
    {                                                                             \
        _Pragma("unroll")                                                         \
        for (int _j = 0; _j < 2; ++_j) {                                          \
            __builtin_amdgcn_global_load_lds(                                     \
                (const __attribute__((address_space(1))) u32*)(                   \
                    wz + ((size_t)(ks_) * 16 + 2 * (2 * wave + _j)) * 64 + lane), \
                (__attribute__((address_space(3))) u32*)&WL[b_][2 * wave + _j][0][0], \
                16, 0, 0);                                                        \
        }                                                                         \
    }

    f32x4 acc[8] = {};

    if (isb) {
        const u16* xb = (const u16*)x;
        uint4 Ab = *(const uint4*)(xb + arow);
        STAGE_WH(0, 0);
        uint4 Abn = *(const uint4*)(xb + arow + 32);
        __syncthreads();
        for (int ks = 0; ks < 32; ++ks) {
            const int cb = ks & 1;
            if (ks + 1 < 32) STAGE_WH(ks + 1, cb ^ 1);
            H8 Ah; Ah.v = (u32x4){Ab.x, Ab.y, Ab.z, Ab.w};
#pragma unroll
            for (int t = 0; t < 8; ++t) {
                H8 bh; bh.v = WL[cb][t][0][lane];
                acc[t] = __builtin_amdgcn_mfma_f32_16x16x32_bf16(Ah.b, bh.b, acc[t], 0, 0, 0);
            }
            Ab = Abn;
            if (ks + 2 < 32) Abn = *(const uint4*)(xb + arow + (size_t)(ks + 2) * 32);
            __syncthreads();
        }
    } else {
        float Ar[8], Arn[8];
        ld8(x, arow, 0, Ar);
        STAGE_W(0, 0);
        ld8(x, arow + 32, 0, Arn);
        __syncthreads();
        for (int ks = 0; ks < 32; ++ks) {
            const int cb = ks & 1;
            if (ks + 1 < 32) STAGE_W(ks + 1, cb ^ 1);
            H8 Ah, Al;
            split8(Ar, Ah.v, Al.v);
#pragma unroll
            for (int t = 0; t < 8; ++t) {
                H8 bh, bl;
                bh.v = WL[cb][t][0][lane]; bl.v = WL[cb][t][1][lane];
                acc[t] = __builtin_amdgcn_mfma_f32_16x16x32_f16(Al.h, bh.h, acc[t], 0, 0, 0);
                acc[t] = __builtin_amdgcn_mfma_f32_16x16x32_f16(Ah.h, bl.h, acc[t], 0, 0, 0);
                acc[t] = __builtin_amdgcn_mfma_f32_16x16x32_f16(Ah.h, bh.h, acc[t], 0, 0, 0);
            }
#pragma unroll
            for (int j = 0; j < 8; ++j) Ar[j] = Arn[j];
            if (ks + 2 < 32) ld8(x, arow + (size_t)(ks + 2) * 32, 0, Arn);
            __syncthreads();
        }
    }
#undef STAGE_W
#undef STAGE_WH

    if (z == 0) {
#pragma unroll
        for (int r = 0; r < 4; ++r) {
            const int row = m0 + wave * 16 + qd * 4 + r;
            u32* op = qout + (size_t)row * DH + c;
#pragma unroll
            for (int t = 0; t < 8; ++t) op[t * 16] = f2pk(acc[t][r]);
        }
    } else {
        // stage [key(local)][dh] f16 tile, then emit MFMA B-fragments
#pragma unroll
        for (int t = 0; t < 8; ++t)
#pragma unroll
            for (int r = 0; r < 4; ++r)
                TS[wave * 16 + qd * 4 + r][16 * t + c] = f2h(acc[t][r]);
        __syncthreads();
        if (z == 1) {
            // kfrag[kt16][ks][lane] = K[kt16*16 + (lane&15)][ks*32 + 8*(lane>>4) + j]
#pragma unroll
            for (int i = 0; i < 4; ++i) {
                const int f = tid + 256 * i;          // 0..1023
                const int lf = f & 63, ks = (f >> 6) & 3, sub = f >> 8;
                const int key = sub * 16 + (lf & 15);
                const int d0  = ks * 32 + 8 * (lf >> 4);
                u32 w[4];
#pragma unroll
                for (int q = 0; q < 4; ++q)
                    w[q] = (u32)TS[key][d0 + 2 * q] | ((u32)TS[key][d0 + 2 * q + 1] << 16);
                kfrag[((size_t)(m0 / 16 + sub) * 4 + ks) * 64 + lf] = (u32x4){w[0], w[1], w[2], w[3]};
            }
        } else {
            // vfrag[kt32][t][lane] = V[kt32*32 + 8*(lane>>4) + j][16t + (lane&15)]
#pragma unroll
            for (int i = 0; i < 4; ++i) {
                const int f = tid + 256 * i;          // 0..1023
                const int lf = f & 63, t = (f >> 6) & 7, sub = f >> 9;
                const int kb2 = sub * 32 + 8 * (lf >> 4);
                const int dh  = 16 * t + (lf & 15);
                u32 w[4];
#pragma unroll
                for (int q = 0; q < 4; ++q)
                    w[q] = (u32)TS[kb2 + 2 * q][dh] | ((u32)TS[kb2 + 2 * q + 1][dh] << 16);
                vfrag[((size_t)(m0 / 32 + sub) * 8 + t) * 64 + lf] = (u32x4){w[0], w[1], w[2], w[3]};
            }
        }
    }
}

// ---------------- attention core: barrier-free, frags from global (L2-hot) ----------------
template <bool WRITE_PARTIAL>
__device__ __forceinline__ void attn_body(
    const u32* qp, const u32x4* __restrict__ kfrag, const u32x4* __restrict__ vfrag,
    u16* outO, u16* outL, float* cur,
    int b, int q0, int kt0, int kt1, int part)
{
    const int tid = threadIdx.x;
    const int wave = tid >> 6, lane = tid & 63;
    const int qd = lane >> 4, c = lane & 15;

    __shared__ u16 PB[4][531];   // per-wave P transpose (wave-private -> no barriers)

    H8 Qh[4];
    {
        const u32* qr = qp + ((size_t)b * S_ + q0 + wave * 16 + c) * DH;
#pragma unroll
        for (int ks = 0; ks < 4; ++ks) {
            uint4 e0 = *(const uint4*)(qr + ks * 32 + qd * 8);
            uint4 e1 = *(const uint4*)(qr + ks * 32 + qd * 8 + 4);
            Qh[ks].u[0] = permHI(e0.y, e0.x); Qh[ks].u[1] = permHI(e0.w, e0.z);
            Qh[ks].u[2] = permHI(e1.y, e1.x); Qh[ks].u[3] = permHI(e1.w, e1.z);
        }
    }

    f32x4 O[8] = {};
    float lsum[4] = {};

    const u32x4* kb0 = kfrag + (size_t)b * 128 * 256;   // kt16 stride = 4*64
    const u32x4* vb0 = vfrag + (size_t)b * 64 * 512;    // kt32 stride = 8*64

    for (int kt = kt0; kt < kt1; ++kt) {
        const u32x4* kf = kb0 + (size_t)kt * 512;       // two kt16 blocks
        const u32x4* vf = vb0 + (size_t)kt * 512;

        f32x4 S0 = {}, S1 = {};
#pragma unroll
        for (int ks = 0; ks < 4; ++ks) {
            H8 kh;
            kh.v = kf[ks * 64 + lane];
            S0 = __builtin_amdgcn_mfma_f32_16x16x32_f16(Qh[ks].h, kh.h, S0, 0, 0, 0);
            kh.v = kf[256 + ks * 64 + lane];
            S1 = __builtin_amdgcn_mfma_f32_16x16x32_f16(Qh[ks].h, kh.h, S1, 0, 0, 0);
        }

        u16* pw = PB[wave];
#pragma unroll
        for (int r = 0; r < 4; ++r) {
            float e0 = exp2f(fmaf(S0[r], SCALE2_, -4.0f));
            float e1 = exp2f(fmaf(S1[r], SCALE2_, -4.0f));
            lsum[r] += e0 + e1;
            pw[(4 * qd + r) * 33 + c]      = f2h(e0);
            pw[(4 * qd + r) * 33 + 16 + c] = f2h(e1);
        }

        u16 e[8];
#pragma unroll
        for (int j = 0; j < 8; ++j) e[j] = pw[c * 33 + 8 * qd + j];
        H8 Ph;
        Ph.u[0] = (u32)e[0] | ((u32)e[1] << 16);
        Ph.u[1] = (u32)e[2] | ((u32)e[3] << 16);
        Ph.u[2] = (u32)e[4] | ((u32)e[5] << 16);
        Ph.u[3] = (u32)e[6] | ((u32)e[7] << 16);

#pragma unroll
        for (int t = 0; t < 8; ++t) {
            H8 vh;
            vh.v = vf[t * 64 + lane];
            O[t] = __builtin_amdgcn_mfma_f32_16x16x32_f16(Ph.h, vh.h, O[t], 0, 0, 0);
        }
    }

    if (WRITE_PARTIAL) {
        float lred[4];
#pragma unroll
        for (int r = 0; r < 4; ++r) {
            float l = lsum[r];
            l += __shfl_xor(l, 1); l += __shfl_xor(l, 2);
            l += __shfl_xor(l, 4); l += __shfl_xor(l, 8);
            lred[r] = l;
        }
        const size_t rb = (size_t)b * S_ + q0 + wave * 16 + 4 * qd;
        u16* Op = outO + (size_t)part * ((size_t)BS_ * DH);
#pragma unroll
        for (int t = 0; t < 8; ++t)
#pragma unroll
            for (int r = 0; r < 4; ++r)
                Op[(rb + r) * DH + t * 16 + c] = f2h(O[t][r]);
        if (c == 0) {
            u16* lp = outL + (size_t)part * BS_;
#pragma unroll
            for (int r = 0; r < 4; ++r) lp[rb + r] = f2h(lred[r]);
        }
    } else {
        float linv[4];
#pragma unroll
        for (int r = 0; r < 4; ++r) {
            float l = lsum[r];
            l += __shfl_xor(l, 1); l += __shfl_xor(l, 2);
            l += __shfl_xor(l, 4); l += __shfl_xor(l, 8);
            linv[r] = 1.0f / l;
        }
        const size_t rb = (size_t)b * S_ + q0 + wave * 16 + 4 * qd;
#pragma unroll
        for (int t = 0; t < 8; ++t)
#pragma unroll
            for (int r = 0; r < 4; ++r)
                cur[(rb + r) * DH + t * 16 + c] = O[t][r] * linv[r];
    }
}

// single-pass fallback: grid (32, 8). XCD swizzle: batch = rid&7 (bijective).
__global__ __launch_bounds__(256) void attn_kernel(
    const u32* qp, const u32x4* __restrict__ kfrag, const u32x4* __restrict__ vfrag, float* cur)
{
    const int rid = blockIdx.x + 32 * blockIdx.y;
    attn_body<false>(qp, kfrag, vfrag, nullptr, nullptr, cur,
                     rid & 7, ((rid >> 3) & 31) * 64, 0, S_ / 32, 0);
}

// split-KV x4: grid (32, 8, 4) = 1024 blocks. batch = rid&7 per XCD.
__global__ __launch_bounds__(256) void attn_split_kernel(
    const u32* qp, const u32x4* __restrict__ kfrag, const u32x4* __restrict__ vfrag,
    u16* __restrict__ Opart, u16* __restrict__ lpart)
{
    const int rid = blockIdx.x + 32 * (blockIdx.y + 8 * blockIdx.z);
    const int b    = rid & 7;
    const int qx   = (rid >> 3) & 31;
    const int part = rid >> 8;
    const int quart = S_ / 128;   // 16 tiles per part
    attn_body<true>(qp, kfrag, vfrag, Opart, lpart, nullptr,
                    b, qx * 64, part * quart, (part + 1) * quart, part);
}

// combine: cur0 = sum_p O_p / sum_p l_p (f16 partials). grid 512 x 256, 16 elems/thread.
__global__ __launch_bounds__(256) void combine_kernel(
    const u16* __restrict__ Opart, const u16* __restrict__ lpart,
    float* __restrict__ cur)
{
    const size_t N1 = (size_t)BS_ * DH;
    const size_t i0 = ((size_t)blockIdx.x * 256 + threadIdx.x) * 16;
    const int row = (int)(i0 >> 7);
    const float lt = h2f(lpart[row]) + h2f(lpart[BS_ + row])
                   + h2f(lpart[2 * BS_ + row]) + h2f(lpart[3 * BS_ + row]);
    const float linv = 1.0f / lt;
    float acc[16] = {};
#pragma unroll
    for (int p = 0; p < 4; ++p) {
        const u16* op = Opart + (size_t)p * N1 + i0;
        uint4 v0 = *(const uint4*)op;
        uint4 v1 = *(const uint4*)(op + 8);
        const u32 w[8] = {v0.x, v0.y, v0.z, v0.w, v1.x, v1.y, v1.z, v1.w};
#pragma unroll
        for (int j = 0; j < 8; ++j) {
            acc[2 * j]     += h2f((u16)(w[j] & 0xffff));
            acc[2 * j + 1] += h2f((u16)(w[j] >> 16));
        }
    }
#pragma unroll
    for (int t = 0; t < 4; ++t)
        *(float4*)(cur + i0 + t * 4) = make_float4(
            acc[4*t] * linv, acc[4*t+1] * linv, acc[4*t+2] * linv, acc[4*t+3] * linv);
}

// ---------------- prepack round weights (straight repack, no algebra) ----------------
// mats: 0=tw, 1=w1[:,0:128], 2=w1[:,128:256], 3=w1[:,256:384], 4=w2
__global__ __launch_bounds__(256) void prepack_rw_kernel(
    const void* __restrict__ tw, const void* __restrict__ w1, const void* __restrict__ w2,
    const int* __restrict__ flag, u32x4* __restrict__ pk)
{
    const int isb = *flag;
    const int gid = blockIdx.x * 256 + threadIdx.x;   // 10240 total
    const int l = gid & 63, t = (gid >> 6) & 7, ks = (gid >> 9) & 3, mat = gid >> 11;
    const int row = 16 * t + (l & 15);
    const int k0  = ks * 32 + 8 * (l >> 4);
    float f[8];
    if (mat == 0)      ld8(tw, (size_t)row * DH + k0, isb, f);
    else if (mat <= 3) ld8(w1, (size_t)row * 384 + (mat - 1) * 128 + k0, isb, f);
    else               ld8(w2, (size_t)row * DH + k0, isb, f);
    u32x4 hi, lo;
    split8(f, hi, lo);
    const size_t base = (((size_t)mat * 4 + ks) * 16 + 2 * t) * 64 + l;
    pk[base] = hi; pk[base + 64] = lo;
}

// pre-split A fragments
struct Afrag { H8 h[4], l[4]; };
__device__ __forceinline__ void splitA(const float (&A)[4][8], Afrag& F) {
#pragma unroll
    for (int ks = 0; ks < 4; ++ks) split8(A[ks], F.h[ks].v, F.l[ks].v);
}
// 128x128 GEMM quarter over staged WB. When isb: weight lo-plane == 0 exactly ->
// skip the Ah x Bl term (bit-identical).
__device__ __forceinline__ void gemm_wb(const Afrag& F, const u32x4 (*WB)[16][64],
                                        const int lane, const int isb, f32x4 (&acc)[8])
{
#pragma unroll
    for (int ks = 0; ks < 4; ++ks) {
#pragma unroll
        for (int t = 0; t < 8; ++t) {
            H8 bh, bl;
            bh.v = WB[ks][2 * t][lane];
            bl.v = WB[ks][2 * t + 1][lane];
            acc[t] = __builtin_amdgcn_mfma_f32_16x16x32_f16(F.l[ks].h, bh.h, acc[t], 0, 0, 0);
            if (!isb)
                acc[t] = __builtin_amdgcn_mfma_f32_16x16x32_f16(F.h[ks].h, bl.h, acc[t], 0, 0, 0);
            acc[t] = __builtin_amdgcn_mfma_f32_16x16x32_f16(F.h[ks].h, bh.h, acc[t], 0, 0, 0);
        }
    }
}

// ---------------- one dialectic round: 64 tokens/block, MFMA ----------------
__global__ __launch_bounds__(256) void round_kernel(
    const float* cur0, const float* curr,
    const u32x4* __restrict__ pk,
    const void* __restrict__ tb, const void* __restrict__ ab,
    const void* __restrict__ b1, const void* __restrict__ b2,
    const void* __restrict__ gw, const void* __restrict__ gb,
    const int* __restrict__ flag, int* active, int* counts, int r,
    float* cur_out, void* dout)
{
    const int isb = *flag;
    const int tok0 = blockIdx.x * 64;
    const int tid = threadIdx.x;
    const bool last = (dout != nullptr);

    if (counts[r] <= 0) {
        if (last) {
            for (int e = tid; e < 64 * DH; e += 256) {
                size_t idx = (size_t)tok0 * DH + e;
                float v = curr[idx];
                if (isb) ((__hip_bfloat16*)dout)[idx] = __float2bfloat16(v);
                else     ((float*)dout)[idx] = v;
            }
        }
        return;
    }

    const int wave = tid >> 6, lane = tid & 63;
    const int qd = lane >> 4, c = lane & 15;

    __shared__ u32x4 WB[4][16][64];    // 64 KB weight stage buffer
    __shared__ float T0S[64][132];     // t0, later synth
    __shared__ float HSS[64][132];     // h
    __shared__ float actS[64], tbS[128], abS[128], b1S[128], b2S[128], gwS[256];
    __shared__ int blkcnt;

#define STAGE_RW(mat_)                                                             \
    {                                                                              \
        _Pragma("unroll")                                                          \
        for (int _j = 0; _j < 16; ++_j) {                                          \
            __builtin_amdgcn_global_load_lds(                                      \
                (const __attribute__((address_space(1))) u32*)(                    \
                    pk + (((size_t)(mat_) * 4 + wave) * 16 + _j) * 64 + lane),     \
                (__attribute__((address_space(3))) u32*)&WB[wave][_j][0],          \
                16, 0, 0);                                                         \
        }                                                                          \
    }

    STAGE_RW(0);   // tw
    if (tid < 64) actS[tid] = active[tok0 + tid] ? 1.0f : 0.0f;
    if (tid < 128) {
        tbS[tid] = ldE(tb, tid, isb); abS[tid] = ldE(ab, tid, isb);
        b1S[tid] = ldE(b1, tid, isb); b2S[tid] = ldE(b2, tid, isb);
    }
    gwS[tid] = ldE(gw, tid, isb);
    if (tid == 0) blkcnt = 0;
    const float gbf = ldE(gb, 0, isb);

    const int rowl = 16 * wave + c;      // this lane's A-row (local)
    const int hr   = 16 * wave + 4 * qd; // this lane's C-row base (local)

    float A1[4][8];
    {
        const float* cr = cur0 + (size_t)(tok0 + rowl) * DH;
#pragma unroll
        for (int ks = 0; ks < 4; ++ks) {
            *(float4*)&A1[ks][0] = *(const float4*)(cr + ks * 32 + 8 * qd);
            *(float4*)&A1[ks][4] = *(const float4*)(cr + ks * 32 + 8 * qd + 4);
        }
    }
    Afrag FA; splitA(A1, FA);
    __syncthreads();   // WB(tw) staged, consts visible

    // ---- GEMM t0 = cur0 @ tw^T ----
    {
        f32x4 acc[8] = {};
        gemm_wb(FA, WB, lane, isb, acc);
#pragma unroll
        for (int t = 0; t < 8; ++t)
#pragma unroll
            for (int rr = 0; rr < 4; ++rr)
                T0S[hr + rr][16 * t + c] = acc[t][rr];
    }
    __syncthreads();
    STAGE_RW(1);       // w1a

    f32x4 acc1[8] = {};
    const float am_r = actS[rowl];
    {
        float Ac[4][8];
#pragma unroll
        for (int ks = 0; ks < 4; ++ks)
#pragma unroll
            for (int j = 0; j < 8; ++j) {
                const int k = ks * 32 + 8 * qd + j;
                Ac[ks][j] = (T0S[rowl][k] + tbS[k]) * am_r;   // at
            }
        Afrag FC; splitA(Ac, FC);
        __syncthreads();
        gemm_wb(FC, WB, lane, isb, acc1);
    }
    __syncthreads();
    STAGE_RW(2);       // w1b
    {
        float Ac[4][8];
#pragma unroll
        for (int ks = 0; ks < 4; ++ks)
#pragma unroll
            for (int j = 0; j < 8; ++j) {
                const int k = ks * 32 + 8 * qd + j;
                Ac[ks][j] = (abS[k] - T0S[rowl][k]) * am_r;   // aa
            }
        Afrag FC; splitA(Ac, FC);
        __syncthreads();
        gemm_wb(FC, WB, lane, isb, acc1);
    }
    __syncthreads();
    STAGE_RW(3);       // w1c
    {
        float Ac[4][8];
        const float* cr = curr + (size_t)(tok0 + rowl) * DH;
#pragma unroll
        for (int ks = 0; ks < 4; ++ks) {
            float4 a0 = *(const float4*)(cr + ks * 32 + 8 * qd);
            float4 a1 = *(const float4*)(cr + ks * 32 + 8 * qd + 4);
            Ac[ks][0] = a0.x * am_r; Ac[ks][1] = a0.y * am_r;
            Ac[ks][2] = a0.z * am_r; Ac[ks][3] = a0.w * am_r;
            Ac[ks][4] = a1.x * am_r; Ac[ks][5] = a1.y * am_r;
            Ac[ks][6] = a1.z * am_r; Ac[ks][7] = a1.w * am_r;
        }
        Afrag FC; splitA(Ac, FC);
        __syncthreads();
        gemm_wb(FC, WB, lane, isb, acc1);
    }
#pragma unroll
    for (int t = 0; t < 8; ++t)
#pragma unroll
        for (int rr = 0; rr < 4; ++rr)
            HSS[hr + rr][16 * t + c] = fmaxf(acc1[t][rr] + b1S[16 * t + c], 0.0f);
    __syncthreads();
    STAGE_RW(4);       // w2
    {
        float Ac[4][8];
#pragma unroll
        for (int ks = 0; ks < 4; ++ks) {
            const float* hp = &HSS[rowl][ks * 32 + 8 * qd];
            *(float4*)&Ac[ks][0] = *(const float4*)hp;
            *(float4*)&Ac[ks][4] = *(const float4*)(hp + 4);
        }
        Afrag FC; splitA(Ac, FC);
        __syncthreads();
        f32x4 acc2[8] = {};
        gemm_wb(FC, WB, lane, isb, acc2);
#pragma unroll
        for (int t = 0; t < 8; ++t)
#pragma unroll
            for (int rr = 0; rr < 4; ++rr)
                T0S[hr + rr][16 * t + c] = acc2[t][rr] + b2S[16 * t + c];
    }
    __syncthreads();

    // ---- gate, update, norm, active ----
    const int tok = tid >> 2, d0 = (tid & 3) * 32;
    const float am = actS[tok];
    const float* cp = curr + (size_t)(tok0 + tok) * DH + d0;
    float cv[32];
#pragma unroll
    for (int t = 0; t < 8; ++t) {
        float4 vv = *(const float4*)(cp + t * 4);
        cv[t * 4] = vv.x; cv[t * 4 + 1] = vv.y; cv[t * 4 + 2] = vv.z; cv[t * 4 + 3] = vv.w;
    }
    const float* srow = &T0S[tok][d0];
    float gp = 0.0f;
#pragma unroll
    for (int e = 0; e < 32; ++e)
        gp += cv[e] * am * gwS[d0 + e] + srow[e] * gwS[128 + d0 + e];
    gp += __shfl_xor(gp, 1, 4);
    gp += __shfl_xor(gp, 2, 4);
    const float gate = 1.0f / (1.0f + __expf(-(gp + gbf)));
    float ss = 0.0f; float up[32];
#pragma unroll
    for (int e = 0; e < 32; ++e) {
        float u = gate * (srow[e] - cv[e] * am) * 0.1f;
        up[e] = u; ss += u * u;
    }
    ss += __shfl_xor(ss, 1, 4);
    ss += __shfl_xor(ss, 2, 4);
    const bool stable = sqrtf(ss) < 0.1f;

    if (last) {
        size_t off = (size_t)(tok0 + tok) * DH + d0;
        if (isb) {
            __hip_bfloat16* op = (__hip_bfloat16*)dout + off;
#pragma unroll
            for (int e = 0; e < 32; ++e) op[e] = __float2bfloat16(cv[e] + up[e]);
        } else {
            float* op = (float*)dout + off;
#pragma unroll
            for (int t = 0; t < 8; ++t)
                *(float4*)(op + t * 4) = make_float4(cv[t * 4] + up[t * 4], cv[t * 4 + 1] + up[t * 4 + 1],
                                                     cv[t * 4 + 2] + up[t * 4 + 2], cv[t * 4 + 3] + up[t * 4 + 3]);
        }
    } else {
        float* op = cur_out + (size_t)(tok0 + tok) * DH + d0;
#pragma unroll
        for (int t = 0; t < 8; ++t)
            *(float4*)(op + t * 4) = make_float4(cv[t * 4] + up[t * 4], cv[t * 4 + 1] + up[t * 4 + 1],
                                                 cv[t * 4 + 2] + up[t * 4 + 2], cv[t * 4 + 3] + up[t * 4 + 3]);
    }
    const int newact = (am > 0.0f && !stable) ? 1 : 0;
    if ((tid & 3) == 0) {
        active[tok0 + tok] = newact;
        if (newact) atomicAdd(&blkcnt, 1);
    }
    __syncthreads();
    if (tid == 0 && blkcnt > 0) atomicAdd(&counts[r + 1], blkcnt);
#undef STAGE_RW
}

extern "C" void kernel_launch(void* const* d_in, const int* in_sizes, int n_in,
                              void* d_out, int out_size, void* d_ws, size_t ws_size,
                              hipStream_t stream) {
    const void* x  = d_in[0];
    const void* wq = d_in[1];
    const void* wk = d_in[2];
    const void* wv = d_in[3];
    const void* tw = d_in[4];
    const void* tb = d_in[5];
    const void* ab = d_in[6];
    const void* w1 = d_in[7];
    const void* b1 = d_in[8];
    const void* w2 = d_in[9];
    const void* b2 = d_in[10];
    const void* gw = d_in[11];
    const void* gb = d_in[12];

    u32* ws = (u32*)d_ws;
    const size_t N1 = (size_t)BS_ * DH;
    // base layout (~24 MiB): qp | kp | vp | active | counts | flag
    u32* qp = ws;
    u32* kp = ws + N1;        // K MFMA-frags (4 MB used of 8 MB region)
    u32* vp = ws + 2 * N1;    // V MFMA-frags (4 MB used of 8 MB region)
    int* active = (int*)(ws + 3 * N1);
    int* counts = active + BS_;
    int* flag   = counts + 4;
    float* cur0  = (float*)qp;
    float* cur_r = (float*)kp;    // overwrites dead K-frags after attn
    // split-KV x4 extension (f16 partials), ends at 42.2 MB <= 42.3 MB guarantee
    u16* Opart16 = (u16*)(ws + 3 * N1 + 32768);
    u16* lpart16 = (u16*)(ws + 5 * N1 + 32768);
    const bool big_ws = ws_size >= (size_t)42300000;        // constant across calls
    // prepacked QKV W: transient in Opart region (dead before attention writes it)
    u32x4* wpk = (u32x4*)(ws + 3 * N1 + 32768);
    // prepacked round weights: in vp region (V-frags dead after attn), 320 KB
    u32x4* pkRW = (u32x4*)vp;
    u32x4* kfragP = (u32x4*)kp;
    u32x4* vfragP = (u32x4*)vp;

    init_kernel<<<dim3(BS_ / 256), 256, 0, stream>>>(x, flag, active, counts);
    prepack_w_kernel<<<dim3(192), 256, 0, stream>>>(wq, wk, wv, flag, wpk);
    qkv_kernel<<<dim3(BS_ / 64, 1, 3), 256, 0, stream>>>(x, wpk, flag, qp, kfragP, vfragP);
    if (big_ws) {
        attn_split_kernel<<<dim3(S_ / 64, B_, 4), 256, 0, stream>>>(qp, kfragP, vfragP, Opart16, lpart16);
        combine_kernel<<<dim3(512), 256, 0, stream>>>(Opart16, lpart16, cur0);
    } else {
        attn_kernel<<<dim3(S_ / 64, B_), 256, 0, stream>>>(qp, kfragP, vfragP, cur0);
    }
    prepack_rw_kernel<<<dim3(40), 256, 0, stream>>>(tw, w1, w2, flag, pkRW);
    round_kernel<<<dim3(BS_ / 64), 256, 0, stream>>>(
        cur0, cur0, pkRW, tb, ab, b1, b2, gw, gb, flag, active, counts, 0, cur_r, nullptr);
    round_kernel<<<dim3(BS_ / 64), 256, 0, stream>>>(
        cur0, cur_r, pkRW, tb, ab, b1, b2, gw, gb, flag, active, counts, 1, cur_r, nullptr);
    round_kernel<<<dim3(BS_ / 64), 256, 0, stream>>>(
        cur0, cur_r, pkRW, tb, ab, b1, b2, gw, gb, flag, active, counts, 2, cur_r, d_out);
}

// Round 10
// 261.335 us; speedup vs baseline: 1.3440x; 1.0199x over previous
//
#include <hip/hip_runtime.h>
#include <hip/hip_bf16.h>

#define B_   8
#define S_   2048
#define DM   1024
#define DH   128
#define BS_  16384
#define SCALE_  0.08838834764831845f
#define SCALE2_ 0.12751744f   // SCALE * log2(e)

typedef unsigned short u16;
typedef unsigned int   u32;
typedef _Float16 half8 __attribute__((ext_vector_type(8)));
typedef __bf16   bf16x8 __attribute__((ext_vector_type(8)));
typedef float    f32x4 __attribute__((ext_vector_type(4)));
typedef u32      u32x4 __attribute__((ext_vector_type(4)));

union H8 { u32x4 v; u32 u[4]; half8 h; bf16x8 b; };

__device__ __forceinline__ float bf2f(u16 u) {
    union { u32 i; float f; } w; w.i = ((u32)u) << 16; return w.f;
}
__device__ __forceinline__ void unpack8(uint4 v, float* f) {
    f[0] = bf2f(v.x & 0xffff); f[1] = bf2f(v.x >> 16);
    f[2] = bf2f(v.y & 0xffff); f[3] = bf2f(v.y >> 16);
    f[4] = bf2f(v.z & 0xffff); f[5] = bf2f(v.z >> 16);
    f[6] = bf2f(v.w & 0xffff); f[7] = bf2f(v.w >> 16);
}
__device__ __forceinline__ float ldE(const void* b, size_t i, int isbf16) {
    return isbf16 ? bf2f(((const u16*)b)[i]) : ((const float*)b)[i];
}
__device__ __forceinline__ void ld8(const void* b, size_t i, int isbf16, float* f) {
    if (isbf16) {
        unpack8(*(const uint4*)((const u16*)b + i), f);
    } else {
        float4 a = *(const float4*)((const float*)b + i);
        float4 c = *(const float4*)((const float*)b + i + 4);
        f[0] = a.x; f[1] = a.y; f[2] = a.z; f[3] = a.w;
        f[4] = c.x; f[5] = c.y; f[6] = c.z; f[7] = c.w;
    }
}
// fp32 -> packed (f16 hi << 16) | f16 lo  (2-term split, ~22 mantissa bits)
__device__ __forceinline__ u32 f2pk(float v) {
    _Float16 h = (_Float16)v;
    _Float16 l = (_Float16)(v - (float)h);
    union { _Float16 f; u16 u; } a, b; a.f = h; b.f = l;
    return ((u32)a.u << 16) | (u32)b.u;
}
// 8 floats -> pair-packed hi/lo frag u32x4
__device__ __forceinline__ void split8(const float* f, u32x4& hi, u32x4& lo) {
    u32 H[8], L[8];
#pragma unroll
    for (int j = 0; j < 8; ++j) {
        _Float16 h = (_Float16)f[j];
        _Float16 l = (_Float16)(f[j] - (float)h);
        union { _Float16 x; u16 u; } a, b; a.x = h; b.x = l;
        H[j] = a.u; L[j] = b.u;
    }
    hi = (u32x4){H[0] | (H[1] << 16), H[2] | (H[3] << 16), H[4] | (H[5] << 16), H[6] | (H[7] << 16)};
    lo = (u32x4){L[0] | (L[1] << 16), L[2] | (L[3] << 16), L[4] | (L[5] << 16), L[6] | (L[7] << 16)};
}
__device__ __forceinline__ u32 permHI(u32 eB, u32 eA) { return __builtin_amdgcn_perm(eB, eA, 0x07060302u); }
__device__ __forceinline__ u16 f2h(float v) { union { _Float16 f; u16 u; } a; a.f = (_Float16)v; return a.u; }
__device__ __forceinline__ float h2f(u16 u) { union { _Float16 f; u16 u; } a; a.u = u; return (float)a.f; }

// ---------------- init: dtype detect + active mask + round counters ----------------
__global__ void init_kernel(const void* x, int* flag, int* active, int* counts) {
    int i = blockIdx.x * 256 + threadIdx.x;
    if (i < BS_) active[i] = 1;
    if (i < 4) counts[i] = (i == 0) ? BS_ : 0;
    if (i == 0) {
        const u16* w = (const u16*)x;
        int sane = 0;
        for (int t = 0; t < 256; ++t) {
            int e = (w[2 * t] >> 7) & 0xFF;
            if (e >= 100 && e <= 135) ++sane;
        }
        *flag = (sane >= 192) ? 1 : 0;   // 1 = bf16, 0 = fp32
    }
}

// ---------------- prepack W into MFMA fragment layout ----------------
// bf16 path: hi slot = raw bf16 pairs (lo unused). fp32 path: f16 hi/lo split.
__global__ __launch_bounds__(256) void prepack_w_kernel(
    const void* __restrict__ wq, const void* __restrict__ wk, const void* __restrict__ wv,
    const int* __restrict__ flag, u32x4* __restrict__ wpk)
{
    const int isb = *flag;
    const int gid = blockIdx.x * 256 + threadIdx.x;
    const int l  = gid & 63;
    const int t  = (gid >> 6) & 7;
    const int ks = (gid >> 9) & 31;
    const int z  = gid >> 14;
    const void* W = (z == 0) ? wq : (z == 1) ? wk : wv;
    const int row = 16 * t + (l & 15);
    const int k0  = ks * 32 + 8 * (l >> 4);
    const size_t base = ((((size_t)z * 32 + ks) * 16) + 2 * t) * 64 + l;
    if (isb) {
        uint4 v = *(const uint4*)((const u16*)W + (size_t)row * DM + k0);
        wpk[base] = (u32x4){v.x, v.y, v.z, v.w};
    } else {
        float f[8];
        ld8(W, (size_t)row * DM + k0, 0, f);
        u32x4 hi, lo;
        split8(f, hi, lo);
        wpk[base]      = hi;
        wpk[base + 64] = lo;
    }
}

// ---------------- MFMA QKV ----------------
// z=0: write Q packs (hi|lo u32). z=1: K MFMA-frags. z=2: V MFMA-frags.
// bf16: native bf16 MFMA, BK=64 (2 K-steps per barrier), 32 KB LDS -> 5 blocks/CU.
__global__ __launch_bounds__(256) void qkv_kernel(
    const void* __restrict__ x, const u32x4* __restrict__ wpk,
    const int* __restrict__ flag, u32* __restrict__ qout,
    u32x4* __restrict__ kfrag, u32x4* __restrict__ vfrag)
{
    const int isb = *flag;
    const int z = blockIdx.z;
    // XCD swizzle (bijective on [0,256)): consecutive x-tiles stay on one XCD
    const int bx = blockIdx.x;
    const int m0 = ((bx & 7) * 32 + (bx >> 3)) * 64;
    const int tid = threadIdx.x;
    const int wave = tid >> 6, lane = tid & 63;
    const int qd = lane >> 4, c = lane & 15;

    __shared__ u32x4 WLraw[2][16][64];   // 32 KB; TS overlays after the loop
    // views
    u32x4 (*WLb)[2][8][64] = (u32x4(*)[2][8][64])WLraw;   // bf16: [buf][ksub][t][lane]
    u32x4 (*WLf)[8][2][64] = (u32x4(*)[8][2][64])WLraw;   // fp32: [buf][t][plane][lane]
    u16 (*TS)[136] = (u16(*)[136])WLraw;                  // 17.4 KB overlay

    const u32x4* wz = wpk + (size_t)z * (32 * 16 * 64);
    const size_t arow = (size_t)(m0 + wave * 16 + c) * DM + 8 * qd;

// bf16 BK=64 stage: iter i covers ks=2i,2i+1; 16 hi slabs, 4 per wave
#define STAGE2(i_, b_)                                                            \
    {                                                                             \
        _Pragma("unroll")                                                         \
        for (int _j = 0; _j < 4; ++_j) {                                          \
            const int _g = wave * 4 + _j, _ksub = _g >> 3, _t = _g & 7;           \
            __builtin_amdgcn_global_load_lds(                                     \
                (const __attribute__((address_space(1))) u32*)(                   \
                    wz + ((size_t)(2 * (i_) + _ksub) * 16 + 2 * _t) * 64 + lane), \
                (__attribute__((address_space(3))) u32*)&WLb[b_][_ksub][_t][0],   \
                16, 0, 0);                                                        \
        }                                                                         \
    }
// fp32 stage (1 K-step): 16 slabs (8 tiles x hi/lo), 4 per wave
#define STAGE_W(ks_, b_)                                                          \
    {                                                                             \
        const u32x4* _src = wz + ((size_t)(ks_) * 16 + 4 * wave) * 64 + lane;     \
        _Pragma("unroll")                                                         \
        for (int _j = 0; _j < 4; ++_j) {                                          \
            __builtin_amdgcn_global_load_lds(                                     \
                (const __attribute__((address_space(1))) u32*)(_src + _j * 64),   \
                (__attribute__((address_space(3))) u32*)&WLf[b_][2 * wave + (_j >> 1)][_j & 1][0], \
                16, 0, 0);                                                        \
        }                                                                         \
    }

    f32x4 acc[8] = {};

    if (isb) {
        const u16* xb = (const u16*)x;
        uint4 A0 = *(const uint4*)(xb + arow);
        uint4 A1 = *(const uint4*)(xb + arow + 32);
        STAGE2(0, 0);
        uint4 A0n = *(const uint4*)(xb + arow + 64);
        uint4 A1n = *(const uint4*)(xb + arow + 96);
        __syncthreads();
        for (int i = 0; i < 16; ++i) {
            const int cb = i & 1;
            if (i + 1 < 16) STAGE2(i + 1, cb ^ 1);
            H8 Ah0; Ah0.v = (u32x4){A0.x, A0.y, A0.z, A0.w};
            H8 Ah1; Ah1.v = (u32x4){A1.x, A1.y, A1.z, A1.w};
#pragma unroll
            for (int t = 0; t < 8; ++t) {
                H8 bh; bh.v = WLb[cb][0][t][lane];
                acc[t] = __builtin_amdgcn_mfma_f32_16x16x32_bf16(Ah0.b, bh.b, acc[t], 0, 0, 0);
            }
#pragma unroll
            for (int t = 0; t < 8; ++t) {
                H8 bh; bh.v = WLb[cb][1][t][lane];
                acc[t] = __builtin_amdgcn_mfma_f32_16x16x32_bf16(Ah1.b, bh.b, acc[t], 0, 0, 0);
            }
            A0 = A0n; A1 = A1n;
            if (i + 2 < 16) {
                A0n = *(const uint4*)(xb + arow + (size_t)(i + 2) * 64);
                A1n = *(const uint4*)(xb + arow + (size_t)(i + 2) * 64 + 32);
            }
            __syncthreads();
        }
    } else {
        float Ar[8], Arn[8];
        ld8(x, arow, 0, Ar);
        STAGE_W(0, 0);
        ld8(x, arow + 32, 0, Arn);
        __syncthreads();
        for (int ks = 0; ks < 32; ++ks) {
            const int cb = ks & 1;
            if (ks + 1 < 32) STAGE_W(ks + 1, cb ^ 1);
            H8 Ah, Al;
            split8(Ar, Ah.v, Al.v);
#pragma unroll
            for (int t = 0; t < 8; ++t) {
                H8 bh, bl;
                bh.v = WLf[cb][t][0][lane]; bl.v = WLf[cb][t][1][lane];
                acc[t] = __builtin_amdgcn_mfma_f32_16x16x32_f16(Al.h, bh.h, acc[t], 0, 0, 0);
                acc[t] = __builtin_amdgcn_mfma_f32_16x16x32_f16(Ah.h, bl.h, acc[t], 0, 0, 0);
                acc[t] = __builtin_amdgcn_mfma_f32_16x16x32_f16(Ah.h, bh.h, acc[t], 0, 0, 0);
            }
#pragma unroll
            for (int j = 0; j < 8; ++j) Ar[j] = Arn[j];
            if (ks + 2 < 32) ld8(x, arow + (size_t)(ks + 2) * 32, 0, Arn);
            __syncthreads();
        }
    }
#undef STAGE2
#undef STAGE_W

    if (z == 0) {
#pragma unroll
        for (int r = 0; r < 4; ++r) {
            const int row = m0 + wave * 16 + qd * 4 + r;
            u32* op = qout + (size_t)row * DH + c;
#pragma unroll
            for (int t = 0; t < 8; ++t) op[t * 16] = f2pk(acc[t][r]);
        }
    } else {
        // stage [key(local)][dh] f16 tile (overlays WL; loop's final barrier protects)
#pragma unroll
        for (int t = 0; t < 8; ++t)
#pragma unroll
            for (int r = 0; r < 4; ++r)
                TS[wave * 16 + qd * 4 + r][16 * t + c] = f2h(acc[t][r]);
        __syncthreads();
        if (z == 1) {
            // kfrag[kt16][ks][lane] = K[kt16*16 + (lane&15)][ks*32 + 8*(lane>>4) + j]
#pragma unroll
            for (int i = 0; i < 4; ++i) {
                const int f = tid + 256 * i;          // 0..1023
                const int lf = f & 63, ks = (f >> 6) & 3, sub = f >> 8;
                const int key = sub * 16 + (lf & 15);
                const int d0  = ks * 32 + 8 * (lf >> 4);
                u32 w[4];
#pragma unroll
                for (int q = 0; q < 4; ++q)
                    w[q] = (u32)TS[key][d0 + 2 * q] | ((u32)TS[key][d0 + 2 * q + 1] << 16);
                kfrag[((size_t)(m0 / 16 + sub) * 4 + ks) * 64 + lf] = (u32x4){w[0], w[1], w[2], w[3]};
            }
        } else {
            // vfrag[kt32][t][lane] = V[kt32*32 + 8*(lane>>4) + j][16t + (lane&15)]
#pragma unroll
            for (int i = 0; i < 4; ++i) {
                const int f = tid + 256 * i;          // 0..1023
                const int lf = f & 63, t = (f >> 6) & 7, sub = f >> 9;
                const int kb2 = sub * 32 + 8 * (lf >> 4);
                const int dh  = 16 * t + (lf & 15);
                u32 w[4];
#pragma unroll
                for (int q = 0; q < 4; ++q)
                    w[q] = (u32)TS[kb2 + 2 * q][dh] | ((u32)TS[kb2 + 2 * q + 1][dh] << 16);
                vfrag[((size_t)(m0 / 32 + sub) * 8 + t) * 64 + lf] = (u32x4){w[0], w[1], w[2], w[3]};
            }
        }
    }
}

// ---------------- attention core: barrier-free, frags from global (L2-hot) ----------------
template <bool WRITE_PARTIAL>
__device__ __forceinline__ void attn_body(
    const u32* qp, const u32x4* __restrict__ kfrag, const u32x4* __restrict__ vfrag,
    u16* outO, u16* outL, float* cur,
    int b, int q0, int kt0, int kt1, int part)
{
    const int tid = threadIdx.x;
    const int wave = tid >> 6, lane = tid & 63;
    const int qd = lane >> 4, c = lane & 15;

    __shared__ u16 PB[4][531];   // per-wave P transpose (wave-private -> no barriers)

    H8 Qh[4];
    {
        const u32* qr = qp + ((size_t)b * S_ + q0 + wave * 16 + c) * DH;
#pragma unroll
        for (int ks = 0; ks < 4; ++ks) {
            uint4 e0 = *(const uint4*)(qr + ks * 32 + qd * 8);
            uint4 e1 = *(const uint4*)(qr + ks * 32 + qd * 8 + 4);
            Qh[ks].u[0] = permHI(e0.y, e0.x); Qh[ks].u[1] = permHI(e0.w, e0.z);
            Qh[ks].u[2] = permHI(e1.y, e1.x); Qh[ks].u[3] = permHI(e1.w, e1.z);
        }
    }

    f32x4 O[8] = {};
    float lsum[4] = {};

    const u32x4* kb0 = kfrag + (size_t)b * 128 * 256;   // kt16 stride = 4*64
    const u32x4* vb0 = vfrag + (size_t)b * 64 * 512;    // kt32 stride = 8*64

    for (int kt = kt0; kt < kt1; ++kt) {
        const u32x4* kf = kb0 + (size_t)kt * 512;       // two kt16 blocks
        const u32x4* vf = vb0 + (size_t)kt * 512;

        f32x4 S0 = {}, S1 = {};
#pragma unroll
        for (int ks = 0; ks < 4; ++ks) {
            H8 kh;
            kh.v = kf[ks * 64 + lane];
            S0 = __builtin_amdgcn_mfma_f32_16x16x32_f16(Qh[ks].h, kh.h, S0, 0, 0, 0);
            kh.v = kf[256 + ks * 64 + lane];
            S1 = __builtin_amdgcn_mfma_f32_16x16x32_f16(Qh[ks].h, kh.h, S1, 0, 0, 0);
        }

        u16* pw = PB[wave];
#pragma unroll
        for (int r = 0; r < 4; ++r) {
            float e0 = exp2f(fmaf(S0[r], SCALE2_, -4.0f));
            float e1 = exp2f(fmaf(S1[r], SCALE2_, -4.0f));
            lsum[r] += e0 + e1;
            pw[(4 * qd + r) * 33 + c]      = f2h(e0);
            pw[(4 * qd + r) * 33 + 16 + c] = f2h(e1);
        }

        u16 e[8];
#pragma unroll
        for (int j = 0; j < 8; ++j) e[j] = pw[c * 33 + 8 * qd + j];
        H8 Ph;
        Ph.u[0] = (u32)e[0] | ((u32)e[1] << 16);
        Ph.u[1] = (u32)e[2] | ((u32)e[3] << 16);
        Ph.u[2] = (u32)e[4] | ((u32)e[5] << 16);
        Ph.u[3] = (u32)e[6] | ((u32)e[7] << 16);

#pragma unroll
        for (int t = 0; t < 8; ++t) {
            H8 vh;
            vh.v = vf[t * 64 + lane];
            O[t] = __builtin_amdgcn_mfma_f32_16x16x32_f16(Ph.h, vh.h, O[t], 0, 0, 0);
        }
    }

    if (WRITE_PARTIAL) {
        float lred[4];
#pragma unroll
        for (int r = 0; r < 4; ++r) {
            float l = lsum[r];
            l += __shfl_xor(l, 1); l += __shfl_xor(l, 2);
            l += __shfl_xor(l, 4); l += __shfl_xor(l, 8);
            lred[r] = l;
        }
        const size_t rb = (size_t)b * S_ + q0 + wave * 16 + 4 * qd;
        u16* Op = outO + (size_t)part * ((size_t)BS_ * DH);
#pragma unroll
        for (int t = 0; t < 8; ++t)
#pragma unroll
            for (int r = 0; r < 4; ++r)
                Op[(rb + r) * DH + t * 16 + c] = f2h(O[t][r]);
        if (c == 0) {
            u16* lp = outL + (size_t)part * BS_;
#pragma unroll
            for (int r = 0; r < 4; ++r) lp[rb + r] = f2h(lred[r]);
        }
    } else {
        float linv[4];
#pragma unroll
        for (int r = 0; r < 4; ++r) {
            float l = lsum[r];
            l += __shfl_xor(l, 1); l += __shfl_xor(l, 2);
            l += __shfl_xor(l, 4); l += __shfl_xor(l, 8);
            linv[r] = 1.0f / l;
        }
        const size_t rb = (size_t)b * S_ + q0 + wave * 16 + 4 * qd;
#pragma unroll
        for (int t = 0; t < 8; ++t)
#pragma unroll
            for (int r = 0; r < 4; ++r)
                cur[(rb + r) * DH + t * 16 + c] = O[t][r] * linv[r];
    }
}

// single-pass fallback: grid (32, 8). XCD swizzle: batch = rid&7 (bijective).
__global__ __launch_bounds__(256) void attn_kernel(
    const u32* qp, const u32x4* __restrict__ kfrag, const u32x4* __restrict__ vfrag, float* cur)
{
    const int rid = blockIdx.x + 32 * blockIdx.y;
    attn_body<false>(qp, kfrag, vfrag, nullptr, nullptr, cur,
                     rid & 7, ((rid >> 3) & 31) * 64, 0, S_ / 32, 0);
}

// split-KV x4: grid (32, 8, 4) = 1024 blocks. batch = rid&7 per XCD.
__global__ __launch_bounds__(256) void attn_split_kernel(
    const u32* qp, const u32x4* __restrict__ kfrag, const u32x4* __restrict__ vfrag,
    u16* __restrict__ Opart, u16* __restrict__ lpart)
{
    const int rid = blockIdx.x + 32 * (blockIdx.y + 8 * blockIdx.z);
    const int b    = rid & 7;
    const int qx   = (rid >> 3) & 31;
    const int part = rid >> 8;
    const int quart = S_ / 128;   // 16 tiles per part
    attn_body<true>(qp, kfrag, vfrag, Opart, lpart, nullptr,
                    b, qx * 64, part * quart, (part + 1) * quart, part);
}

// combine: cur0 = sum_p O_p / sum_p l_p (f16 partials). grid 512 x 256, 16 elems/thread.
__global__ __launch_bounds__(256) void combine_kernel(
    const u16* __restrict__ Opart, const u16* __restrict__ lpart,
    float* __restrict__ cur)
{
    const size_t N1 = (size_t)BS_ * DH;
    const size_t i0 = ((size_t)blockIdx.x * 256 + threadIdx.x) * 16;
    const int row = (int)(i0 >> 7);
    const float lt = h2f(lpart[row]) + h2f(lpart[BS_ + row])
                   + h2f(lpart[2 * BS_ + row]) + h2f(lpart[3 * BS_ + row]);
    const float linv = 1.0f / lt;
    float acc[16] = {};
#pragma unroll
    for (int p = 0; p < 4; ++p) {
        const u16* op = Opart + (size_t)p * N1 + i0;
        uint4 v0 = *(const uint4*)op;
        uint4 v1 = *(const uint4*)(op + 8);
        const u32 w[8] = {v0.x, v0.y, v0.z, v0.w, v1.x, v1.y, v1.z, v1.w};
#pragma unroll
        for (int j = 0; j < 8; ++j) {
            acc[2 * j]     += h2f((u16)(w[j] & 0xffff));
            acc[2 * j + 1] += h2f((u16)(w[j] >> 16));
        }
    }
#pragma unroll
    for (int t = 0; t < 4; ++t)
        *(float4*)(cur + i0 + t * 4) = make_float4(
            acc[4*t] * linv, acc[4*t+1] * linv, acc[4*t+2] * linv, acc[4*t+3] * linv);
}

// ---------------- prepack round weights (straight repack, no algebra) ----------------
// mats: 0=tw, 1=w1[:,0:128], 2=w1[:,128:256], 3=w1[:,256:384], 4=w2
__global__ __launch_bounds__(256) void prepack_rw_kernel(
    const void* __restrict__ tw, const void* __restrict__ w1, const void* __restrict__ w2,
    const int* __restrict__ flag, u32x4* __restrict__ pk)
{
    const int isb = *flag;
    const int gid = blockIdx.x * 256 + threadIdx.x;   // 10240 total
    const int l = gid & 63, t = (gid >> 6) & 7, ks = (gid >> 9) & 3, mat = gid >> 11;
    const int row = 16 * t + (l & 15);
    const int k0  = ks * 32 + 8 * (l >> 4);
    float f[8];
    if (mat == 0)      ld8(tw, (size_t)row * DH + k0, isb, f);
    else if (mat <= 3) ld8(w1, (size_t)row * 384 + (mat - 1) * 128 + k0, isb, f);
    else               ld8(w2, (size_t)row * DH + k0, isb, f);
    u32x4 hi, lo;
    split8(f, hi, lo);
    const size_t base = (((size_t)mat * 4 + ks) * 16 + 2 * t) * 64 + l;
    pk[base] = hi; pk[base + 64] = lo;
}

// pre-split A fragments
struct Afrag { H8 h[4], l[4]; };
__device__ __forceinline__ void splitA(const float (&A)[4][8], Afrag& F) {
#pragma unroll
    for (int ks = 0; ks < 4; ++ks) split8(A[ks], F.h[ks].v, F.l[ks].v);
}

// ---------------- one dialectic round: 64 tokens/block, MFMA, ~70 KB LDS ----------------
__global__ __launch_bounds__(256) void round_kernel(
    const float* cur0, const float* curr,
    const u32x4* __restrict__ pk,
    const void* __restrict__ tb, const void* __restrict__ ab,
    const void* __restrict__ b1, const void* __restrict__ b2,
    const void* __restrict__ gw, const void* __restrict__ gb,
    const int* __restrict__ flag, int* active, int* counts, int r,
    float* cur_out, void* dout)
{
    const int isb = *flag;
    const int tok0 = blockIdx.x * 64;
    const int tid = threadIdx.x;
    const bool last = (dout != nullptr);

    if (counts[r] <= 0) {
        if (last) {
            for (int e = tid; e < 64 * DH; e += 256) {
                size_t idx = (size_t)tok0 * DH + e;
                float v = curr[idx];
                if (isb) ((__hip_bfloat16*)dout)[idx] = __float2bfloat16(v);
                else     ((float*)dout)[idx] = v;
            }
        }
        return;
    }

    const int wave = tid >> 6, lane = tid & 63;
    const int qd = lane >> 4, c = lane & 15;

    __shared__ u32x4 WB[4][8][64];     // 32 KB weight stage buffer
    __shared__ u16 T0S[64][132];       // t0, later synth (f16, 16.9 KB)
    __shared__ u16 HSS[64][132];       // h (f16)
    __shared__ float actS[64], tbS[128], abS[128], b1S[128], b2S[128], gwS[256];
    __shared__ int blkcnt;

    // bf16: stage hi slabs only; WB[ks][t]
    auto stageB = [&](int mat) {
#pragma unroll
        for (int j = 0; j < 8; ++j) {
            __builtin_amdgcn_global_load_lds(
                (const __attribute__((address_space(1))) u32*)(
                    pk + (((size_t)mat * 4 + wave) * 16 + 2 * j) * 64 + lane),
                (__attribute__((address_space(3))) u32*)&WB[wave][j][0],
                16, 0, 0);
        }
    };
    // fp32: stage ks-pair {2h, 2h+1}, both planes; WB[kl*2+p][t]
    auto stageF = [&](int mat, int h) {
#pragma unroll
        for (int j = 0; j < 8; ++j) {
            const int g = wave * 8 + j, kl = g >> 4, p = (g >> 3) & 1, t = g & 7;
            __builtin_amdgcn_global_load_lds(
                (const __attribute__((address_space(1))) u32*)(
                    pk + (((size_t)mat * 4 + 2 * h + kl) * 16 + 2 * t + p) * 64 + lane),
                (__attribute__((address_space(3))) u32*)&WB[kl * 2 + p][t][0],
                16, 0, 0);
        }
    };
    auto gemmB = [&](const Afrag& F, f32x4 (&acc)[8]) {
#pragma unroll
        for (int ks = 0; ks < 4; ++ks)
#pragma unroll
            for (int t = 0; t < 8; ++t) {
                H8 bh; bh.v = WB[ks][t][lane];
                acc[t] = __builtin_amdgcn_mfma_f32_16x16x32_f16(F.l[ks].h, bh.h, acc[t], 0, 0, 0);
                acc[t] = __builtin_amdgcn_mfma_f32_16x16x32_f16(F.h[ks].h, bh.h, acc[t], 0, 0, 0);
            }
    };
    auto gemmF = [&](const Afrag& F, int h, f32x4 (&acc)[8]) {
#pragma unroll
        for (int kl = 0; kl < 2; ++kl) {
            const int ks = 2 * h + kl;
#pragma unroll
            for (int t = 0; t < 8; ++t) {
                H8 bh, bl;
                bh.v = WB[kl * 2][t][lane];
                bl.v = WB[kl * 2 + 1][t][lane];
                acc[t] = __builtin_amdgcn_mfma_f32_16x16x32_f16(F.l[ks].h, bh.h, acc[t], 0, 0, 0);
                acc[t] = __builtin_amdgcn_mfma_f32_16x16x32_f16(F.h[ks].h, bl.h, acc[t], 0, 0, 0);
                acc[t] = __builtin_amdgcn_mfma_f32_16x16x32_f16(F.h[ks].h, bh.h, acc[t], 0, 0, 0);
            }
        }
    };
    // run a full 128x128 GEMM over mat (WB first half already staged; barrier done by caller)
    auto runGemm = [&](int mat, const Afrag& F, f32x4 (&acc)[8]) {
        if (isb) {
            gemmB(F, acc);
        } else {
            gemmF(F, 0, acc);
            __syncthreads();
            stageF(mat, 1);
            __syncthreads();
            gemmF(F, 1, acc);
        }
    };

    if (isb) stageB(0); else stageF(0, 0);    // tw
    if (tid < 64) actS[tid] = active[tok0 + tid] ? 1.0f : 0.0f;
    if (tid < 128) {
        tbS[tid] = ldE(tb, tid, isb); abS[tid] = ldE(ab, tid, isb);
        b1S[tid] = ldE(b1, tid, isb); b2S[tid] = ldE(b2, tid, isb);
    }
    gwS[tid] = ldE(gw, tid, isb);
    if (tid == 0) blkcnt = 0;
    const float gbf = ldE(gb, 0, isb);

    const int rowl = 16 * wave + c;      // this lane's A-row (local)
    const int hr   = 16 * wave + 4 * qd; // this lane's C-row base (local)

    float A1[4][8];
    {
        const float* cr = cur0 + (size_t)(tok0 + rowl) * DH;
#pragma unroll
        for (int ks = 0; ks < 4; ++ks) {
            *(float4*)&A1[ks][0] = *(const float4*)(cr + ks * 32 + 8 * qd);
            *(float4*)&A1[ks][4] = *(const float4*)(cr + ks * 32 + 8 * qd + 4);
        }
    }
    Afrag FA; splitA(A1, FA);
    __syncthreads();   // staging (first half) done, consts visible

    // ---- GEMM t0 = cur0 @ tw^T ----
    {
        f32x4 acc[8] = {};
        runGemm(0, FA, acc);
#pragma unroll
        for (int t = 0; t < 8; ++t)
#pragma unroll
            for (int rr = 0; rr < 4; ++rr)
                T0S[hr + rr][16 * t + c] = f2h(acc[t][rr]);
    }
    __syncthreads();
    if (isb) stageB(1); else stageF(1, 0);    // w1a

    f32x4 acc1[8] = {};
    const float am_r = actS[rowl];
    {
        float Ac[4][8];
#pragma unroll
        for (int ks = 0; ks < 4; ++ks)
#pragma unroll
            for (int j = 0; j < 8; ++j) {
                const int k = ks * 32 + 8 * qd + j;
                Ac[ks][j] = (h2f(T0S[rowl][k]) + tbS[k]) * am_r;   // at
            }
        Afrag FC; splitA(Ac, FC);
        __syncthreads();
        runGemm(1, FC, acc1);
    }
    __syncthreads();
    if (isb) stageB(2); else stageF(2, 0);    // w1b
    {
        float Ac[4][8];
#pragma unroll
        for (int ks = 0; ks < 4; ++ks)
#pragma unroll
            for (int j = 0; j < 8; ++j) {
                const int k = ks * 32 + 8 * qd + j;
                Ac[ks][j] = (abS[k] - h2f(T0S[rowl][k])) * am_r;   // aa
            }
        Afrag FC; splitA(Ac, FC);
        __syncthreads();
        runGemm(2, FC, acc1);
    }
    __syncthreads();
    if (isb) stageB(3); else stageF(3, 0);    // w1c
    {
        float Ac[4][8];
        const float* cr = curr + (size_t)(tok0 + rowl) * DH;
#pragma unroll
        for (int ks = 0; ks < 4; ++ks) {
            float4 a0 = *(const float4*)(cr + ks * 32 + 8 * qd);
            float4 a1 = *(const float4*)(cr + ks * 32 + 8 * qd + 4);
            Ac[ks][0] = a0.x * am_r; Ac[ks][1] = a0.y * am_r;
            Ac[ks][2] = a0.z * am_r; Ac[ks][3] = a0.w * am_r;
            Ac[ks][4] = a1.x * am_r; Ac[ks][5] = a1.y * am_r;
            Ac[ks][6] = a1.z * am_r; Ac[ks][7] = a1.w * am_r;
        }
        Afrag FC; splitA(Ac, FC);
        __syncthreads();
        runGemm(3, FC, acc1);
    }
#pragma unroll
    for (int t = 0; t < 8; ++t)
#pragma unroll
        for (int rr = 0; rr < 4; ++rr)
            HSS[hr + rr][16 * t + c] = f2h(fmaxf(acc1[t][rr] + b1S[16 * t + c], 0.0f));
    __syncthreads();
    if (isb) stageB(4); else stageF(4, 0);    // w2
    {
        float Ac[4][8];
#pragma unroll
        for (int ks = 0; ks < 4; ++ks)
#pragma unroll
            for (int j = 0; j < 8; ++j)
                Ac[ks][j] = h2f(HSS[rowl][ks * 32 + 8 * qd + j]);
        Afrag FC; splitA(Ac, FC);
        __syncthreads();
        f32x4 acc2[8] = {};
        runGemm(4, FC, acc2);
#pragma unroll
        for (int t = 0; t < 8; ++t)
#pragma unroll
            for (int rr = 0; rr < 4; ++rr)
                T0S[hr + rr][16 * t + c] = f2h(acc2[t][rr] + b2S[16 * t + c]);
    }
    __syncthreads();

    // ---- gate, update, norm, active ----
    const int tok = tid >> 2, d0 = (tid & 3) * 32;
    const float am = actS[tok];
    const float* cp = curr + (size_t)(tok0 + tok) * DH + d0;
    float cv[32];
#pragma unroll
    for (int t = 0; t < 8; ++t) {
        float4 vv = *(const float4*)(cp + t * 4);
        cv[t * 4] = vv.x; cv[t * 4 + 1] = vv.y; cv[t * 4 + 2] = vv.z; cv[t * 4 + 3] = vv.w;
    }
    float srow[32];
#pragma unroll
    for (int e = 0; e < 32; ++e) srow[e] = h2f(T0S[tok][d0 + e]);
    float gp = 0.0f;
#pragma unroll
    for (int e = 0; e < 32; ++e)
        gp += cv[e] * am * gwS[d0 + e] + srow[e] * gwS[128 + d0 + e];
    gp += __shfl_xor(gp, 1, 4);
    gp += __shfl_xor(gp, 2, 4);
    const float gate = 1.0f / (1.0f + __expf(-(gp + gbf)));
    float ss = 0.0f; float up[32];
#pragma unroll
    for (int e = 0; e < 32; ++e) {
        float u = gate * (srow[e] - cv[e] * am) * 0.1f;
        up[e] = u; ss += u * u;
    }
    ss += __shfl_xor(ss, 1, 4);
    ss += __shfl_xor(ss, 2, 4);
    const bool stable = sqrtf(ss) < 0.1f;

    if (last) {
        size_t off = (size_t)(tok0 + tok) * DH + d0;
        if (isb) {
            __hip_bfloat16* op = (__hip_bfloat16*)dout + off;
#pragma unroll
            for (int e = 0; e < 32; ++e) op[e] = __float2bfloat16(cv[e] + up[e]);
        } else {
            float* op = (float*)dout + off;
#pragma unroll
            for (int t = 0; t < 8; ++t)
                *(float4*)(op + t * 4) = make_float4(cv[t * 4] + up[t * 4], cv[t * 4 + 1] + up[t * 4 + 1],
                                                     cv[t * 4 + 2] + up[t * 4 + 2], cv[t * 4 + 3] + up[t * 4 + 3]);
        }
    } else {
        float* op = cur_out + (size_t)(tok0 + tok) * DH + d0;
#pragma unroll
        for (int t = 0; t < 8; ++t)
            *(float4*)(op + t * 4) = make_float4(cv[t * 4] + up[t * 4], cv[t * 4 + 1] + up[t * 4 + 1],
                                                 cv[t * 4 + 2] + up[t * 4 + 2], cv[t * 4 + 3] + up[t * 4 + 3]);
    }
    const int newact = (am > 0.0f && !stable) ? 1 : 0;
    if ((tid & 3) == 0) {
        active[tok0 + tok] = newact;
        if (newact) atomicAdd(&blkcnt, 1);
    }
    __syncthreads();
    if (tid == 0 && blkcnt > 0) atomicAdd(&counts[r + 1], blkcnt);
}

extern "C" void kernel_launch(void* const* d_in, const int* in_sizes, int n_in,
                              void* d_out, int out_size, void* d_ws, size_t ws_size,
                              hipStream_t stream) {
    const void* x  = d_in[0];
    const void* wq = d_in[1];
    const void* wk = d_in[2];
    const void* wv = d_in[3];
    const void* tw = d_in[4];
    const void* tb = d_in[5];
    const void* ab = d_in[6];
    const void* w1 = d_in[7];
    const void* b1 = d_in[8];
    const void* w2 = d_in[9];
    const void* b2 = d_in[10];
    const void* gw = d_in[11];
    const void* gb = d_in[12];

    u32* ws = (u32*)d_ws;
    const size_t N1 = (size_t)BS_ * DH;
    // base layout (~24 MiB): qp | kp | vp | active | counts | flag
    u32* qp = ws;
    u32* kp = ws + N1;        // K MFMA-frags (4 MB used of 8 MB region)
    u32* vp = ws + 2 * N1;    // V MFMA-frags (4 MB used of 8 MB region)
    int* active = (int*)(ws + 3 * N1);
    int* counts = active + BS_;
    int* flag   = counts + 4;
    float* cur0  = (float*)qp;
    float* cur_r = (float*)kp;    // overwrites dead K-frags after attn
    // split-KV x4 extension (f16 partials), ends at 42.2 MB <= 42.3 MB guarantee
    u16* Opart16 = (u16*)(ws + 3 * N1 + 32768);
    u16* lpart16 = (u16*)(ws + 5 * N1 + 32768);
    const bool big_ws = ws_size >= (size_t)42300000;        // constant across calls
    // prepacked QKV W: transient in Opart region (dead before attention writes it)
    u32x4* wpk = (u32x4*)(ws + 3 * N1 + 32768);
    // prepacked round weights: in vp region (V-frags dead after attn), 320 KB
    u32x4* pkRW = (u32x4*)vp;
    u32x4* kfragP = (u32x4*)kp;
    u32x4* vfragP = (u32x4*)vp;

    init_kernel<<<dim3(BS_ / 256), 256, 0, stream>>>(x, flag, active, counts);
    prepack_w_kernel<<<dim3(192), 256, 0, stream>>>(wq, wk, wv, flag, wpk);
    qkv_kernel<<<dim3(BS_ / 64, 1, 3), 256, 0, stream>>>(x, wpk, flag, qp, kfragP, vfragP);
    if (big_ws) {
        attn_split_kernel<<<dim3(S_ / 64, B_, 4), 256, 0, stream>>>(qp, kfragP, vfragP, Opart16, lpart16);
        combine_kernel<<<dim3(512), 256, 0, stream>>>(Opart16, lpart16, cur0);
    } else {
        attn_kernel<<<dim3(S_ / 64, B_), 256, 0, stream>>>(qp, kfragP, vfragP, cur0);
    }
    prepack_rw_kernel<<<dim3(40), 256, 0, stream>>>(tw, w1, w2, flag, pkRW);
    round_kernel<<<dim3(BS_ / 64), 256, 0, stream>>>(
        cur0, cur0, pkRW, tb, ab, b1, b2, gw, gb, flag, active, counts, 0, cur_r, nullptr);
    round_kernel<<<dim3(BS_ / 64), 256, 0, stream>>>(
        cur0, cur_r, pkRW, tb, ab, b1, b2, gw, gb, flag, active, counts, 1, cur_r, nullptr);
    round_kernel<<<dim3(BS_ / 64), 256, 0, stream>>>(
        cur0, cur_r, pkRW, tb, ab, b1, b2, gw, gb, flag, active, counts, 2, cur_r, d_out);
}

// Round 11
// 258.257 us; speedup vs baseline: 1.3600x; 1.0119x over previous
//
#include <hip/hip_runtime.h>
#include <hip/hip_bf16.h>

#define B_   8
#define S_   2048
#define DM   1024
#define DH   128
#define BS_  16384
#define SCALE_  0.08838834764831845f
#define SCALE2_ 0.12751744f   // SCALE * log2(e)

typedef unsigned short u16;
typedef unsigned int   u32;
typedef _Float16 half8 __attribute__((ext_vector_type(8)));
typedef __bf16   bf16x8 __attribute__((ext_vector_type(8)));
typedef float    f32x4 __attribute__((ext_vector_type(4)));
typedef u32      u32x4 __attribute__((ext_vector_type(4)));

union H8 { u32x4 v; u32 u[4]; half8 h; bf16x8 b; };

__device__ __forceinline__ float bf2f(u16 u) {
    union { u32 i; float f; } w; w.i = ((u32)u) << 16; return w.f;
}
__device__ __forceinline__ void unpack8(uint4 v, float* f) {
    f[0] = bf2f(v.x & 0xffff); f[1] = bf2f(v.x >> 16);
    f[2] = bf2f(v.y & 0xffff); f[3] = bf2f(v.y >> 16);
    f[4] = bf2f(v.z & 0xffff); f[5] = bf2f(v.z >> 16);
    f[6] = bf2f(v.w & 0xffff); f[7] = bf2f(v.w >> 16);
}
__device__ __forceinline__ float ldE(const void* b, size_t i, int isbf16) {
    return isbf16 ? bf2f(((const u16*)b)[i]) : ((const float*)b)[i];
}
__device__ __forceinline__ void ld8(const void* b, size_t i, int isbf16, float* f) {
    if (isbf16) {
        unpack8(*(const uint4*)((const u16*)b + i), f);
    } else {
        float4 a = *(const float4*)((const float*)b + i);
        float4 c = *(const float4*)((const float*)b + i + 4);
        f[0] = a.x; f[1] = a.y; f[2] = a.z; f[3] = a.w;
        f[4] = c.x; f[5] = c.y; f[6] = c.z; f[7] = c.w;
    }
}
// fp32 -> packed (f16 hi << 16) | f16 lo  (2-term split, ~22 mantissa bits)
__device__ __forceinline__ u32 f2pk(float v) {
    _Float16 h = (_Float16)v;
    _Float16 l = (_Float16)(v - (float)h);
    union { _Float16 f; u16 u; } a, b; a.f = h; b.f = l;
    return ((u32)a.u << 16) | (u32)b.u;
}
// 8 floats -> pair-packed hi/lo frag u32x4
__device__ __forceinline__ void split8(const float* f, u32x4& hi, u32x4& lo) {
    u32 H[8], L[8];
#pragma unroll
    for (int j = 0; j < 8; ++j) {
        _Float16 h = (_Float16)f[j];
        _Float16 l = (_Float16)(f[j] - (float)h);
        union { _Float16 x; u16 u; } a, b; a.x = h; b.x = l;
        H[j] = a.u; L[j] = b.u;
    }
    hi = (u32x4){H[0] | (H[1] << 16), H[2] | (H[3] << 16), H[4] | (H[5] << 16), H[6] | (H[7] << 16)};
    lo = (u32x4){L[0] | (L[1] << 16), L[2] | (L[3] << 16), L[4] | (L[5] << 16), L[6] | (L[7] << 16)};
}
__device__ __forceinline__ u32 permHI(u32 eB, u32 eA) { return __builtin_amdgcn_perm(eB, eA, 0x07060302u); }
__device__ __forceinline__ u16 f2h(float v) { union { _Float16 f; u16 u; } a; a.f = (_Float16)v; return a.u; }
__device__ __forceinline__ float h2f(u16 u) { union { _Float16 f; u16 u; } a; a.u = u; return (float)a.f; }

// ---------------- init: dtype detect + active mask + round counters ----------------
__global__ void init_kernel(const void* x, int* flag, int* active, int* counts) {
    int i = blockIdx.x * 256 + threadIdx.x;
    if (i < BS_) active[i] = 1;
    if (i < 4) counts[i] = (i == 0) ? BS_ : 0;
    if (i == 0) {
        const u16* w = (const u16*)x;
        int sane = 0;
        for (int t = 0; t < 256; ++t) {
            int e = (w[2 * t] >> 7) & 0xFF;
            if (e >= 100 && e <= 135) ++sane;
        }
        *flag = (sane >= 192) ? 1 : 0;   // 1 = bf16, 0 = fp32
    }
}

// ---------------- prepack W into MFMA fragment layout ----------------
// bf16 path: hi slot = raw bf16 pairs (lo unused). fp32 path: f16 hi/lo split.
__global__ __launch_bounds__(256) void prepack_w_kernel(
    const void* __restrict__ wq, const void* __restrict__ wk, const void* __restrict__ wv,
    const int* __restrict__ flag, u32x4* __restrict__ wpk)
{
    const int isb = *flag;
    const int gid = blockIdx.x * 256 + threadIdx.x;
    const int l  = gid & 63;
    const int t  = (gid >> 6) & 7;
    const int ks = (gid >> 9) & 31;
    const int z  = gid >> 14;
    const void* W = (z == 0) ? wq : (z == 1) ? wk : wv;
    const int row = 16 * t + (l & 15);
    const int k0  = ks * 32 + 8 * (l >> 4);
    const size_t base = ((((size_t)z * 32 + ks) * 16) + 2 * t) * 64 + l;
    if (isb) {
        uint4 v = *(const uint4*)((const u16*)W + (size_t)row * DM + k0);
        wpk[base] = (u32x4){v.x, v.y, v.z, v.w};
    } else {
        float f[8];
        ld8(W, (size_t)row * DM + k0, 0, f);
        u32x4 hi, lo;
        split8(f, hi, lo);
        wpk[base]      = hi;
        wpk[base + 64] = lo;
    }
}

// ---------------- MFMA QKV ----------------
// z=0: write Q packs (hi|lo u32). z=1: K MFMA-frags. z=2: V MFMA-frags.
// bf16: native bf16 MFMA, BK=64 (2 K-steps per barrier), 32 KB LDS -> 5 blocks/CU.
__global__ __launch_bounds__(256) void qkv_kernel(
    const void* __restrict__ x, const u32x4* __restrict__ wpk,
    const int* __restrict__ flag, u32* __restrict__ qout,
    u32x4* __restrict__ kfrag, u32x4* __restrict__ vfrag)
{
    const int isb = *flag;
    const int z = blockIdx.z;
    // XCD swizzle (bijective on [0,256)): consecutive x-tiles stay on one XCD
    const int bx = blockIdx.x;
    const int m0 = ((bx & 7) * 32 + (bx >> 3)) * 64;
    const int tid = threadIdx.x;
    const int wave = tid >> 6, lane = tid & 63;
    const int qd = lane >> 4, c = lane & 15;

    __shared__ u32x4 WLraw[2][16][64];   // 32 KB; TS overlays after the loop
    // views
    u32x4 (*WLb)[2][8][64] = (u32x4(*)[2][8][64])WLraw;   // bf16: [buf][ksub][t][lane]
    u32x4 (*WLf)[8][2][64] = (u32x4(*)[8][2][64])WLraw;   // fp32: [buf][t][plane][lane]
    u16 (*TS)[136] = (u16(*)[136])WLraw;                  // 17.4 KB overlay

    const u32x4* wz = wpk + (size_t)z * (32 * 16 * 64);
    const size_t arow = (size_t)(m0 + wave * 16 + c) * DM + 8 * qd;

// bf16 BK=64 stage: iter i covers ks=2i,2i+1; 16 hi slabs, 4 per wave
#define STAGE2(i_, b_)                                                            \
    {                                                                             \
        _Pragma("unroll")                                                         \
        for (int _j = 0; _j < 4; ++_j) {                                          \
            const int _g = wave * 4 + _j, _ksub = _g >> 3, _t = _g & 7;           \
            __builtin_amdgcn_global_load_lds(                                     \
                (const __attribute__((address_space(1))) u32*)(                   \
                    wz + ((size_t)(2 * (i_) + _ksub) * 16 + 2 * _t) * 64 + lane), \
                (__attribute__((address_space(3))) u32*)&WLb[b_][_ksub][_t][0],   \
                16, 0, 0);                                                        \
        }                                                                         \
    }
// fp32 stage (1 K-step): 16 slabs (8 tiles x hi/lo), 4 per wave
#define STAGE_W(ks_, b_)                                                          \
    {                                                                             \
        const u32x4* _src = wz + ((size_t)(ks_) * 16 + 4 * wave) * 64 + lane;     \
        _Pragma("unroll")                                                         \
        for (int _j = 0; _j < 4; ++_j) {                                          \
            __builtin_amdgcn_global_load_lds(                                     \
                (const __attribute__((address_space(1))) u32*)(_src + _j * 64),   \
                (__attribute__((address_space(3))) u32*)&WLf[b_][2 * wave + (_j >> 1)][_j & 1][0], \
                16, 0, 0);                                                        \
        }                                                                         \
    }

    f32x4 acc[8] = {};

    if (isb) {
        const u16* xb = (const u16*)x;
        uint4 A0 = *(const uint4*)(xb + arow);
        uint4 A1 = *(const uint4*)(xb + arow + 32);
        STAGE2(0, 0);
        uint4 A0n = *(const uint4*)(xb + arow + 64);
        uint4 A1n = *(const uint4*)(xb + arow + 96);
        __syncthreads();
        for (int i = 0; i < 16; ++i) {
            const int cb = i & 1;
            if (i + 1 < 16) STAGE2(i + 1, cb ^ 1);
            H8 Ah0; Ah0.v = (u32x4){A0.x, A0.y, A0.z, A0.w};
            H8 Ah1; Ah1.v = (u32x4){A1.x, A1.y, A1.z, A1.w};
#pragma unroll
            for (int t = 0; t < 8; ++t) {
                H8 bh; bh.v = WLb[cb][0][t][lane];
                acc[t] = __builtin_amdgcn_mfma_f32_16x16x32_bf16(Ah0.b, bh.b, acc[t], 0, 0, 0);
            }
#pragma unroll
            for (int t = 0; t < 8; ++t) {
                H8 bh; bh.v = WLb[cb][1][t][lane];
                acc[t] = __builtin_amdgcn_mfma_f32_16x16x32_bf16(Ah1.b, bh.b, acc[t], 0, 0, 0);
            }
            A0 = A0n; A1 = A1n;
            if (i + 2 < 16) {
                A0n = *(const uint4*)(xb + arow + (size_t)(i + 2) * 64);
                A1n = *(const uint4*)(xb + arow + (size_t)(i + 2) * 64 + 32);
            }
            __syncthreads();
        }
    } else {
        float Ar[8], Arn[8];
        ld8(x, arow, 0, Ar);
        STAGE_W(0, 0);
        ld8(x, arow + 32, 0, Arn);
        __syncthreads();
        for (int ks = 0; ks < 32; ++ks) {
            const int cb = ks & 1;
            if (ks + 1 < 32) STAGE_W(ks + 1, cb ^ 1);
            H8 Ah, Al;
            split8(Ar, Ah.v, Al.v);
#pragma unroll
            for (int t = 0; t < 8; ++t) {
                H8 bh, bl;
                bh.v = WLf[cb][t][0][lane]; bl.v = WLf[cb][t][1][lane];
                acc[t] = __builtin_amdgcn_mfma_f32_16x16x32_f16(Al.h, bh.h, acc[t], 0, 0, 0);
                acc[t] = __builtin_amdgcn_mfma_f32_16x16x32_f16(Ah.h, bl.h, acc[t], 0, 0, 0);
                acc[t] = __builtin_amdgcn_mfma_f32_16x16x32_f16(Ah.h, bh.h, acc[t], 0, 0, 0);
            }
#pragma unroll
            for (int j = 0; j < 8; ++j) Ar[j] = Arn[j];
            if (ks + 2 < 32) ld8(x, arow + (size_t)(ks + 2) * 32, 0, Arn);
            __syncthreads();
        }
    }
#undef STAGE2
#undef STAGE_W

    if (z == 0) {
#pragma unroll
        for (int r = 0; r < 4; ++r) {
            const int row = m0 + wave * 16 + qd * 4 + r;
            u32* op = qout + (size_t)row * DH + c;
#pragma unroll
            for (int t = 0; t < 8; ++t) op[t * 16] = f2pk(acc[t][r]);
        }
    } else {
        // stage [key(local)][dh] f16 tile (overlays WL; loop's final barrier protects)
#pragma unroll
        for (int t = 0; t < 8; ++t)
#pragma unroll
            for (int r = 0; r < 4; ++r)
                TS[wave * 16 + qd * 4 + r][16 * t + c] = f2h(acc[t][r]);
        __syncthreads();
        if (z == 1) {
            // kfrag[kt16][ks][lane] = K[kt16*16 + (lane&15)][ks*32 + 8*(lane>>4) + j]
#pragma unroll
            for (int i = 0; i < 4; ++i) {
                const int f = tid + 256 * i;          // 0..1023
                const int lf = f & 63, ks = (f >> 6) & 3, sub = f >> 8;
                const int key = sub * 16 + (lf & 15);
                const int d0  = ks * 32 + 8 * (lf >> 4);
                u32 w[4];
#pragma unroll
                for (int q = 0; q < 4; ++q)
                    w[q] = (u32)TS[key][d0 + 2 * q] | ((u32)TS[key][d0 + 2 * q + 1] << 16);
                kfrag[((size_t)(m0 / 16 + sub) * 4 + ks) * 64 + lf] = (u32x4){w[0], w[1], w[2], w[3]};
            }
        } else {
            // vfrag[kt32][t][lane] = V[kt32*32 + 8*(lane>>4) + j][16t + (lane&15)]
#pragma unroll
            for (int i = 0; i < 4; ++i) {
                const int f = tid + 256 * i;          // 0..1023
                const int lf = f & 63, t = (f >> 6) & 7, sub = f >> 9;
                const int kb2 = sub * 32 + 8 * (lf >> 4);
                const int dh  = 16 * t + (lf & 15);
                u32 w[4];
#pragma unroll
                for (int q = 0; q < 4; ++q)
                    w[q] = (u32)TS[kb2 + 2 * q][dh] | ((u32)TS[kb2 + 2 * q + 1][dh] << 16);
                vfrag[((size_t)(m0 / 32 + sub) * 8 + t) * 64 + lf] = (u32x4){w[0], w[1], w[2], w[3]};
            }
        }
    }
}

// ---------------- attention core: barrier-free, frags from global (L2-hot) ----------------
template <bool WRITE_PARTIAL>
__device__ __forceinline__ void attn_body(
    const u32* qp, const u32x4* __restrict__ kfrag, const u32x4* __restrict__ vfrag,
    u16* outO, u16* outL, float* cur,
    int b, int q0, int kt0, int kt1, int part)
{
    const int tid = threadIdx.x;
    const int wave = tid >> 6, lane = tid & 63;
    const int qd = lane >> 4, c = lane & 15;

    __shared__ u16 PB[4][531];   // per-wave P transpose (wave-private -> no barriers)

    H8 Qh[4];
    {
        const u32* qr = qp + ((size_t)b * S_ + q0 + wave * 16 + c) * DH;
#pragma unroll
        for (int ks = 0; ks < 4; ++ks) {
            uint4 e0 = *(const uint4*)(qr + ks * 32 + qd * 8);
            uint4 e1 = *(const uint4*)(qr + ks * 32 + qd * 8 + 4);
            Qh[ks].u[0] = permHI(e0.y, e0.x); Qh[ks].u[1] = permHI(e0.w, e0.z);
            Qh[ks].u[2] = permHI(e1.y, e1.x); Qh[ks].u[3] = permHI(e1.w, e1.z);
        }
    }

    f32x4 O[8] = {};
    float lsum[4] = {};

    const u32x4* kb0 = kfrag + (size_t)b * 128 * 256;   // kt16 stride = 4*64
    const u32x4* vb0 = vfrag + (size_t)b * 64 * 512;    // kt32 stride = 8*64

    for (int kt = kt0; kt < kt1; ++kt) {
        const u32x4* kf = kb0 + (size_t)kt * 512;       // two kt16 blocks
        const u32x4* vf = vb0 + (size_t)kt * 512;

        f32x4 S0 = {}, S1 = {};
#pragma unroll
        for (int ks = 0; ks < 4; ++ks) {
            H8 kh;
            kh.v = kf[ks * 64 + lane];
            S0 = __builtin_amdgcn_mfma_f32_16x16x32_f16(Qh[ks].h, kh.h, S0, 0, 0, 0);
            kh.v = kf[256 + ks * 64 + lane];
            S1 = __builtin_amdgcn_mfma_f32_16x16x32_f16(Qh[ks].h, kh.h, S1, 0, 0, 0);
        }

        u16* pw = PB[wave];
#pragma unroll
        for (int r = 0; r < 4; ++r) {
            float e0 = exp2f(fmaf(S0[r], SCALE2_, -4.0f));
            float e1 = exp2f(fmaf(S1[r], SCALE2_, -4.0f));
            lsum[r] += e0 + e1;
            pw[(4 * qd + r) * 33 + c]      = f2h(e0);
            pw[(4 * qd + r) * 33 + 16 + c] = f2h(e1);
        }

        u16 e[8];
#pragma unroll
        for (int j = 0; j < 8; ++j) e[j] = pw[c * 33 + 8 * qd + j];
        H8 Ph;
        Ph.u[0] = (u32)e[0] | ((u32)e[1] << 16);
        Ph.u[1] = (u32)e[2] | ((u32)e[3] << 16);
        Ph.u[2] = (u32)e[4] | ((u32)e[5] << 16);
        Ph.u[3] = (u32)e[6] | ((u32)e[7] << 16);

#pragma unroll
        for (int t = 0; t < 8; ++t) {
            H8 vh;
            vh.v = vf[t * 64 + lane];
            O[t] = __builtin_amdgcn_mfma_f32_16x16x32_f16(Ph.h, vh.h, O[t], 0, 0, 0);
        }
    }

    if (WRITE_PARTIAL) {
        float lred[4];
#pragma unroll
        for (int r = 0; r < 4; ++r) {
            float l = lsum[r];
            l += __shfl_xor(l, 1); l += __shfl_xor(l, 2);
            l += __shfl_xor(l, 4); l += __shfl_xor(l, 8);
            lred[r] = l;
        }
        const size_t rb = (size_t)b * S_ + q0 + wave * 16 + 4 * qd;
        u16* Op = outO + (size_t)part * ((size_t)BS_ * DH);
#pragma unroll
        for (int t = 0; t < 8; ++t)
#pragma unroll
            for (int r = 0; r < 4; ++r)
                Op[(rb + r) * DH + t * 16 + c] = f2h(O[t][r]);
        if (c == 0) {
            u16* lp = outL + (size_t)part * BS_;
#pragma unroll
            for (int r = 0; r < 4; ++r) lp[rb + r] = f2h(lred[r]);
        }
    } else {
        float linv[4];
#pragma unroll
        for (int r = 0; r < 4; ++r) {
            float l = lsum[r];
            l += __shfl_xor(l, 1); l += __shfl_xor(l, 2);
            l += __shfl_xor(l, 4); l += __shfl_xor(l, 8);
            linv[r] = 1.0f / l;
        }
        const size_t rb = (size_t)b * S_ + q0 + wave * 16 + 4 * qd;
#pragma unroll
        for (int t = 0; t < 8; ++t)
#pragma unroll
            for (int r = 0; r < 4; ++r)
                cur[(rb + r) * DH + t * 16 + c] = O[t][r] * linv[r];
    }
}

// single-pass fallback: grid (32, 8). XCD swizzle: batch = rid&7 (bijective).
__global__ __launch_bounds__(256) void attn_kernel(
    const u32* qp, const u32x4* __restrict__ kfrag, const u32x4* __restrict__ vfrag, float* cur)
{
    const int rid = blockIdx.x + 32 * blockIdx.y;
    attn_body<false>(qp, kfrag, vfrag, nullptr, nullptr, cur,
                     rid & 7, ((rid >> 3) & 31) * 64, 0, S_ / 32, 0);
}

// split-KV x4: grid (32, 8, 4) = 1024 blocks. batch = rid&7 per XCD.
__global__ __launch_bounds__(256) void attn_split_kernel(
    const u32* qp, const u32x4* __restrict__ kfrag, const u32x4* __restrict__ vfrag,
    u16* __restrict__ Opart, u16* __restrict__ lpart)
{
    const int rid = blockIdx.x + 32 * (blockIdx.y + 8 * blockIdx.z);
    const int b    = rid & 7;
    const int qx   = (rid >> 3) & 31;
    const int part = rid >> 8;
    const int quart = S_ / 128;   // 16 tiles per part
    attn_body<true>(qp, kfrag, vfrag, Opart, lpart, nullptr,
                    b, qx * 64, part * quart, (part + 1) * quart, part);
}

// combine: cur0 = sum_p O_p / sum_p l_p (f16 partials). grid 512 x 256, 16 elems/thread.
__global__ __launch_bounds__(256) void combine_kernel(
    const u16* __restrict__ Opart, const u16* __restrict__ lpart,
    float* __restrict__ cur)
{
    const size_t N1 = (size_t)BS_ * DH;
    const size_t i0 = ((size_t)blockIdx.x * 256 + threadIdx.x) * 16;
    const int row = (int)(i0 >> 7);
    const float lt = h2f(lpart[row]) + h2f(lpart[BS_ + row])
                   + h2f(lpart[2 * BS_ + row]) + h2f(lpart[3 * BS_ + row]);
    const float linv = 1.0f / lt;
    float acc[16] = {};
#pragma unroll
    for (int p = 0; p < 4; ++p) {
        const u16* op = Opart + (size_t)p * N1 + i0;
        uint4 v0 = *(const uint4*)op;
        uint4 v1 = *(const uint4*)(op + 8);
        const u32 w[8] = {v0.x, v0.y, v0.z, v0.w, v1.x, v1.y, v1.z, v1.w};
#pragma unroll
        for (int j = 0; j < 8; ++j) {
            acc[2 * j]     += h2f((u16)(w[j] & 0xffff));
            acc[2 * j + 1] += h2f((u16)(w[j] >> 16));
        }
    }
#pragma unroll
    for (int t = 0; t < 4; ++t)
        *(float4*)(cur + i0 + t * 4) = make_float4(
            acc[4*t] * linv, acc[4*t+1] * linv, acc[4*t+2] * linv, acc[4*t+3] * linv);
}

// ---------------- prepack round weights (straight repack, no algebra) ----------------
// mats: 0=tw, 1=w1[:,0:128], 2=w1[:,128:256], 3=w1[:,256:384], 4=w2
__global__ __launch_bounds__(256) void prepack_rw_kernel(
    const void* __restrict__ tw, const void* __restrict__ w1, const void* __restrict__ w2,
    const int* __restrict__ flag, u32x4* __restrict__ pk)
{
    const int isb = *flag;
    const int gid = blockIdx.x * 256 + threadIdx.x;   // 10240 total
    const int l = gid & 63, t = (gid >> 6) & 7, ks = (gid >> 9) & 3, mat = gid >> 11;
    const int row = 16 * t + (l & 15);
    const int k0  = ks * 32 + 8 * (l >> 4);
    float f[8];
    if (mat == 0)      ld8(tw, (size_t)row * DH + k0, isb, f);
    else if (mat <= 3) ld8(w1, (size_t)row * 384 + (mat - 1) * 128 + k0, isb, f);
    else               ld8(w2, (size_t)row * DH + k0, isb, f);
    u32x4 hi, lo;
    split8(f, hi, lo);
    const size_t base = (((size_t)mat * 4 + ks) * 16 + 2 * t) * 64 + l;
    pk[base] = hi; pk[base + 64] = lo;
}

// pre-split A fragments
struct Afrag { H8 h[4], l[4]; };
__device__ __forceinline__ void splitA(const float (&A)[4][8], Afrag& F) {
#pragma unroll
    for (int ks = 0; ks < 4; ++ks) split8(A[ks], F.h[ks].v, F.l[ks].v);
}

// ---------------- one dialectic round: 32 tokens/block, grid 512, dbuf stage ----------------
// Waves: rowg = wave>>1 picks rows 16*rowg..+15; colh = wave&1 picks col-tiles 4*colh..+3.
__global__ __launch_bounds__(256) void round_kernel(
    const float* cur0, const float* curr,
    const u32x4* __restrict__ pk,
    const void* __restrict__ tb, const void* __restrict__ ab,
    const void* __restrict__ b1, const void* __restrict__ b2,
    const void* __restrict__ gw, const void* __restrict__ gb,
    const int* __restrict__ flag, int* active, int* counts, int r,
    float* cur_out, void* dout)
{
    const int isb = *flag;
    const int tok0 = blockIdx.x * 32;
    const int tid = threadIdx.x;
    const bool last = (dout != nullptr);

    if (counts[r] <= 0) {
        if (last) {
            for (int e = tid; e < 32 * DH; e += 256) {
                size_t idx = (size_t)tok0 * DH + e;
                float v = curr[idx];
                if (isb) ((__hip_bfloat16*)dout)[idx] = __float2bfloat16(v);
                else     ((float*)dout)[idx] = v;
            }
        }
        return;
    }

    const int wave = tid >> 6, lane = tid & 63;
    const int qd = lane >> 4, c = lane & 15;
    const int rowg = wave >> 1, colh = wave & 1;

    __shared__ u32x4 WB[2][4][8][64];   // 64 KB double-buffered weight stage
    __shared__ u16 TS[32][132];         // t0 -> h -> synth (f16, 8.4 KB)
    __shared__ float actS[32], tbS[128], abS[128], b1S[128], b2S[128], gwS[256];
    __shared__ int blkcnt;

    // bf16: stage full mat (hi slabs) into buf; 32 slabs, 8 per wave
    auto stageB = [&](int mat, int buf) {
#pragma unroll
        for (int j = 0; j < 8; ++j) {
            const int g = wave * 8 + j, ks = g >> 3, t = g & 7;
            __builtin_amdgcn_global_load_lds(
                (const __attribute__((address_space(1))) u32*)(
                    pk + (((size_t)mat * 4 + ks) * 16 + 2 * t) * 64 + lane),
                (__attribute__((address_space(3))) u32*)&WB[buf][ks][t][0],
                16, 0, 0);
        }
    };
    // fp32: stage ks-half h of mat (2ks x 8t x 2 planes = 32 slabs), 8 per wave
    auto stageF = [&](int mat, int h, int buf) {
#pragma unroll
        for (int j = 0; j < 8; ++j) {
            const int g = wave * 8 + j, kl = g >> 4, p = (g >> 3) & 1, t = g & 7;
            __builtin_amdgcn_global_load_lds(
                (const __attribute__((address_space(1))) u32*)(
                    pk + (((size_t)mat * 4 + 2 * h + kl) * 16 + 2 * t + p) * 64 + lane),
                (__attribute__((address_space(3))) u32*)&WB[buf][kl * 2 + p][t][0],
                16, 0, 0);
        }
    };
    auto gemmB = [&](const Afrag& F, int buf, f32x4 (&acc)[4]) {
#pragma unroll
        for (int ks = 0; ks < 4; ++ks)
#pragma unroll
            for (int tl = 0; tl < 4; ++tl) {
                H8 bh; bh.v = WB[buf][ks][4 * colh + tl][lane];
                acc[tl] = __builtin_amdgcn_mfma_f32_16x16x32_f16(F.l[ks].h, bh.h, acc[tl], 0, 0, 0);
                acc[tl] = __builtin_amdgcn_mfma_f32_16x16x32_f16(F.h[ks].h, bh.h, acc[tl], 0, 0, 0);
            }
    };
    auto gemmFh = [&](const Afrag& F, int h, int buf, f32x4 (&acc)[4]) {
#pragma unroll
        for (int kl = 0; kl < 2; ++kl) {
            const int ks = 2 * h + kl;
#pragma unroll
            for (int tl = 0; tl < 4; ++tl) {
                H8 bh, bl;
                bh.v = WB[buf][kl * 2][4 * colh + tl][lane];
                bl.v = WB[buf][kl * 2 + 1][4 * colh + tl][lane];
                acc[tl] = __builtin_amdgcn_mfma_f32_16x16x32_f16(F.l[ks].h, bh.h, acc[tl], 0, 0, 0);
                acc[tl] = __builtin_amdgcn_mfma_f32_16x16x32_f16(F.h[ks].h, bl.h, acc[tl], 0, 0, 0);
                acc[tl] = __builtin_amdgcn_mfma_f32_16x16x32_f16(F.h[ks].h, bh.h, acc[tl], 0, 0, 0);
            }
        }
    };
    auto STAGE = [&](int mat, int buf) { if (isb) stageB(mat, buf); else stageF(mat, 0, buf); };
    // full GEMM over mat in buf (first half pre-staged+barriered by caller)
    auto GEMM = [&](int mat, const Afrag& F, int buf, f32x4 (&acc)[4]) {
        if (isb) {
            gemmB(F, buf, acc);
        } else {
            gemmFh(F, 0, buf, acc);
            __syncthreads();
            stageF(mat, 1, buf);
            __syncthreads();
            gemmFh(F, 1, buf, acc);
        }
    };

    STAGE(0, 0);   // tw
    if (tid < 32) actS[tid] = active[tok0 + tid] ? 1.0f : 0.0f;
    if (tid < 128) {
        tbS[tid] = ldE(tb, tid, isb); abS[tid] = ldE(ab, tid, isb);
        b1S[tid] = ldE(b1, tid, isb); b2S[tid] = ldE(b2, tid, isb);
    }
    gwS[tid] = ldE(gw, tid, isb);
    if (tid == 0) blkcnt = 0;
    const float gbf = ldE(gb, 0, isb);

    const int rowl = 16 * rowg + c;      // this lane's A-row (local, 0..31)
    const int hr   = 16 * rowg + 4 * qd; // this lane's C-row base (local)

    float A1[4][8];
    {
        const float* cr = cur0 + (size_t)(tok0 + rowl) * DH;
#pragma unroll
        for (int ks = 0; ks < 4; ++ks) {
            *(float4*)&A1[ks][0] = *(const float4*)(cr + ks * 32 + 8 * qd);
            *(float4*)&A1[ks][4] = *(const float4*)(cr + ks * 32 + 8 * qd + 4);
        }
    }
    Afrag FA; splitA(A1, FA);
    __syncthreads();                     // buf0 ready, consts visible

    // ---- t0 = cur0 @ tw^T ----
    STAGE(1, 1);                         // prefetch w1a under the GEMM
    {
        f32x4 accT[4] = {};
        GEMM(0, FA, 0, accT);
#pragma unroll
        for (int tl = 0; tl < 4; ++tl)
#pragma unroll
            for (int rr = 0; rr < 4; ++rr)
                TS[hr + rr][16 * (4 * colh + tl) + c] = f2h(accT[tl][rr]);
    }
    __syncthreads();                     // buf1 ready, TS(t0) visible, buf0 free

    STAGE(2, 0);                         // w1b
    f32x4 acc1[4] = {};
    const float am_r = actS[rowl];
    {
        float Ac[4][8];
#pragma unroll
        for (int ks = 0; ks < 4; ++ks)
#pragma unroll
            for (int j = 0; j < 8; ++j) {
                const int k = ks * 32 + 8 * qd + j;
                Ac[ks][j] = (h2f(TS[rowl][k]) + tbS[k]) * am_r;   // at
            }
        Afrag FC; splitA(Ac, FC);
        GEMM(1, FC, 1, acc1);
    }
    __syncthreads();                     // buf0 ready, buf1 free

    STAGE(3, 1);                         // w1c
    {
        float Ac[4][8];
#pragma unroll
        for (int ks = 0; ks < 4; ++ks)
#pragma unroll
            for (int j = 0; j < 8; ++j) {
                const int k = ks * 32 + 8 * qd + j;
                Ac[ks][j] = (abS[k] - h2f(TS[rowl][k])) * am_r;   // aa
            }
        Afrag FC; splitA(Ac, FC);
        GEMM(2, FC, 0, acc1);
    }
    __syncthreads();                     // buf1 ready; all TS(t0) reads complete

    STAGE(4, 0);                         // w2
    {
        float Ac[4][8];
        const float* cr = curr + (size_t)(tok0 + rowl) * DH;
#pragma unroll
        for (int ks = 0; ks < 4; ++ks) {
            float4 a0 = *(const float4*)(cr + ks * 32 + 8 * qd);
            float4 a1 = *(const float4*)(cr + ks * 32 + 8 * qd + 4);
            Ac[ks][0] = a0.x * am_r; Ac[ks][1] = a0.y * am_r;
            Ac[ks][2] = a0.z * am_r; Ac[ks][3] = a0.w * am_r;
            Ac[ks][4] = a1.x * am_r; Ac[ks][5] = a1.y * am_r;
            Ac[ks][6] = a1.z * am_r; Ac[ks][7] = a1.w * am_r;
        }
        Afrag FC; splitA(Ac, FC);
        GEMM(3, FC, 1, acc1);
    }
    // h = relu(acc1 + b1) -> TS (t0 dead; own rows/cols only)
#pragma unroll
    for (int tl = 0; tl < 4; ++tl)
#pragma unroll
        for (int rr = 0; rr < 4; ++rr) {
            const int col = 16 * (4 * colh + tl) + c;
            TS[hr + rr][col] = f2h(fmaxf(acc1[tl][rr] + b1S[col], 0.0f));
        }
    __syncthreads();                     // buf0(w2) ready, h visible

    {
        float Ac[4][8];
#pragma unroll
        for (int ks = 0; ks < 4; ++ks)
#pragma unroll
            for (int j = 0; j < 8; ++j)
                Ac[ks][j] = h2f(TS[rowl][ks * 32 + 8 * qd + j]);
        Afrag FC; splitA(Ac, FC);
        f32x4 acc2[4] = {};
        GEMM(4, FC, 0, acc2);
        __syncthreads();                 // all h reads done before synth overwrite
#pragma unroll
        for (int tl = 0; tl < 4; ++tl)
#pragma unroll
            for (int rr = 0; rr < 4; ++rr) {
                const int col = 16 * (4 * colh + tl) + c;
                TS[hr + rr][col] = f2h(acc2[tl][rr] + b2S[col]);
            }
    }
    __syncthreads();                     // synth visible

    // ---- gate, update, norm, active: 8 threads/token, 16 elems each ----
    const int tok = tid >> 3, d0 = (tid & 7) * 16;
    const float am = actS[tok];
    const float* cp = curr + (size_t)(tok0 + tok) * DH + d0;
    float cv[16];
#pragma unroll
    for (int t = 0; t < 4; ++t) {
        float4 vv = *(const float4*)(cp + t * 4);
        cv[t * 4] = vv.x; cv[t * 4 + 1] = vv.y; cv[t * 4 + 2] = vv.z; cv[t * 4 + 3] = vv.w;
    }
    float srow[16];
#pragma unroll
    for (int e = 0; e < 16; ++e) srow[e] = h2f(TS[tok][d0 + e]);
    float gp = 0.0f;
#pragma unroll
    for (int e = 0; e < 16; ++e)
        gp += cv[e] * am * gwS[d0 + e] + srow[e] * gwS[128 + d0 + e];
    gp += __shfl_xor(gp, 1, 8);
    gp += __shfl_xor(gp, 2, 8);
    gp += __shfl_xor(gp, 4, 8);
    const float gate = 1.0f / (1.0f + __expf(-(gp + gbf)));
    float ss = 0.0f; float up[16];
#pragma unroll
    for (int e = 0; e < 16; ++e) {
        float u = gate * (srow[e] - cv[e] * am) * 0.1f;
        up[e] = u; ss += u * u;
    }
    ss += __shfl_xor(ss, 1, 8);
    ss += __shfl_xor(ss, 2, 8);
    ss += __shfl_xor(ss, 4, 8);
    const bool stable = sqrtf(ss) < 0.1f;

    if (last) {
        size_t off = (size_t)(tok0 + tok) * DH + d0;
        if (isb) {
            __hip_bfloat16* op = (__hip_bfloat16*)dout + off;
#pragma unroll
            for (int e = 0; e < 16; ++e) op[e] = __float2bfloat16(cv[e] + up[e]);
        } else {
            float* op = (float*)dout + off;
#pragma unroll
            for (int t = 0; t < 4; ++t)
                *(float4*)(op + t * 4) = make_float4(cv[t * 4] + up[t * 4], cv[t * 4 + 1] + up[t * 4 + 1],
                                                     cv[t * 4 + 2] + up[t * 4 + 2], cv[t * 4 + 3] + up[t * 4 + 3]);
        }
    } else {
        float* op = cur_out + (size_t)(tok0 + tok) * DH + d0;
#pragma unroll
        for (int t = 0; t < 4; ++t)
            *(float4*)(op + t * 4) = make_float4(cv[t * 4] + up[t * 4], cv[t * 4 + 1] + up[t * 4 + 1],
                                                 cv[t * 4 + 2] + up[t * 4 + 2], cv[t * 4 + 3] + up[t * 4 + 3]);
    }
    const int newact = (am > 0.0f && !stable) ? 1 : 0;
    if ((tid & 7) == 0) {
        active[tok0 + tok] = newact;
        if (newact) atomicAdd(&blkcnt, 1);
    }
    __syncthreads();
    if (tid == 0 && blkcnt > 0) atomicAdd(&counts[r + 1], blkcnt);
}

extern "C" void kernel_launch(void* const* d_in, const int* in_sizes, int n_in,
                              void* d_out, int out_size, void* d_ws, size_t ws_size,
                              hipStream_t stream) {
    const void* x  = d_in[0];
    const void* wq = d_in[1];
    const void* wk = d_in[2];
    const void* wv = d_in[3];
    const void* tw = d_in[4];
    const void* tb = d_in[5];
    const void* ab = d_in[6];
    const void* w1 = d_in[7];
    const void* b1 = d_in[8];
    const void* w2 = d_in[9];
    const void* b2 = d_in[10];
    const void* gw = d_in[11];
    const void* gb = d_in[12];

    u32* ws = (u32*)d_ws;
    const size_t N1 = (size_t)BS_ * DH;
    // base layout (~24 MiB): qp | kp | vp | active | counts | flag
    u32* qp = ws;
    u32* kp = ws + N1;        // K MFMA-frags (4 MB used of 8 MB region)
    u32* vp = ws + 2 * N1;    // V MFMA-frags (4 MB used of 8 MB region)
    int* active = (int*)(ws + 3 * N1);
    int* counts = active + BS_;
    int* flag   = counts + 4;
    float* cur0  = (float*)qp;
    float* cur_r = (float*)kp;    // overwrites dead K-frags after attn
    // split-KV x4 extension (f16 partials), ends at 42.2 MB <= 42.3 MB guarantee
    u16* Opart16 = (u16*)(ws + 3 * N1 + 32768);
    u16* lpart16 = (u16*)(ws + 5 * N1 + 32768);
    const bool big_ws = ws_size >= (size_t)42300000;        // constant across calls
    // prepacked QKV W: transient in Opart region (dead before attention writes it)
    u32x4* wpk = (u32x4*)(ws + 3 * N1 + 32768);
    // prepacked round weights: in vp region (V-frags dead after attn), 320 KB
    u32x4* pkRW = (u32x4*)vp;
    u32x4* kfragP = (u32x4*)kp;
    u32x4* vfragP = (u32x4*)vp;

    init_kernel<<<dim3(BS_ / 256), 256, 0, stream>>>(x, flag, active, counts);
    prepack_w_kernel<<<dim3(192), 256, 0, stream>>>(wq, wk, wv, flag, wpk);
    qkv_kernel<<<dim3(BS_ / 64, 1, 3), 256, 0, stream>>>(x, wpk, flag, qp, kfragP, vfragP);
    if (big_ws) {
        attn_split_kernel<<<dim3(S_ / 64, B_, 4), 256, 0, stream>>>(qp, kfragP, vfragP, Opart16, lpart16);
        combine_kernel<<<dim3(512), 256, 0, stream>>>(Opart16, lpart16, cur0);
    } else {
        attn_kernel<<<dim3(S_ / 64, B_), 256, 0, stream>>>(qp, kfragP, vfragP, cur0);
    }
    prepack_rw_kernel<<<dim3(40), 256, 0, stream>>>(tw, w1, w2, flag, pkRW);
    round_kernel<<<dim3(BS_ / 32), 256, 0, stream>>>(
        cur0, cur0, pkRW, tb, ab, b1, b2, gw, gb, flag, active, counts, 0, cur_r, nullptr);
    round_kernel<<<dim3(BS_ / 32), 256, 0, stream>>>(
        cur0, cur_r, pkRW, tb, ab, b1, b2, gw, gb, flag, active, counts, 1, cur_r, nullptr);
    round_kernel<<<dim3(BS_ / 32), 256, 0, stream>>>(
        cur0, cur_r, pkRW, tb, ab, b1, b2, gw, gb, flag, active, counts, 2, cur_r, d_out);
}